// Round 4
// baseline (9563.682 us; speedup 1.0000x reference)
//
#include <hip/hip_runtime.h>
#include <hip/hip_bf16.h>

typedef __hip_bfloat16 bf16;
typedef unsigned short us;

#define Bz 4
#define Tz 2048
#define Dz 1024
#define Hz 8
#define DKz 96
#define DVz 192
#define KDz 768
#define VDz 1536
#define Iz 4096
#define BTz (Bz*Tz)

static __device__ __forceinline__ float us2f(us s){
  return __uint_as_float(((unsigned)s) << 16);
}
static __device__ __forceinline__ us f2bs(float f){
  bf16 t = __float2bfloat16(f);
  return *(us*)&t;
}
static __device__ __forceinline__ float sigmoidf_(float x){ return 1.f/(1.f+expf(-x)); }
static __device__ __forceinline__ float siluf_(float x){ return x*sigmoidf_(x); }
static __device__ __forceinline__ float bcastf(float x, int l){
  return __int_as_float(__builtin_amdgcn_readlane(__float_as_int(x), l));
}

// ---------------- RMSNorm (f32 in -> bf16 out, f32 weights) ----------------
__global__ __launch_bounds__(256) void rmsnorm_kernel(
    const float* __restrict__ x, const float* __restrict__ w, bf16* __restrict__ out)
{
  const int row = blockIdx.x;
  const float* xr = x + (size_t)row*Dz;
  const int i0 = threadIdx.x*4;
  float4 xv = *(const float4*)(xr + i0);
  float ss = xv.x*xv.x+xv.y*xv.y+xv.z*xv.z+xv.w*xv.w;
  #pragma unroll
  for (int off=32; off>=1; off>>=1) ss += __shfl_xor(ss, off);
  __shared__ float red[4];
  if ((threadIdx.x&63)==0) red[threadIdx.x>>6] = ss;
  __syncthreads();
  ss = red[0]+red[1]+red[2]+red[3];
  const float inv = rsqrtf(ss*(1.f/Dz) + 1e-6f);
  float4 wv = *(const float4*)(w + i0);
  ushort4 ov;
  ov.x=f2bs(xv.x*inv*wv.x); ov.y=f2bs(xv.y*inv*wv.y);
  ov.z=f2bs(xv.z*inv*wv.z); ov.w=f2bs(xv.w*inv*wv.w);
  *(ushort4*)((us*)out + (size_t)row*Dz + i0) = ov;
}

// ------------- Tiled GEMM: C[M,N] = A[M,K](bf16) @ B[K,N](f32) (+res) -------------
// MODE 0: write bf16.
// MODE 1: write f32, add f32 residual.
// MODE 3: write bf16 = silu(bf16 res) * acc   (res/out alias elementwise: safe)
template<int MODE>
__global__ __launch_bounds__(256) void gemm_kernel(
    const bf16* __restrict__ A, const float* __restrict__ Bw,
    const void* __restrict__ res, void* __restrict__ Cout,
    int M, int N, int K)
{
  __shared__ float As[16][64];
  __shared__ float Bs[16][64];
  const int bm = blockIdx.y*64, bn = blockIdx.x*64;
  const int tid = threadIdx.x;
  const int tx = tid & 15, ty = tid >> 4;
  const int am = tid >> 2, ak = (tid & 3) * 4;
  const int bk = tid >> 4, bn4 = (tid & 15) * 4;
  const us* Ap = (const us*)A + (size_t)(bm+am)*K + ak;
  const float* Bp = Bw + (size_t)bk*N + bn + bn4;
  float acc[4][4] = {};
  for (int k0 = 0; k0 < K; k0 += 16){
    ushort4 av = *(const ushort4*)(Ap + k0);
    float4 bv = *(const float4*)(Bp + (size_t)k0*N);
    As[ak+0][am]=us2f(av.x); As[ak+1][am]=us2f(av.y);
    As[ak+2][am]=us2f(av.z); As[ak+3][am]=us2f(av.w);
    *(float4*)&Bs[bk][bn4] = bv;
    __syncthreads();
    #pragma unroll
    for (int kk=0; kk<16; kk++){
      float4 a4 = *(float4*)&As[kk][ty*4];
      float4 b4 = *(float4*)&Bs[kk][tx*4];
      float a[4]={a4.x,a4.y,a4.z,a4.w}, b[4]={b4.x,b4.y,b4.z,b4.w};
      #pragma unroll
      for (int i=0;i<4;i++)
        #pragma unroll
        for (int j=0;j<4;j++)
          acc[i][j] = fmaf(a[i], b[j], acc[i][j]);
    }
    __syncthreads();
  }
  #pragma unroll
  for (int i=0;i<4;i++){
    const int row = bm + ty*4 + i;
    const size_t base = (size_t)row*N + bn + tx*4;
    if (MODE==0){
      ushort4 ov;
      ov.x=f2bs(acc[i][0]); ov.y=f2bs(acc[i][1]); ov.z=f2bs(acc[i][2]); ov.w=f2bs(acc[i][3]);
      *(ushort4*)((us*)Cout + base) = ov;
    } else if (MODE==1){
      float4 rv = *(const float4*)((const float*)res + base);
      float4 ov = make_float4(acc[i][0]+rv.x, acc[i][1]+rv.y, acc[i][2]+rv.z, acc[i][3]+rv.w);
      *(float4*)((float*)Cout + base) = ov;
    } else {
      ushort4 rv = *(const ushort4*)((const us*)res + base);
      ushort4 ov;
      ov.x=f2bs(siluf_(us2f(rv.x))*acc[i][0]); ov.y=f2bs(siluf_(us2f(rv.y))*acc[i][1]);
      ov.z=f2bs(siluf_(us2f(rv.z))*acc[i][2]); ov.w=f2bs(siluf_(us2f(rv.w))*acc[i][3]);
      *(ushort4*)((us*)Cout + base) = ov;
    }
  }
}

// ---------------- beta / g projections (N=8 each, f32 weights) ----------------
__global__ __launch_bounds__(256) void beta_g_kernel(
    const bf16* __restrict__ hh, const float* __restrict__ Wb, const float* __restrict__ Wa,
    const float* __restrict__ A_log, const float* __restrict__ dt_bias,
    float* __restrict__ beta, float* __restrict__ g)
{
  const int row = blockIdx.x;
  const us* hr = (const us*)hh + (size_t)row*Dz;
  float ab[8]={0,0,0,0,0,0,0,0}, aa[8]={0,0,0,0,0,0,0,0};
  for (int kk=threadIdx.x; kk<Dz; kk+=256){
    const float hv = us2f(hr[kk]);
    float4 b0 = *(const float4*)(Wb + kk*8);
    float4 b1 = *(const float4*)(Wb + kk*8 + 4);
    float4 a0 = *(const float4*)(Wa + kk*8);
    float4 a1 = *(const float4*)(Wa + kk*8 + 4);
    ab[0]=fmaf(hv,b0.x,ab[0]); ab[1]=fmaf(hv,b0.y,ab[1]);
    ab[2]=fmaf(hv,b0.z,ab[2]); ab[3]=fmaf(hv,b0.w,ab[3]);
    ab[4]=fmaf(hv,b1.x,ab[4]); ab[5]=fmaf(hv,b1.y,ab[5]);
    ab[6]=fmaf(hv,b1.z,ab[6]); ab[7]=fmaf(hv,b1.w,ab[7]);
    aa[0]=fmaf(hv,a0.x,aa[0]); aa[1]=fmaf(hv,a0.y,aa[1]);
    aa[2]=fmaf(hv,a0.z,aa[2]); aa[3]=fmaf(hv,a0.w,aa[3]);
    aa[4]=fmaf(hv,a1.x,aa[4]); aa[5]=fmaf(hv,a1.y,aa[5]);
    aa[6]=fmaf(hv,a1.z,aa[6]); aa[7]=fmaf(hv,a1.w,aa[7]);
  }
  #pragma unroll
  for (int off=32; off>=1; off>>=1){
    #pragma unroll
    for (int n=0;n<8;n++){ ab[n]+=__shfl_xor(ab[n],off); aa[n]+=__shfl_xor(aa[n],off); }
  }
  __shared__ float red[4][16];
  const int wv = threadIdx.x>>6, ln = threadIdx.x&63;
  if (ln==0){
    #pragma unroll
    for (int n=0;n<8;n++){ red[wv][n]=ab[n]; red[wv][8+n]=aa[n]; }
  }
  __syncthreads();
  if (threadIdx.x < 8){
    const int n = threadIdx.x;
    float sb = red[0][n]+red[1][n]+red[2][n]+red[3][n];
    float sa = red[0][8+n]+red[1][8+n]+red[2][8+n]+red[3][8+n];
    beta[(size_t)row*Hz+n] = 1.f/(1.f+expf(-sb));
    float xx = sa + dt_bias[n];
    float sp = (xx > 20.f) ? xx : log1pf(expf(xx));
    g[(size_t)row*Hz+n] = -expf(A_log[n])*sp;
  }
}

// ---------------- fused conv(K=4)+SiLU+l2norm + gated delta-rule scan ----------------
// 1 block per (b,h), 192 threads; thread j owns S column j (96 f32 regs).
__global__ __launch_bounds__(192) void scan_kernel(
    const bf16* __restrict__ preq, const bf16* __restrict__ prek, const bf16* __restrict__ prev,
    const float* __restrict__ wqc, const float* __restrict__ wkc, const float* __restrict__ wvc,
    const float* __restrict__ g, const float* __restrict__ beta, bf16* __restrict__ o)
{
  const int bh = blockIdx.x; const int b = bh >> 3, h = bh & 7;
  const int j = threadIdx.x, lane = threadIdx.x & 63;
  const bool hi = lane < 32;
  const int kc0 = h*DKz + lane, kc1 = kc0 + 64;
  const int vc  = h*DVz + j;

  float wq0[4], wq1[4], wk0[4], wk1[4], wv[4];
  #pragma unroll
  for (int i=0;i<4;i++){
    wq0[i] = wqc[kc0*4+i];
    wk0[i] = wkc[kc0*4+i];
    wv[i]  = wvc[vc*4+i];
    wq1[i] = hi ? wqc[kc1*4+i] : 0.f;
    wk1[i] = hi ? wkc[kc1*4+i] : 0.f;
  }

  const us* QP = (const us*)preq + (size_t)b*Tz*KDz;
  const us* KP = (const us*)prek + (size_t)b*Tz*KDz;
  const us* VP = (const us*)prev + (size_t)b*Tz*VDz;
  us* op = (us*)o + (size_t)b*Tz*VDz + vc;
  const float* gp = g + (size_t)b*Tz*Hz + h;
  const float* bp = beta + (size_t)b*Tz*Hz + h;

  float S[96];
  #pragma unroll
  for (int i=0;i<96;i++) S[i]=0.f;

  // conv rings: taps t-3, t-2, t-1 (zero-init = causal zero pad at t<0)
  float q0a=0,q0b=0,q0c=0, q1a=0,q1b=0,q1c=0;
  float k0a=0,k0b=0,k0c=0, k1a=0,k1b=0,k1c=0;
  float va=0,vb=0,vcc=0;

  float nq0 = us2f(QP[kc0]), nq1 = hi? us2f(QP[kc1]) : 0.f;
  float nk0 = us2f(KP[kc0]), nk1 = hi? us2f(KP[kc1]) : 0.f;
  float nv  = us2f(VP[vc]);
  float ng = gp[0], nb = bp[0];

  for (int t=0; t<Tz; t++){
    const float rq0=nq0, rq1=nq1, rk0=nk0, rk1=nk1, rv=nv, cg=ng, cb=nb;
    if (t+1 < Tz){
      const size_t r = (size_t)(t+1);
      nq0 = us2f(QP[r*KDz+kc0]); nq1 = hi? us2f(QP[r*KDz+kc1]) : 0.f;
      nk0 = us2f(KP[r*KDz+kc0]); nk1 = hi? us2f(KP[r*KDz+kc1]) : 0.f;
      nv  = us2f(VP[r*VDz+vc]);
      ng  = gp[r*Hz]; nb = bp[r*Hz];
    }
    // depthwise causal conv, 4 taps
    float yq0 = fmaf(q0a,wq0[0], fmaf(q0b,wq0[1], fmaf(q0c,wq0[2], rq0*wq0[3])));
    float yq1 = fmaf(q1a,wq1[0], fmaf(q1b,wq1[1], fmaf(q1c,wq1[2], rq1*wq1[3])));
    float yk0 = fmaf(k0a,wk0[0], fmaf(k0b,wk0[1], fmaf(k0c,wk0[2], rk0*wk0[3])));
    float yk1 = fmaf(k1a,wk1[0], fmaf(k1b,wk1[1], fmaf(k1c,wk1[2], rk1*wk1[3])));
    float yv  = fmaf(va ,wv[0],  fmaf(vb ,wv[1],  fmaf(vcc,wv[2],  rv *wv[3])));
    q0a=q0b; q0b=q0c; q0c=rq0;   q1a=q1b; q1b=q1c; q1c=rq1;
    k0a=k0b; k0b=k0c; k0c=rk0;   k1a=k1b; k1b=k1c; k1c=rk1;
    va=vb; vb=vcc; vcc=rv;
    yq0 = siluf_(yq0); yq1 = hi? siluf_(yq1) : 0.f;
    yk0 = siluf_(yk0); yk1 = hi? siluf_(yk1) : 0.f;
    const float cv = siluf_(yv);
    // l2norm over 96 channels (wave butterfly; lanes>=32 contribute 0 for *1 slots)
    float ssq = yq0*yq0 + yq1*yq1;
    float ssk = yk0*yk0 + yk1*yk1;
    #pragma unroll
    for (int off=32; off>=1; off>>=1){ ssq += __shfl_xor(ssq,off); ssk += __shfl_xor(ssk,off); }
    const float invq = rsqrtf(ssq + 1e-6f) * 0.10206207262f;  // * dk^-0.5
    const float invk = rsqrtf(ssk + 1e-6f);
    const float cq0 = yq0*invq, cq1 = yq1*invq;
    const float ck0 = yk0*invk, ck1 = yk1*invk;

    // gated delta rule
    const float eg = expf(cg);
    float a4[4]={0.f,0.f,0.f,0.f};
    #pragma unroll
    for (int kk=0;kk<96;kk++)
      a4[kk&3] = fmaf(bcastf(kk<64?ck0:ck1, kk&63), S[kk], a4[kk&3]);
    const float vold = (a4[0]+a4[1])+(a4[2]+a4[3]);   // k . S_{t-1}
    const float delta = (cv - eg*vold)*cb;
    float ob[4]={0.f,0.f,0.f,0.f};
    #pragma unroll
    for (int kk=0;kk<96;kk++){
      const float kb = bcastf(kk<64?ck0:ck1, kk&63);
      const float qb = bcastf(kk<64?cq0:cq1, kk&63);
      const float s = fmaf(eg, S[kk], kb*delta);
      S[kk] = s;
      ob[kk&3] = fmaf(qb, s, ob[kk&3]);
    }
    op[(size_t)t*VDz] = f2bs((ob[0]+ob[1])+(ob[2]+ob[3]));
  }
}

// ---------------- output gate: rmsnorm_dv(o) * silu(gout) ----------------
__global__ __launch_bounds__(64) void gate_out_kernel(
    const bf16* __restrict__ o, const bf16* __restrict__ gout,
    const float* __restrict__ onw, bf16* __restrict__ og)
{
  const size_t base = (size_t)blockIdx.x * DVz;
  const int lane = threadIdx.x;
  const us* O = (const us*)o;
  float x0 = us2f(O[base+lane]), x1 = us2f(O[base+64+lane]), x2 = us2f(O[base+128+lane]);
  float ss = x0*x0 + x1*x1 + x2*x2;
  #pragma unroll
  for (int off=32; off>=1; off>>=1) ss += __shfl_xor(ss, off);
  const float inv = rsqrtf(ss*(1.f/DVz) + 1e-6f);
  const us* G = (const us*)gout;
  us* OG = (us*)og;
  float xs[3] = {x0, x1, x2};
  #pragma unroll
  for (int i=0;i<3;i++){
    const int c = lane + 64*i;
    const float gv = us2f(G[base+c]);
    OG[base+c] = f2bs(xs[i]*inv*onw[c] * siluf_(gv));
  }
}

extern "C" void kernel_launch(void* const* d_in, const int* in_sizes, int n_in,
                              void* d_out, int out_size, void* d_ws, size_t ws_size,
                              hipStream_t stream) {
  const float* x        = (const float*)d_in[0];
  const float* Wq       = (const float*)d_in[1];
  const float* Wk       = (const float*)d_in[2];
  const float* Wv       = (const float*)d_in[3];
  const float* Wb       = (const float*)d_in[4];
  const float* Wa       = (const float*)d_in[5];
  const float* A_log    = (const float*)d_in[6];
  const float* dt_bias  = (const float*)d_in[7];
  const float* conv_q_w = (const float*)d_in[8];
  const float* conv_k_w = (const float*)d_in[9];
  const float* conv_v_w = (const float*)d_in[10];
  const float* Wg       = (const float*)d_in[11];
  const float* onorm_w  = (const float*)d_in[12];
  const float* Wo       = (const float*)d_in[13];
  const float* norm1_w  = (const float*)d_in[14];
  const float* norm2_w  = (const float*)d_in[15];
  const float* Wgate    = (const float*)d_in[16];
  const float* Wup      = (const float*)d_in[17];
  const float* Wdown    = (const float*)d_in[18];

  char* W = (char*)d_ws;
  // workspace layout; PEAK = 92,798,976 bytes (during scan). lifetime-safe aliasing.
  bf16*  h_    = (bf16*) (W + 0);          // [8192,1024] bf16; live: rmsnorm1 -> gout GEMM
  bf16*  preq  = (bf16*) (W + 16777216);   // [8192,768];  live: GEMM -> scan
  bf16*  prek  = (bf16*) (W + 29360128);   // [8192,768];  live: GEMM -> scan
  bf16*  prev  = (bf16*) (W + 41943040);   // [8192,1536]; live: GEMM -> scan
  float* beta_ = (float*)(W + 67108864);   // [8192,8];    live: beta_g -> scan
  float* g_    = (float*)(W + 67371008);   // [8192,8];    live: beta_g -> scan
  bf16*  o_    = (bf16*) (W + 67633152);   // [8192,1536]; live: scan -> gate_out  (peak end 92,798,976)
  // aliases over dead regions
  bf16*  gout  = (bf16*) (W + 41943040);   // [8192,1536] over prev (dead after scan)
  bf16*  og    = (bf16*) (W + 0);          // [8192,1536] over h_+preq-head (dead after gout GEMM)
  float* x2    = (float*)(W + 41943040);   // [8192,1024] f32 over gout+o_-head (dead after gate_out)
  bf16*  h2    = (bf16*) (W + 25165824);   // [8192,1024] over preq/prek-tail (dead after scan)
  bf16*  gateC = (bf16*) (W + 0);          // [2048,4096] chunk over og (dead after Wo GEMM)

  // 1. pre-norm
  rmsnorm_kernel<<<BTz, 256, 0, stream>>>(x, norm1_w, h_);
  // 2. q/k/v projections (pre-conv), beta/g
  gemm_kernel<0><<<dim3(12,128), 256, 0, stream>>>(h_, Wq, nullptr, preq, BTz, KDz, Dz);
  gemm_kernel<0><<<dim3(12,128), 256, 0, stream>>>(h_, Wk, nullptr, prek, BTz, KDz, Dz);
  gemm_kernel<0><<<dim3(24,128), 256, 0, stream>>>(h_, Wv, nullptr, prev, BTz, VDz, Dz);
  beta_g_kernel<<<BTz, 256, 0, stream>>>(h_, Wb, Wa, A_log, dt_bias, beta_, g_);
  // 3. fused conv+silu+l2norm + recurrent scan
  scan_kernel<<<Bz*Hz, 192, 0, stream>>>(preq, prek, prev, conv_q_w, conv_k_w, conv_v_w,
                                         g_, beta_, o_);
  // 4. output-gate projection (after scan so it can reuse prev's storage)
  gemm_kernel<0><<<dim3(24,128), 256, 0, stream>>>(h_, Wg, nullptr, gout, BTz, VDz, Dz);
  // 5. output gating + Wo projection with residual
  gate_out_kernel<<<BTz*Hz, 64, 0, stream>>>(o_, gout, onorm_w, og);
  gemm_kernel<1><<<dim3(16,128), 256, 0, stream>>>(og, Wo, x, x2, BTz, Dz, VDz);
  // 6. MLP, chunked over 4 x 2048 rows (gate buffer = 16.8 MB instead of 67 MB)
  rmsnorm_kernel<<<BTz, 256, 0, stream>>>(x2, norm2_w, h2);
  for (int c = 0; c < 4; c++){
    const bf16*  h2c = h2 + (size_t)c*2048*Dz;
    const float* x2c = x2 + (size_t)c*2048*Dz;
    float*       out = (float*)d_out + (size_t)c*2048*Dz;   // OUTPUT IS F32 (reference dtype)
    gemm_kernel<0><<<dim3(64,32), 256, 0, stream>>>(h2c, Wgate, nullptr, gateC, 2048, Iz, Dz);
    gemm_kernel<3><<<dim3(64,32), 256, 0, stream>>>(h2c, Wup, gateC, gateC, 2048, Iz, Dz);
    gemm_kernel<1><<<dim3(16,32), 256, 0, stream>>>(gateC, Wdown, x2c, out, 2048, Dz, Iz);
  }
}

// Round 5
// 5573.463 us; speedup vs baseline: 1.7159x; 1.7159x over previous
//
#include <hip/hip_runtime.h>
#include <hip/hip_bf16.h>

typedef __hip_bfloat16 bf16;
typedef unsigned short us;
typedef short short8v __attribute__((ext_vector_type(8)));
typedef float f32x4 __attribute__((ext_vector_type(4)));
typedef __attribute__((address_space(3))) unsigned int lds_u32;
typedef __attribute__((address_space(1))) const unsigned int glb_u32;

#define GLOAD16(gp, lp) __builtin_amdgcn_global_load_lds((glb_u32*)(gp), (lds_u32*)(lp), 16, 0, 0)

#define Bz 4
#define Tz 2048
#define Dz 1024
#define Hz 8
#define DKz 96
#define DVz 192
#define KDz 768
#define VDz 1536
#define Iz 4096
#define BTz (Bz*Tz)

static __device__ __forceinline__ float us2f(us s){
  return __uint_as_float(((unsigned)s) << 16);
}
static __device__ __forceinline__ us f2bs(float f){
  bf16 t = __float2bfloat16(f);
  return *(us*)&t;
}
static __device__ __forceinline__ float sigmoidf_(float x){ return 1.f/(1.f+expf(-x)); }
static __device__ __forceinline__ float siluf_(float x){ return x*sigmoidf_(x); }
static __device__ __forceinline__ float bcastf(float x, int l){
  return __int_as_float(__builtin_amdgcn_readlane(__float_as_int(x), l));
}

// ---------------- weight prep: W[K,N] f32 -> WT[N,K] bf16 ----------------
__global__ __launch_bounds__(256) void wprep_kernel(
    const float* __restrict__ Wsrc, us* __restrict__ WTdst, int K, int N)
{
  __shared__ float t[32][33];
  const int k0 = blockIdx.x*32, n0 = blockIdx.y*32;
  const int c = threadIdx.x & 31, r8 = threadIdx.x >> 5;
  #pragma unroll
  for (int i=0;i<4;i++){
    const int r = r8 + i*8;
    t[r][c] = Wsrc[(size_t)(k0+r)*N + n0 + c];
  }
  __syncthreads();
  #pragma unroll
  for (int i=0;i<4;i++){
    const int r = r8 + i*8;
    WTdst[(size_t)(n0+r)*K + k0 + c] = f2bs(t[c][r]);
  }
}

// ---------------- RMSNorm (f32 in -> bf16 out, f32 weights) ----------------
__global__ __launch_bounds__(256) void rmsnorm_kernel(
    const float* __restrict__ x, const float* __restrict__ w, bf16* __restrict__ out)
{
  const int row = blockIdx.x;
  const float* xr = x + (size_t)row*Dz;
  const int i0 = threadIdx.x*4;
  float4 xv = *(const float4*)(xr + i0);
  float ss = xv.x*xv.x+xv.y*xv.y+xv.z*xv.z+xv.w*xv.w;
  #pragma unroll
  for (int off=32; off>=1; off>>=1) ss += __shfl_xor(ss, off);
  __shared__ float red[4];
  if ((threadIdx.x&63)==0) red[threadIdx.x>>6] = ss;
  __syncthreads();
  ss = red[0]+red[1]+red[2]+red[3];
  const float inv = rsqrtf(ss*(1.f/Dz) + 1e-6f);
  float4 wv = *(const float4*)(w + i0);
  ushort4 ov;
  ov.x=f2bs(xv.x*inv*wv.x); ov.y=f2bs(xv.y*inv*wv.y);
  ov.z=f2bs(xv.z*inv*wv.z); ov.w=f2bs(xv.w*inv*wv.w);
  *(ushort4*)((us*)out + (size_t)row*Dz + i0) = ov;
}

// ------------- MFMA GEMM: C[M,N] = A[M,K](bf16) @ BT[N,K](bf16)^T (+res) -------------
// Tile 128x128, BK=64, 256 threads (4 waves, 2x2), mfma_f32_16x16x32_bf16.
// MODE 0: write bf16.  MODE 1: write f32 + f32 residual.  MODE 3: bf16 = silu(bf16 res)*acc.
template<int MODE>
__global__ __launch_bounds__(256, 2) void mgemm_kernel(
    const bf16* __restrict__ A, const us* __restrict__ BT,
    const void* __restrict__ res, void* __restrict__ Cout,
    int M, int N, int K)
{
  __shared__ us As[128*64];
  __shared__ us Bs[128*64];
  const int m0 = blockIdx.y*128, n0 = blockIdx.x*128;
  const int tid = threadIdx.x;
  const int wid = tid >> 6, lane = tid & 63;
  const int wr = wid >> 1, wc = wid & 1;
  const int fq = lane >> 4, fr = lane & 15;

  const us* Ab = (const us*)A + (size_t)(m0 + (tid>>3))*K + (tid&7)*8;
  const us* Bb = BT + (size_t)(n0 + (tid>>3))*K + (tid&7)*8;
  char* AsB = (char*)As;
  char* BsB = (char*)Bs;
  const int ldsoff = wid*1024;

  f32x4 acc[4][4] = {};
  const int nk = K >> 6;
  for (int kt = 0; kt < nk; ++kt){
    const int kb = kt*64;
    #pragma unroll
    for (int i=0;i<4;i++){
      GLOAD16(Ab + (size_t)(32*i)*K + kb, AsB + ldsoff + i*4096);
      GLOAD16(Bb + (size_t)(32*i)*K + kb, BsB + ldsoff + i*4096);
    }
    __syncthreads();
    #pragma unroll
    for (int ks=0; ks<2; ks++){
      short8v af[4], bf[4];
      #pragma unroll
      for (int r=0;r<4;r++)
        af[r] = *(const short8v*)&As[(wr*64 + r*16 + fr)*64 + ks*32 + fq*8];
      #pragma unroll
      for (int c=0;c<4;c++)
        bf[c] = *(const short8v*)&Bs[(wc*64 + c*16 + fr)*64 + ks*32 + fq*8];
      #pragma unroll
      for (int r=0;r<4;r++)
        #pragma unroll
        for (int c=0;c<4;c++)
          acc[r][c] = __builtin_amdgcn_mfma_f32_16x16x32_bf16(af[r], bf[c], acc[r][c], 0, 0, 0);
    }
    __syncthreads();
  }
  #pragma unroll
  for (int r=0;r<4;r++){
    #pragma unroll
    for (int c=0;c<4;c++){
      const int col = n0 + wc*64 + c*16 + fr;
      #pragma unroll
      for (int jj=0;jj<4;jj++){
        const int row = m0 + wr*64 + r*16 + fq*4 + jj;
        const size_t idx = (size_t)row*N + col;
        const float a = acc[r][c][jj];
        if (MODE==0){
          ((us*)Cout)[idx] = f2bs(a);
        } else if (MODE==1){
          ((float*)Cout)[idx] = a + ((const float*)res)[idx];
        } else {
          ((us*)Cout)[idx] = f2bs(siluf_(us2f(((const us*)res)[idx]))*a);
        }
      }
    }
  }
}

// ---------------- beta / exp(g) projections (N=8 each, f32 weights) ----------------
__global__ __launch_bounds__(256) void beta_g_kernel(
    const bf16* __restrict__ hh, const float* __restrict__ Wb, const float* __restrict__ Wa,
    const float* __restrict__ A_log, const float* __restrict__ dt_bias,
    float* __restrict__ beta, float* __restrict__ eg)
{
  const int row = blockIdx.x;
  const us* hr = (const us*)hh + (size_t)row*Dz;
  float ab[8]={0,0,0,0,0,0,0,0}, aa[8]={0,0,0,0,0,0,0,0};
  for (int kk=threadIdx.x; kk<Dz; kk+=256){
    const float hv = us2f(hr[kk]);
    float4 b0 = *(const float4*)(Wb + kk*8);
    float4 b1 = *(const float4*)(Wb + kk*8 + 4);
    float4 a0 = *(const float4*)(Wa + kk*8);
    float4 a1 = *(const float4*)(Wa + kk*8 + 4);
    ab[0]=fmaf(hv,b0.x,ab[0]); ab[1]=fmaf(hv,b0.y,ab[1]);
    ab[2]=fmaf(hv,b0.z,ab[2]); ab[3]=fmaf(hv,b0.w,ab[3]);
    ab[4]=fmaf(hv,b1.x,ab[4]); ab[5]=fmaf(hv,b1.y,ab[5]);
    ab[6]=fmaf(hv,b1.z,ab[6]); ab[7]=fmaf(hv,b1.w,ab[7]);
    aa[0]=fmaf(hv,a0.x,aa[0]); aa[1]=fmaf(hv,a0.y,aa[1]);
    aa[2]=fmaf(hv,a0.z,aa[2]); aa[3]=fmaf(hv,a0.w,aa[3]);
    aa[4]=fmaf(hv,a1.x,aa[4]); aa[5]=fmaf(hv,a1.y,aa[5]);
    aa[6]=fmaf(hv,a1.z,aa[6]); aa[7]=fmaf(hv,a1.w,aa[7]);
  }
  #pragma unroll
  for (int off=32; off>=1; off>>=1){
    #pragma unroll
    for (int n=0;n<8;n++){ ab[n]+=__shfl_xor(ab[n],off); aa[n]+=__shfl_xor(aa[n],off); }
  }
  __shared__ float red[4][16];
  const int wv = threadIdx.x>>6, ln = threadIdx.x&63;
  if (ln==0){
    #pragma unroll
    for (int n=0;n<8;n++){ red[wv][n]=ab[n]; red[wv][8+n]=aa[n]; }
  }
  __syncthreads();
  if (threadIdx.x < 8){
    const int n = threadIdx.x;
    float sb = red[0][n]+red[1][n]+red[2][n]+red[3][n];
    float sa = red[0][8+n]+red[1][8+n]+red[2][8+n]+red[3][8+n];
    beta[(size_t)row*Hz+n] = 1.f/(1.f+expf(-sb));
    float xx = sa + dt_bias[n];
    float sp = (xx > 20.f) ? xx : log1pf(expf(xx));
    eg[(size_t)row*Hz+n] = expf(-expf(A_log[n])*sp);
  }
}

// ------------- conv(K=4)+SiLU+l2norm SCALES for q,k (parallel over B*T*H) -------------
__global__ __launch_bounds__(64) void conv_inv_kernel(
    const bf16* __restrict__ preq, const bf16* __restrict__ prek,
    const float* __restrict__ wqc, const float* __restrict__ wkc,
    float* __restrict__ invq, float* __restrict__ invk)
{
  const int idx = blockIdx.x; const int h = idx & 7; const int bt = idx >> 3;
  const int t = bt & (Tz-1);
  const int lane = threadIdx.x;
  const us* Q = (const us*)preq;
  const us* K = (const us*)prek;
  const int c0 = h*DKz + lane, c1 = c0 + 64;
  const bool hi = lane < 32;
  float yq0=0.f, yq1=0.f, yk0=0.f, yk1=0.f;
  #pragma unroll
  for (int i=0;i<4;i++){
    const int ti = t - 3 + i;
    if (ti >= 0){
      const size_t rowb = (size_t)(bt-3+i)*KDz;
      yq0 = fmaf(us2f(Q[rowb + c0]), wqc[c0*4+i], yq0);
      yk0 = fmaf(us2f(K[rowb + c0]), wkc[c0*4+i], yk0);
      if (hi){
        yq1 = fmaf(us2f(Q[rowb + c1]), wqc[c1*4+i], yq1);
        yk1 = fmaf(us2f(K[rowb + c1]), wkc[c1*4+i], yk1);
      }
    }
  }
  yq0 = siluf_(yq0); yk0 = siluf_(yk0);
  yq1 = hi ? siluf_(yq1) : 0.f;
  yk1 = hi ? siluf_(yk1) : 0.f;
  float ssq = yq0*yq0 + yq1*yq1;
  float ssk = yk0*yk0 + yk1*yk1;
  #pragma unroll
  for (int off=32; off>=1; off>>=1){ ssq += __shfl_xor(ssq,off); ssk += __shfl_xor(ssk,off); }
  if (lane == 0){
    invq[(size_t)bt*Hz + h] = rsqrtf(ssq + 1e-6f) * 0.10206207262f;  // * dk^-0.5
    invk[(size_t)bt*Hz + h] = rsqrtf(ssk + 1e-6f);
  }
}

// ---------------- fused conv+SiLU(+precomputed l2 scales) + gated delta-rule scan ------
// 1 block per (b,h), 192 threads; thread j owns S column j (96 f32 regs).
// Pipelined: step t's S-update runs while step t+1's loads are in flight;
// step t+1's conv/silu/normalize happens after the update (off the critical chain).
__global__ __launch_bounds__(192, 1) void scan_kernel(
    const bf16* __restrict__ preq, const bf16* __restrict__ prek, const bf16* __restrict__ prev,
    const float* __restrict__ wqc, const float* __restrict__ wkc, const float* __restrict__ wvc,
    const float* __restrict__ eg_, const float* __restrict__ beta,
    const float* __restrict__ invq_, const float* __restrict__ invk_,
    bf16* __restrict__ o)
{
  const int bh = blockIdx.x; const int b = bh >> 3, h = bh & 7;
  const int j = threadIdx.x, lane = threadIdx.x & 63;
  const bool hi = lane < 32;
  const int kc0 = h*DKz + lane, kc1 = kc0 + 64;
  const int vc  = h*DVz + j;

  float wq0[4], wq1[4], wk0[4], wk1[4], wv[4];
  #pragma unroll
  for (int i=0;i<4;i++){
    wq0[i] = wqc[kc0*4+i];
    wk0[i] = wkc[kc0*4+i];
    wv[i]  = wvc[vc*4+i];
    wq1[i] = hi ? wqc[kc1*4+i] : 0.f;
    wk1[i] = hi ? wkc[kc1*4+i] : 0.f;
  }

  const us* QP = (const us*)preq + (size_t)b*Tz*KDz;
  const us* KP = (const us*)prek + (size_t)b*Tz*KDz;
  const us* VP = (const us*)prev + (size_t)b*Tz*VDz;
  us* op = (us*)o + (size_t)b*Tz*VDz + vc;
  const float* egp = eg_   + (size_t)b*Tz*Hz + h;
  const float* bp  = beta  + (size_t)b*Tz*Hz + h;
  const float* iqp = invq_ + (size_t)b*Tz*Hz + h;
  const float* ikp = invk_ + (size_t)b*Tz*Hz + h;

  float S[96];
  #pragma unroll
  for (int i=0;i<96;i++) S[i]=0.f;

  // conv rings (t-3, t-2, t-1), zero = causal pad
  float q0a=0,q0b=0,q0c=0, q1a=0,q1b=0,q1c=0;
  float k0a=0,k0b=0,k0c=0, k1a=0,k1b=0,k1c=0;
  float va=0,vb=0,vcz=0;

  // raw(0)
  float rq0 = us2f(QP[kc0]), rq1 = hi? us2f(QP[kc1]) : 0.f;
  float rk0 = us2f(KP[kc0]), rk1 = hi? us2f(KP[kc1]) : 0.f;
  float rv  = us2f(VP[vc]);
  float reg = egp[0], rb = bp[0], riq = iqp[0], rik = ikp[0];

  // normalized cur(0): rings are zero so conv = raw*w3
  float cq0, cq1, ck0, ck1, cv, ceg, cb;
  {
    float yq0 = siluf_(rq0*wq0[3]);
    float yq1 = hi ? siluf_(rq1*wq1[3]) : 0.f;
    float yk0 = siluf_(rk0*wk0[3]);
    float yk1 = hi ? siluf_(rk1*wk1[3]) : 0.f;
    cv = siluf_(rv*wv[3]);
    cq0 = yq0*riq; cq1 = yq1*riq; ck0 = yk0*rik; ck1 = yk1*rik;
    ceg = reg; cb = rb;
    q0c = rq0; q1c = rq1; k0c = rk0; k1c = rk1; vcz = rv;
  }

  for (int t=0; t<Tz; t++){
    const bool more = (t+1 < Tz);
    if (more){
      const size_t r = (size_t)(t+1);
      rq0 = us2f(QP[r*KDz+kc0]); rq1 = hi? us2f(QP[r*KDz+kc1]) : 0.f;
      rk0 = us2f(KP[r*KDz+kc0]); rk1 = hi? us2f(KP[r*KDz+kc1]) : 0.f;
      rv  = us2f(VP[r*VDz+vc]);
      reg = egp[r*Hz]; rb = bp[r*Hz]; riq = iqp[r*Hz]; rik = ikp[r*Hz];
    }
    // ---- S-update for step t (critical path) ----
    const float eg = ceg;
    float a4[4]={0.f,0.f,0.f,0.f};
    #pragma unroll
    for (int kk=0;kk<96;kk++)
      a4[kk&3] = fmaf(bcastf(kk<64?ck0:ck1, kk&63), S[kk], a4[kk&3]);
    const float vold = (a4[0]+a4[1])+(a4[2]+a4[3]);
    const float delta = (cv - eg*vold)*cb;
    float ob[4]={0.f,0.f,0.f,0.f};
    #pragma unroll
    for (int kk=0;kk<96;kk++){
      const float kb = bcastf(kk<64?ck0:ck1, kk&63);
      const float qb = bcastf(kk<64?cq0:cq1, kk&63);
      const float s = fmaf(eg, S[kk], kb*delta);
      S[kk] = s;
      ob[kk&3] = fmaf(qb, s, ob[kk&3]);
    }
    op[(size_t)t*VDz] = f2bs((ob[0]+ob[1])+(ob[2]+ob[3]));
    // ---- normalize step t+1 (off critical path) ----
    if (more){
      float yq0 = fmaf(q0a,wq0[0], fmaf(q0b,wq0[1], fmaf(q0c,wq0[2], rq0*wq0[3])));
      float yq1 = fmaf(q1a,wq1[0], fmaf(q1b,wq1[1], fmaf(q1c,wq1[2], rq1*wq1[3])));
      float yk0 = fmaf(k0a,wk0[0], fmaf(k0b,wk0[1], fmaf(k0c,wk0[2], rk0*wk0[3])));
      float yk1 = fmaf(k1a,wk1[0], fmaf(k1b,wk1[1], fmaf(k1c,wk1[2], rk1*wk1[3])));
      float yv  = fmaf(va ,wv[0],  fmaf(vb ,wv[1],  fmaf(vcz,wv[2],  rv *wv[3])));
      q0a=q0b; q0b=q0c; q0c=rq0;   q1a=q1b; q1b=q1c; q1c=rq1;
      k0a=k0b; k0b=k0c; k0c=rk0;   k1a=k1b; k1b=k1c; k1c=rk1;
      va=vb; vb=vcz; vcz=rv;
      yq0 = siluf_(yq0); yq1 = hi? siluf_(yq1) : 0.f;
      yk0 = siluf_(yk0); yk1 = hi? siluf_(yk1) : 0.f;
      cv = siluf_(yv);
      cq0 = yq0*riq; cq1 = yq1*riq; ck0 = yk0*rik; ck1 = yk1*rik;
      ceg = reg; cb = rb;
    }
  }
}

// ---------------- output gate: rmsnorm_dv(o) * silu(gout) ----------------
__global__ __launch_bounds__(64) void gate_out_kernel(
    const bf16* __restrict__ o, const bf16* __restrict__ gout,
    const float* __restrict__ onw, bf16* __restrict__ og)
{
  const size_t base = (size_t)blockIdx.x * DVz;
  const int lane = threadIdx.x;
  const us* O = (const us*)o;
  float x0 = us2f(O[base+lane]), x1 = us2f(O[base+64+lane]), x2 = us2f(O[base+128+lane]);
  float ss = x0*x0 + x1*x1 + x2*x2;
  #pragma unroll
  for (int off=32; off>=1; off>>=1) ss += __shfl_xor(ss, off);
  const float inv = rsqrtf(ss*(1.f/DVz) + 1e-6f);
  const us* G = (const us*)gout;
  us* OG = (us*)og;
  float xs[3] = {x0, x1, x2};
  #pragma unroll
  for (int i=0;i<3;i++){
    const int c = lane + 64*i;
    const float gv = us2f(G[base+c]);
    OG[base+c] = f2bs(xs[i]*inv*onw[c] * siluf_(gv));
  }
}

extern "C" void kernel_launch(void* const* d_in, const int* in_sizes, int n_in,
                              void* d_out, int out_size, void* d_ws, size_t ws_size,
                              hipStream_t stream) {
  const float* x        = (const float*)d_in[0];
  const float* Wq       = (const float*)d_in[1];
  const float* Wk       = (const float*)d_in[2];
  const float* Wv       = (const float*)d_in[3];
  const float* Wb       = (const float*)d_in[4];
  const float* Wa       = (const float*)d_in[5];
  const float* A_log    = (const float*)d_in[6];
  const float* dt_bias  = (const float*)d_in[7];
  const float* conv_q_w = (const float*)d_in[8];
  const float* conv_k_w = (const float*)d_in[9];
  const float* conv_v_w = (const float*)d_in[10];
  const float* Wg       = (const float*)d_in[11];
  const float* onorm_w  = (const float*)d_in[12];
  const float* Wo       = (const float*)d_in[13];
  const float* norm1_w  = (const float*)d_in[14];
  const float* norm2_w  = (const float*)d_in[15];
  const float* Wgate    = (const float*)d_in[16];
  const float* Wup      = (const float*)d_in[17];
  const float* Wdown    = (const float*)d_in[18];

  char* W = (char*)d_ws;
  // bf16-transposed weights (rewritten every launch; deterministic)
  us* WoT    = (us*)(W + 0);           // [1024,1536]  3.15 MB
  us* WgateT = (us*)(W + 3145728);     // [4096,1024]  8.39 MB
  us* WupT   = (us*)(W + 11534336);    // [4096,1024]  8.39 MB
  us* WdownT = (us*)(W + 19922944);    // [1024,4096]  8.39 MB
  us* WqT    = (us*)(W + 28311552);    // [768,1024]   1.57 MB (dead after proj)
  us* WkT    = (us*)(W + 29884416);    // [768,1024]
  us* WvT    = (us*)(W + 31457280);    // [1536,1024]  3.15 MB
  us* WgT    = (us*)(W + 34603008);    // [1536,1024]  -> ends 37,748,736
  // activations
  bf16*  h_    = (bf16*) (W + 37748736);   // [8192,1024]; dead after gout GEMM
  bf16*  preq  = (bf16*) (W + 54525952);   // [8192,768];  dead after scan
  bf16*  prek  = (bf16*) (W + 67108864);   // [8192,768];  dead after scan
  bf16*  prev  = (bf16*) (W + 79691776);   // [8192,1536]; dead after scan
  float* beta_ = (float*)(W + 104857600);  // [8192,8]
  float* eg_   = (float*)(W + 105119744);  // [8192,8]
  float* invq_ = (float*)(W + 105381888);  // [8192,8]
  float* invk_ = (float*)(W + 105644032);  // [8192,8]
  bf16*  gout  = (bf16*) (W + 105906176);  // [8192,1536]; -> ends 131,072,000 (PEAK)
  // aliases over dead regions
  bf16*  o_    = (bf16*) (W + 28311552);   // [8192,1536] over WqT..WgT+h_ (dead pre-scan)
  bf16*  og    = (bf16*) (W + 54525952);   // [8192,1536] over preq+prek (dead post-scan)
  float* x2    = (float*)(W + 79691776);   // [8192,1024] f32 over prev+scalars+gout-head
  bf16*  h2    = (bf16*) (W + 113246208);  // [8192,1024] over gout tail (dead)
  bf16*  gateC = (bf16*) (W + 28311552);   // [2048,4096] over o_ region (dead post-gating)

  // 0. weight prep (transpose + f32->bf16)
  wprep_kernel<<<dim3(48,32),  256, 0, stream>>>(Wo,    WoT,    1536, 1024);
  wprep_kernel<<<dim3(32,128), 256, 0, stream>>>(Wgate, WgateT, 1024, 4096);
  wprep_kernel<<<dim3(32,128), 256, 0, stream>>>(Wup,   WupT,   1024, 4096);
  wprep_kernel<<<dim3(128,32), 256, 0, stream>>>(Wdown, WdownT, 4096, 1024);
  wprep_kernel<<<dim3(32,24),  256, 0, stream>>>(Wq,    WqT,    1024, 768);
  wprep_kernel<<<dim3(32,24),  256, 0, stream>>>(Wk,    WkT,    1024, 768);
  wprep_kernel<<<dim3(32,48),  256, 0, stream>>>(Wv,    WvT,    1024, 1536);
  wprep_kernel<<<dim3(32,48),  256, 0, stream>>>(Wg,    WgT,    1024, 1536);
  // 1. pre-norm
  rmsnorm_kernel<<<BTz, 256, 0, stream>>>(x, norm1_w, h_);
  // 2. projections + beta/eg
  mgemm_kernel<0><<<dim3(6,64),  256, 0, stream>>>(h_, WqT, nullptr, preq, BTz, KDz, Dz);
  mgemm_kernel<0><<<dim3(6,64),  256, 0, stream>>>(h_, WkT, nullptr, prek, BTz, KDz, Dz);
  mgemm_kernel<0><<<dim3(12,64), 256, 0, stream>>>(h_, WvT, nullptr, prev, BTz, VDz, Dz);
  beta_g_kernel<<<BTz, 256, 0, stream>>>(h_, Wb, Wa, A_log, dt_bias, beta_, eg_);
  mgemm_kernel<0><<<dim3(12,64), 256, 0, stream>>>(h_, WgT, nullptr, gout, BTz, VDz, Dz);
  // 3. l2norm scales, then fused conv+scan
  conv_inv_kernel<<<BTz*Hz, 64, 0, stream>>>(preq, prek, conv_q_w, conv_k_w, invq_, invk_);
  scan_kernel<<<Bz*Hz, 192, 0, stream>>>(preq, prek, prev, conv_q_w, conv_k_w, conv_v_w,
                                         eg_, beta_, invq_, invk_, o_);
  // 4. output gating + Wo projection with residual
  gate_out_kernel<<<BTz*Hz, 64, 0, stream>>>(o_, gout, onorm_w, og);
  mgemm_kernel<1><<<dim3(8,64), 256, 0, stream>>>(og, WoT, x, x2, BTz, Dz, VDz);
  // 5. MLP, chunked over 4 x 2048 rows
  rmsnorm_kernel<<<BTz, 256, 0, stream>>>(x2, norm2_w, h2);
  for (int c = 0; c < 4; c++){
    const bf16*  h2c = h2 + (size_t)c*2048*Dz;
    const float* x2c = x2 + (size_t)c*2048*Dz;
    float*       out = (float*)d_out + (size_t)c*2048*Dz;
    mgemm_kernel<0><<<dim3(32,16), 256, 0, stream>>>(h2c, WgateT, nullptr, gateC, 2048, Iz, Dz);
    mgemm_kernel<3><<<dim3(32,16), 256, 0, stream>>>(h2c, WupT, gateC, gateC, 2048, Iz, Dz);
    mgemm_kernel<1><<<dim3(8,16),  256, 0, stream>>>(gateC, WdownT, x2c, out, 2048, Dz, Iz);
  }
}

// Round 6
// 3533.740 us; speedup vs baseline: 2.7064x; 1.5772x over previous
//
#include <hip/hip_runtime.h>
#include <hip/hip_bf16.h>

typedef __hip_bfloat16 bf16;
typedef unsigned short us;
typedef short short8v __attribute__((ext_vector_type(8)));
typedef float f32x4 __attribute__((ext_vector_type(4)));
typedef __attribute__((address_space(3))) unsigned int lds_u32;
typedef __attribute__((address_space(1))) const unsigned int glb_u32;

#define GLOAD16(gp, lp) __builtin_amdgcn_global_load_lds((glb_u32*)(gp), (lds_u32*)(lp), 16, 0, 0)

#define Bz 4
#define Tz 2048
#define Dz 1024
#define Hz 8
#define DKz 96
#define DVz 192
#define KDz 768
#define VDz 1536
#define Iz 4096
#define BTz (Bz*Tz)

static __device__ __forceinline__ float us2f(us s){
  return __uint_as_float(((unsigned)s) << 16);
}
static __device__ __forceinline__ us f2bs(float f){
  bf16 t = __float2bfloat16(f);
  return *(us*)&t;
}
static __device__ __forceinline__ float sigmoidf_(float x){ return 1.f/(1.f+expf(-x)); }
static __device__ __forceinline__ float siluf_(float x){ return x*sigmoidf_(x); }

// ---------------- weight prep: W[K,N] f32 -> WT[N,K] bf16 ----------------
__global__ __launch_bounds__(256) void wprep_kernel(
    const float* __restrict__ Wsrc, us* __restrict__ WTdst, int K, int N)
{
  __shared__ float t[32][33];
  const int k0 = blockIdx.x*32, n0 = blockIdx.y*32;
  const int c = threadIdx.x & 31, r8 = threadIdx.x >> 5;
  #pragma unroll
  for (int i=0;i<4;i++){
    const int r = r8 + i*8;
    t[r][c] = Wsrc[(size_t)(k0+r)*N + n0 + c];
  }
  __syncthreads();
  #pragma unroll
  for (int i=0;i<4;i++){
    const int r = r8 + i*8;
    WTdst[(size_t)(n0+r)*K + k0 + c] = f2bs(t[c][r]);
  }
}

// ---------------- RMSNorm (f32 in -> bf16 out, f32 weights) ----------------
__global__ __launch_bounds__(256) void rmsnorm_kernel(
    const float* __restrict__ x, const float* __restrict__ w, bf16* __restrict__ out)
{
  const int row = blockIdx.x;
  const float* xr = x + (size_t)row*Dz;
  const int i0 = threadIdx.x*4;
  float4 xv = *(const float4*)(xr + i0);
  float ss = xv.x*xv.x+xv.y*xv.y+xv.z*xv.z+xv.w*xv.w;
  #pragma unroll
  for (int off=32; off>=1; off>>=1) ss += __shfl_xor(ss, off);
  __shared__ float red[4];
  if ((threadIdx.x&63)==0) red[threadIdx.x>>6] = ss;
  __syncthreads();
  ss = red[0]+red[1]+red[2]+red[3];
  const float inv = rsqrtf(ss*(1.f/Dz) + 1e-6f);
  float4 wv = *(const float4*)(w + i0);
  ushort4 ov;
  ov.x=f2bs(xv.x*inv*wv.x); ov.y=f2bs(xv.y*inv*wv.y);
  ov.z=f2bs(xv.z*inv*wv.z); ov.w=f2bs(xv.w*inv*wv.w);
  *(ushort4*)((us*)out + (size_t)row*Dz + i0) = ov;
}

// ------------- MFMA GEMM: C[M,N] = A[M,K](bf16) @ BT[N,K](bf16)^T (+res) -------------
// Tile 128x128, BK=64, 256 threads (4 waves, 2x2), mfma_f32_16x16x32_bf16.
// MODE 0: write bf16.  MODE 1: write f32 + f32 residual.  MODE 3: bf16 = silu(bf16 res)*acc.
template<int MODE>
__global__ __launch_bounds__(256, 2) void mgemm_kernel(
    const bf16* __restrict__ A, const us* __restrict__ BT,
    const void* __restrict__ res, void* __restrict__ Cout,
    int M, int N, int K)
{
  __shared__ us As[128*64];
  __shared__ us Bs[128*64];
  const int m0 = blockIdx.y*128, n0 = blockIdx.x*128;
  const int tid = threadIdx.x;
  const int wid = tid >> 6, lane = tid & 63;
  const int wr = wid >> 1, wc = wid & 1;
  const int fq = lane >> 4, fr = lane & 15;

  const us* Ab = (const us*)A + (size_t)(m0 + (tid>>3))*K + (tid&7)*8;
  const us* Bb = BT + (size_t)(n0 + (tid>>3))*K + (tid&7)*8;
  char* AsB = (char*)As;
  char* BsB = (char*)Bs;
  const int ldsoff = wid*1024;

  f32x4 acc[4][4] = {};
  const int nk = K >> 6;
  for (int kt = 0; kt < nk; ++kt){
    const int kb = kt*64;
    #pragma unroll
    for (int i=0;i<4;i++){
      GLOAD16(Ab + (size_t)(32*i)*K + kb, AsB + ldsoff + i*4096);
      GLOAD16(Bb + (size_t)(32*i)*K + kb, BsB + ldsoff + i*4096);
    }
    __syncthreads();
    #pragma unroll
    for (int ks=0; ks<2; ks++){
      short8v af[4], bf[4];
      #pragma unroll
      for (int r=0;r<4;r++)
        af[r] = *(const short8v*)&As[(wr*64 + r*16 + fr)*64 + ks*32 + fq*8];
      #pragma unroll
      for (int c=0;c<4;c++)
        bf[c] = *(const short8v*)&Bs[(wc*64 + c*16 + fr)*64 + ks*32 + fq*8];
      #pragma unroll
      for (int r=0;r<4;r++)
        #pragma unroll
        for (int c=0;c<4;c++)
          acc[r][c] = __builtin_amdgcn_mfma_f32_16x16x32_bf16(af[r], bf[c], acc[r][c], 0, 0, 0);
    }
    __syncthreads();
  }
  #pragma unroll
  for (int r=0;r<4;r++){
    #pragma unroll
    for (int c=0;c<4;c++){
      const int col = n0 + wc*64 + c*16 + fr;
      #pragma unroll
      for (int jj=0;jj<4;jj++){
        const int row = m0 + wr*64 + r*16 + fq*4 + jj;
        const size_t idx = (size_t)row*N + col;
        const float a = acc[r][c][jj];
        if (MODE==0){
          ((us*)Cout)[idx] = f2bs(a);
        } else if (MODE==1){
          ((float*)Cout)[idx] = a + ((const float*)res)[idx];
        } else {
          ((us*)Cout)[idx] = f2bs(siluf_(us2f(((const us*)res)[idx]))*a);
        }
      }
    }
  }
}

// ---------------- beta / exp(g) projections (N=8 each, f32 weights) ----------------
__global__ __launch_bounds__(256) void beta_g_kernel(
    const bf16* __restrict__ hh, const float* __restrict__ Wb, const float* __restrict__ Wa,
    const float* __restrict__ A_log, const float* __restrict__ dt_bias,
    float* __restrict__ beta, float* __restrict__ eg)
{
  const int row = blockIdx.x;
  const us* hr = (const us*)hh + (size_t)row*Dz;
  float ab[8]={0,0,0,0,0,0,0,0}, aa[8]={0,0,0,0,0,0,0,0};
  for (int kk=threadIdx.x; kk<Dz; kk+=256){
    const float hv = us2f(hr[kk]);
    float4 b0 = *(const float4*)(Wb + kk*8);
    float4 b1 = *(const float4*)(Wb + kk*8 + 4);
    float4 a0 = *(const float4*)(Wa + kk*8);
    float4 a1 = *(const float4*)(Wa + kk*8 + 4);
    ab[0]=fmaf(hv,b0.x,ab[0]); ab[1]=fmaf(hv,b0.y,ab[1]);
    ab[2]=fmaf(hv,b0.z,ab[2]); ab[3]=fmaf(hv,b0.w,ab[3]);
    ab[4]=fmaf(hv,b1.x,ab[4]); ab[5]=fmaf(hv,b1.y,ab[5]);
    ab[6]=fmaf(hv,b1.z,ab[6]); ab[7]=fmaf(hv,b1.w,ab[7]);
    aa[0]=fmaf(hv,a0.x,aa[0]); aa[1]=fmaf(hv,a0.y,aa[1]);
    aa[2]=fmaf(hv,a0.z,aa[2]); aa[3]=fmaf(hv,a0.w,aa[3]);
    aa[4]=fmaf(hv,a1.x,aa[4]); aa[5]=fmaf(hv,a1.y,aa[5]);
    aa[6]=fmaf(hv,a1.z,aa[6]); aa[7]=fmaf(hv,a1.w,aa[7]);
  }
  #pragma unroll
  for (int off=32; off>=1; off>>=1){
    #pragma unroll
    for (int n=0;n<8;n++){ ab[n]+=__shfl_xor(ab[n],off); aa[n]+=__shfl_xor(aa[n],off); }
  }
  __shared__ float red[4][16];
  const int wv = threadIdx.x>>6, ln = threadIdx.x&63;
  if (ln==0){
    #pragma unroll
    for (int n=0;n<8;n++){ red[wv][n]=ab[n]; red[wv][8+n]=aa[n]; }
  }
  __syncthreads();
  if (threadIdx.x < 8){
    const int n = threadIdx.x;
    float sb = red[0][n]+red[1][n]+red[2][n]+red[3][n];
    float sa = red[0][8+n]+red[1][8+n]+red[2][8+n]+red[3][8+n];
    beta[(size_t)row*Hz+n] = 1.f/(1.f+expf(-sb));
    float xx = sa + dt_bias[n];
    float sp = (xx > 20.f) ? xx : log1pf(expf(xx));
    eg[(size_t)row*Hz+n] = expf(-expf(A_log[n])*sp);
  }
}

// ------------- conv(K=4)+SiLU+l2norm SCALES for q,k (parallel over B*T*H) -------------
__global__ __launch_bounds__(64) void conv_inv_kernel(
    const bf16* __restrict__ preq, const bf16* __restrict__ prek,
    const float* __restrict__ wqc, const float* __restrict__ wkc,
    float* __restrict__ invq, float* __restrict__ invk)
{
  const int idx = blockIdx.x; const int h = idx & 7; const int bt = idx >> 3;
  const int t = bt & (Tz-1);
  const int lane = threadIdx.x;
  const us* Q = (const us*)preq;
  const us* K = (const us*)prek;
  const int c0 = h*DKz + lane, c1 = c0 + 64;
  const bool hi = lane < 32;
  float yq0=0.f, yq1=0.f, yk0=0.f, yk1=0.f;
  #pragma unroll
  for (int i=0;i<4;i++){
    const int ti = t - 3 + i;
    if (ti >= 0){
      const size_t rowb = (size_t)(bt-3+i)*KDz;
      yq0 = fmaf(us2f(Q[rowb + c0]), wqc[c0*4+i], yq0);
      yk0 = fmaf(us2f(K[rowb + c0]), wkc[c0*4+i], yk0);
      if (hi){
        yq1 = fmaf(us2f(Q[rowb + c1]), wqc[c1*4+i], yq1);
        yk1 = fmaf(us2f(K[rowb + c1]), wkc[c1*4+i], yk1);
      }
    }
  }
  yq0 = siluf_(yq0); yk0 = siluf_(yk0);
  yq1 = hi ? siluf_(yq1) : 0.f;
  yk1 = hi ? siluf_(yk1) : 0.f;
  float ssq = yq0*yq0 + yq1*yq1;
  float ssk = yk0*yk0 + yk1*yk1;
  #pragma unroll
  for (int off=32; off>=1; off>>=1){ ssq += __shfl_xor(ssq,off); ssk += __shfl_xor(ssk,off); }
  if (lane == 0){
    invq[(size_t)bt*Hz + h] = rsqrtf(ssq + 1e-6f) * 0.10206207262f;  // * dk^-0.5
    invk[(size_t)bt*Hz + h] = rsqrtf(ssk + 1e-6f);
  }
}

// ---------------- gated delta-rule scan, 768 threads (12 waves) ----------------
// Block per (b,h). tid = j*4 + g: thread owns S[g*24 .. g*24+23][j] (24 f32 regs).
// Per step: 192 "writer" threads produce conv+silu+scaled k,q into LDS (double-buffered);
// all threads consume via broadcast ds_read_b128; cross-group reductions via shfl_xor(1,2).
__global__ __launch_bounds__(768, 3) void scan_kernel(
    const bf16* __restrict__ preq, const bf16* __restrict__ prek, const bf16* __restrict__ prev,
    const float* __restrict__ wqc, const float* __restrict__ wkc, const float* __restrict__ wvc,
    const float* __restrict__ eg_, const float* __restrict__ beta,
    const float* __restrict__ invq_, const float* __restrict__ invk_,
    bf16* __restrict__ o)
{
  const int bh = blockIdx.x; const int b = bh >> 3, h = bh & 7;
  const int tid = threadIdx.x;
  const int j = tid >> 2, g = tid & 3;
  const int vc = h*DVz + j;

  __shared__ float kq[2][192];   // [buf][96 k | 96 q]

  // v-conv weights for column j
  float wv[4];
  #pragma unroll
  for (int i=0;i<4;i++) wv[i] = wvc[vc*4+i];

  // writer role: tid<96 -> k channel tid; 96<=tid<192 -> q channel tid-96
  const bool isK = (tid < 96);
  const bool isQ = (tid >= 96) && (tid < 192);
  const int ch = isK ? tid : (tid - 96);
  const int kcol = h*DKz + ch;
  float wr[4] = {0.f,0.f,0.f,0.f};
  if (isK){
    #pragma unroll
    for (int i=0;i<4;i++) wr[i] = wkc[kcol*4+i];
  } else if (isQ){
    #pragma unroll
    for (int i=0;i<4;i++) wr[i] = wqc[kcol*4+i];
  }

  const us* QP = (const us*)preq + (size_t)b*Tz*KDz + kcol;
  const us* KP = (const us*)prek + (size_t)b*Tz*KDz + kcol;
  const us* VP = (const us*)prev + (size_t)b*Tz*VDz + vc;
  us* op = (us*)o + (size_t)b*Tz*VDz + vc;
  const float* egp = eg_   + (size_t)b*Tz*Hz + h;
  const float* bp  = beta  + (size_t)b*Tz*Hz + h;
  const float* iqp = invq_ + (size_t)b*Tz*Hz + h;
  const float* ikp = invk_ + (size_t)b*Tz*Hz + h;

  float S[24];
  #pragma unroll
  for (int m=0;m<24;m++) S[m]=0.f;

  // conv rings (t-3,t-2,t-1), zero = causal pad
  float ra=0.f, rb_=0.f, rc=0.f;     // writer ring (k or q raw)
  float va=0.f, vb=0.f, vcr=0.f;     // v raw ring

  // prologue: produce step-0 values
  float cv, ceg, cb;
  {
    if (isK){
      const float raw = us2f(KP[0]);
      kq[0][ch] = siluf_(raw*wr[3]) * ikp[0];
      rc = raw;
    } else if (isQ){
      const float raw = us2f(QP[0]);
      kq[0][96+ch] = siluf_(raw*wr[3]) * iqp[0];
      rc = raw;
    }
    const float rv = us2f(VP[0]);
    cv = siluf_(rv*wv[3]); vcr = rv;
    ceg = egp[0]; cb = bp[0];
  }
  __syncthreads();

  int p = 0;
  for (int t=0; t<Tz; t++){
    // 1. read this group's k,q slices (broadcast b128, conflict-free)
    float4 kv[6], qv[6];
    #pragma unroll
    for (int m=0;m<6;m++){
      kv[m] = *(const float4*)&kq[p][g*24 + m*4];
      qv[m] = *(const float4*)&kq[p][96 + g*24 + m*4];
    }
    // 2. partial v_old = k . S (pre-decay), reduce across g
    float a0=0.f,a1=0.f,a2=0.f,a3=0.f;
    #pragma unroll
    for (int m=0;m<6;m++){
      a0 = fmaf(kv[m].x, S[m*4+0], a0);
      a1 = fmaf(kv[m].y, S[m*4+1], a1);
      a2 = fmaf(kv[m].z, S[m*4+2], a2);
      a3 = fmaf(kv[m].w, S[m*4+3], a3);
    }
    float pv = (a0+a1)+(a2+a3);
    pv += __shfl_xor(pv, 1);
    pv += __shfl_xor(pv, 2);
    const float delta = (cv - ceg*pv)*cb;
    // 3. S update + o partial
    float o0=0.f,o1=0.f,o2=0.f,o3=0.f;
    #pragma unroll
    for (int m=0;m<6;m++){
      float s;
      s = fmaf(ceg, S[m*4+0], kv[m].x*delta); S[m*4+0]=s; o0 = fmaf(qv[m].x, s, o0);
      s = fmaf(ceg, S[m*4+1], kv[m].y*delta); S[m*4+1]=s; o1 = fmaf(qv[m].y, s, o1);
      s = fmaf(ceg, S[m*4+2], kv[m].z*delta); S[m*4+2]=s; o2 = fmaf(qv[m].z, s, o2);
      s = fmaf(ceg, S[m*4+3], kv[m].w*delta); S[m*4+3]=s; o3 = fmaf(qv[m].w, s, o3);
    }
    float po = (o0+o1)+(o2+o3);
    po += __shfl_xor(po, 1);
    po += __shfl_xor(po, 2);
    if (g == 0) op[(size_t)t*VDz] = f2bs(po);
    // 4. produce step t+1 into the other buffer
    if (t+1 < Tz){
      const size_t r = (size_t)(t+1);
      if (isK){
        const float raw = us2f(KP[r*KDz]);
        const float y = fmaf(ra,wr[0], fmaf(rb_,wr[1], fmaf(rc,wr[2], raw*wr[3])));
        ra=rb_; rb_=rc; rc=raw;
        kq[p^1][ch] = siluf_(y) * ikp[r*Hz];
      } else if (isQ){
        const float raw = us2f(QP[r*KDz]);
        const float y = fmaf(ra,wr[0], fmaf(rb_,wr[1], fmaf(rc,wr[2], raw*wr[3])));
        ra=rb_; rb_=rc; rc=raw;
        kq[p^1][96+ch] = siluf_(y) * iqp[r*Hz];
      }
      const float rv = us2f(VP[r*VDz]);
      const float yv = fmaf(va,wv[0], fmaf(vb,wv[1], fmaf(vcr,wv[2], rv*wv[3])));
      va=vb; vb=vcr; vcr=rv;
      cv = siluf_(yv);
      ceg = egp[r*Hz]; cb = bp[r*Hz];
    }
    __syncthreads();
    p ^= 1;
  }
}

// ---------------- output gate: rmsnorm_dv(o) * silu(gout) ----------------
__global__ __launch_bounds__(64) void gate_out_kernel(
    const bf16* __restrict__ o, const bf16* __restrict__ gout,
    const float* __restrict__ onw, bf16* __restrict__ og)
{
  const size_t base = (size_t)blockIdx.x * DVz;
  const int lane = threadIdx.x;
  const us* O = (const us*)o;
  float x0 = us2f(O[base+lane]), x1 = us2f(O[base+64+lane]), x2 = us2f(O[base+128+lane]);
  float ss = x0*x0 + x1*x1 + x2*x2;
  #pragma unroll
  for (int off=32; off>=1; off>>=1) ss += __shfl_xor(ss, off);
  const float inv = rsqrtf(ss*(1.f/DVz) + 1e-6f);
  const us* G = (const us*)gout;
  us* OG = (us*)og;
  float xs[3] = {x0, x1, x2};
  #pragma unroll
  for (int i=0;i<3;i++){
    const int c = lane + 64*i;
    const float gv = us2f(G[base+c]);
    OG[base+c] = f2bs(xs[i]*inv*onw[c] * siluf_(gv));
  }
}

extern "C" void kernel_launch(void* const* d_in, const int* in_sizes, int n_in,
                              void* d_out, int out_size, void* d_ws, size_t ws_size,
                              hipStream_t stream) {
  const float* x        = (const float*)d_in[0];
  const float* Wq       = (const float*)d_in[1];
  const float* Wk       = (const float*)d_in[2];
  const float* Wv       = (const float*)d_in[3];
  const float* Wb       = (const float*)d_in[4];
  const float* Wa       = (const float*)d_in[5];
  const float* A_log    = (const float*)d_in[6];
  const float* dt_bias  = (const float*)d_in[7];
  const float* conv_q_w = (const float*)d_in[8];
  const float* conv_k_w = (const float*)d_in[9];
  const float* conv_v_w = (const float*)d_in[10];
  const float* Wg       = (const float*)d_in[11];
  const float* onorm_w  = (const float*)d_in[12];
  const float* Wo       = (const float*)d_in[13];
  const float* norm1_w  = (const float*)d_in[14];
  const float* norm2_w  = (const float*)d_in[15];
  const float* Wgate    = (const float*)d_in[16];
  const float* Wup      = (const float*)d_in[17];
  const float* Wdown    = (const float*)d_in[18];

  char* W = (char*)d_ws;
  // bf16-transposed weights (rewritten every launch; deterministic)
  us* WoT    = (us*)(W + 0);           // [1024,1536]  3.15 MB
  us* WgateT = (us*)(W + 3145728);     // [4096,1024]  8.39 MB
  us* WupT   = (us*)(W + 11534336);    // [4096,1024]  8.39 MB
  us* WdownT = (us*)(W + 19922944);    // [1024,4096]  8.39 MB
  us* WqT    = (us*)(W + 28311552);    // [768,1024]   1.57 MB (dead after proj)
  us* WkT    = (us*)(W + 29884416);    // [768,1024]
  us* WvT    = (us*)(W + 31457280);    // [1536,1024]  3.15 MB
  us* WgT    = (us*)(W + 34603008);    // [1536,1024]  -> ends 37,748,736
  // activations
  bf16*  h_    = (bf16*) (W + 37748736);   // [8192,1024]; dead after gout GEMM
  bf16*  preq  = (bf16*) (W + 54525952);   // [8192,768];  dead after scan
  bf16*  prek  = (bf16*) (W + 67108864);   // [8192,768];  dead after scan
  bf16*  prev  = (bf16*) (W + 79691776);   // [8192,1536]; dead after scan
  float* beta_ = (float*)(W + 104857600);  // [8192,8]
  float* eg_   = (float*)(W + 105119744);  // [8192,8]
  float* invq_ = (float*)(W + 105381888);  // [8192,8]
  float* invk_ = (float*)(W + 105644032);  // [8192,8]
  bf16*  gout  = (bf16*) (W + 105906176);  // [8192,1536]; -> ends 131,072,000 (PEAK)
  // aliases over dead regions
  bf16*  o_    = (bf16*) (W + 28311552);   // [8192,1536] over WqT..WgT+h_ (dead pre-scan)
  bf16*  og    = (bf16*) (W + 54525952);   // [8192,1536] over preq+prek (dead post-scan)
  float* x2    = (float*)(W + 79691776);   // [8192,1024] f32 over prev+scalars+gout-head
  bf16*  h2    = (bf16*) (W + 113246208);  // [8192,1024] over gout tail (dead)
  bf16*  gateC = (bf16*) (W + 28311552);   // [2048,4096] over o_ region (dead post-gating)

  // 0. weight prep (transpose + f32->bf16)
  wprep_kernel<<<dim3(48,32),  256, 0, stream>>>(Wo,    WoT,    1536, 1024);
  wprep_kernel<<<dim3(32,128), 256, 0, stream>>>(Wgate, WgateT, 1024, 4096);
  wprep_kernel<<<dim3(32,128), 256, 0, stream>>>(Wup,   WupT,   1024, 4096);
  wprep_kernel<<<dim3(128,32), 256, 0, stream>>>(Wdown, WdownT, 4096, 1024);
  wprep_kernel<<<dim3(32,24),  256, 0, stream>>>(Wq,    WqT,    1024, 768);
  wprep_kernel<<<dim3(32,24),  256, 0, stream>>>(Wk,    WkT,    1024, 768);
  wprep_kernel<<<dim3(32,48),  256, 0, stream>>>(Wv,    WvT,    1024, 1536);
  wprep_kernel<<<dim3(32,48),  256, 0, stream>>>(Wg,    WgT,    1024, 1536);
  // 1. pre-norm
  rmsnorm_kernel<<<BTz, 256, 0, stream>>>(x, norm1_w, h_);
  // 2. projections + beta/eg
  mgemm_kernel<0><<<dim3(6,64),  256, 0, stream>>>(h_, WqT, nullptr, preq, BTz, KDz, Dz);
  mgemm_kernel<0><<<dim3(6,64),  256, 0, stream>>>(h_, WkT, nullptr, prek, BTz, KDz, Dz);
  mgemm_kernel<0><<<dim3(12,64), 256, 0, stream>>>(h_, WvT, nullptr, prev, BTz, VDz, Dz);
  beta_g_kernel<<<BTz, 256, 0, stream>>>(h_, Wb, Wa, A_log, dt_bias, beta_, eg_);
  mgemm_kernel<0><<<dim3(12,64), 256, 0, stream>>>(h_, WgT, nullptr, gout, BTz, VDz, Dz);
  // 3. l2norm scales, then fused conv+scan (768-thread, LDS-staged)
  conv_inv_kernel<<<BTz*Hz, 64, 0, stream>>>(preq, prek, conv_q_w, conv_k_w, invq_, invk_);
  scan_kernel<<<Bz*Hz, 768, 0, stream>>>(preq, prek, prev, conv_q_w, conv_k_w, conv_v_w,
                                         eg_, beta_, invq_, invk_, o_);
  // 4. output gating + Wo projection with residual
  gate_out_kernel<<<BTz*Hz, 64, 0, stream>>>(o_, gout, onorm_w, og);
  mgemm_kernel<1><<<dim3(8,64), 256, 0, stream>>>(og, WoT, x, x2, BTz, Dz, VDz);
  // 5. MLP, chunked over 4 x 2048 rows
  rmsnorm_kernel<<<BTz, 256, 0, stream>>>(x2, norm2_w, h2);
  for (int c = 0; c < 4; c++){
    const bf16*  h2c = h2 + (size_t)c*2048*Dz;
    const float* x2c = x2 + (size_t)c*2048*Dz;
    float*       out = (float*)d_out + (size_t)c*2048*Dz;
    mgemm_kernel<0><<<dim3(32,16), 256, 0, stream>>>(h2c, WgateT, nullptr, gateC, 2048, Iz, Dz);
    mgemm_kernel<3><<<dim3(32,16), 256, 0, stream>>>(h2c, WupT, gateC, gateC, 2048, Iz, Dz);
    mgemm_kernel<1><<<dim3(8,16),  256, 0, stream>>>(gateC, WdownT, x2c, out, 2048, Dz, Iz);
  }
}

// Round 7
// 2524.671 us; speedup vs baseline: 3.7881x; 1.3997x over previous
//
#include <hip/hip_runtime.h>
#include <hip/hip_bf16.h>

typedef __hip_bfloat16 bf16;
typedef unsigned short us;
typedef short short8v __attribute__((ext_vector_type(8)));
typedef float f32x4 __attribute__((ext_vector_type(4)));
typedef __attribute__((address_space(3))) unsigned int lds_u32;
typedef __attribute__((address_space(1))) const unsigned int glb_u32;

#define GLOAD16(gp, lp) __builtin_amdgcn_global_load_lds((glb_u32*)(gp), (lds_u32*)(lp), 16, 0, 0)

#define Bz 4
#define Tz 2048
#define Dz 1024
#define Hz 8
#define DKz 96
#define DVz 192
#define KDz 768
#define VDz 1536
#define Iz 4096
#define BTz (Bz*Tz)

static __device__ __forceinline__ float us2f(us s){
  return __uint_as_float(((unsigned)s) << 16);
}
static __device__ __forceinline__ us f2bs(float f){
  bf16 t = __float2bfloat16(f);
  return *(us*)&t;
}
static __device__ __forceinline__ float sigmoidf_(float x){ return 1.f/(1.f+expf(-x)); }
static __device__ __forceinline__ float siluf_(float x){ return x*sigmoidf_(x); }

// ---------------- weight prep: W[K,N] f32 -> WT[N,K] bf16 ----------------
__global__ __launch_bounds__(256) void wprep_kernel(
    const float* __restrict__ Wsrc, us* __restrict__ WTdst, int K, int N)
{
  __shared__ float t[32][33];
  const int k0 = blockIdx.x*32, n0 = blockIdx.y*32;
  const int c = threadIdx.x & 31, r8 = threadIdx.x >> 5;
  #pragma unroll
  for (int i=0;i<4;i++){
    const int r = r8 + i*8;
    t[r][c] = Wsrc[(size_t)(k0+r)*N + n0 + c];
  }
  __syncthreads();
  #pragma unroll
  for (int i=0;i<4;i++){
    const int r = r8 + i*8;
    WTdst[(size_t)(n0+r)*K + k0 + c] = f2bs(t[c][r]);
  }
}

// ---------------- RMSNorm (f32 in -> bf16 out, f32 weights) ----------------
__global__ __launch_bounds__(256) void rmsnorm_kernel(
    const float* __restrict__ x, const float* __restrict__ w, bf16* __restrict__ out)
{
  const int row = blockIdx.x;
  const float* xr = x + (size_t)row*Dz;
  const int i0 = threadIdx.x*4;
  float4 xv = *(const float4*)(xr + i0);
  float ss = xv.x*xv.x+xv.y*xv.y+xv.z*xv.z+xv.w*xv.w;
  #pragma unroll
  for (int off=32; off>=1; off>>=1) ss += __shfl_xor(ss, off);
  __shared__ float red[4];
  if ((threadIdx.x&63)==0) red[threadIdx.x>>6] = ss;
  __syncthreads();
  ss = red[0]+red[1]+red[2]+red[3];
  const float inv = rsqrtf(ss*(1.f/Dz) + 1e-6f);
  float4 wv = *(const float4*)(w + i0);
  ushort4 ov;
  ov.x=f2bs(xv.x*inv*wv.x); ov.y=f2bs(xv.y*inv*wv.y);
  ov.z=f2bs(xv.z*inv*wv.z); ov.w=f2bs(xv.w*inv*wv.w);
  *(ushort4*)((us*)out + (size_t)row*Dz + i0) = ov;
}

// ------------- MFMA GEMM: C[M,N] = A[M,K](bf16) @ BT[N,K](bf16)^T (+res) -------------
// Tile 128x128, BK=64, 256 threads (4 waves, 2x2), mfma_f32_16x16x32_bf16.
// MODE 0: write bf16.  MODE 1: write f32 + f32 residual.  MODE 3: bf16 = silu(bf16 res)*acc.
template<int MODE>
__global__ __launch_bounds__(256, 2) void mgemm_kernel(
    const bf16* __restrict__ A, const us* __restrict__ BT,
    const void* __restrict__ res, void* __restrict__ Cout,
    int M, int N, int K)
{
  __shared__ us As[128*64];
  __shared__ us Bs[128*64];
  const int m0 = blockIdx.y*128, n0 = blockIdx.x*128;
  const int tid = threadIdx.x;
  const int wid = tid >> 6, lane = tid & 63;
  const int wr = wid >> 1, wc = wid & 1;
  const int fq = lane >> 4, fr = lane & 15;

  const us* Ab = (const us*)A + (size_t)(m0 + (tid>>3))*K + (tid&7)*8;
  const us* Bb = BT + (size_t)(n0 + (tid>>3))*K + (tid&7)*8;
  char* AsB = (char*)As;
  char* BsB = (char*)Bs;
  const int ldsoff = wid*1024;

  f32x4 acc[4][4] = {};
  const int nk = K >> 6;
  for (int kt = 0; kt < nk; ++kt){
    const int kb = kt*64;
    #pragma unroll
    for (int i=0;i<4;i++){
      GLOAD16(Ab + (size_t)(32*i)*K + kb, AsB + ldsoff + i*4096);
      GLOAD16(Bb + (size_t)(32*i)*K + kb, BsB + ldsoff + i*4096);
    }
    __syncthreads();
    #pragma unroll
    for (int ks=0; ks<2; ks++){
      short8v af[4], bf[4];
      #pragma unroll
      for (int r=0;r<4;r++)
        af[r] = *(const short8v*)&As[(wr*64 + r*16 + fr)*64 + ks*32 + fq*8];
      #pragma unroll
      for (int c=0;c<4;c++)
        bf[c] = *(const short8v*)&Bs[(wc*64 + c*16 + fr)*64 + ks*32 + fq*8];
      #pragma unroll
      for (int r=0;r<4;r++)
        #pragma unroll
        for (int c=0;c<4;c++)
          acc[r][c] = __builtin_amdgcn_mfma_f32_16x16x32_bf16(af[r], bf[c], acc[r][c], 0, 0, 0);
    }
    __syncthreads();
  }
  #pragma unroll
  for (int r=0;r<4;r++){
    #pragma unroll
    for (int c=0;c<4;c++){
      const int col = n0 + wc*64 + c*16 + fr;
      #pragma unroll
      for (int jj=0;jj<4;jj++){
        const int row = m0 + wr*64 + r*16 + fq*4 + jj;
        const size_t idx = (size_t)row*N + col;
        const float a = acc[r][c][jj];
        if (MODE==0){
          ((us*)Cout)[idx] = f2bs(a);
        } else if (MODE==1){
          ((float*)Cout)[idx] = a + ((const float*)res)[idx];
        } else {
          ((us*)Cout)[idx] = f2bs(siluf_(us2f(((const us*)res)[idx]))*a);
        }
      }
    }
  }
}

// ---------------- beta / exp(g) projections (N=8 each, f32 weights) ----------------
__global__ __launch_bounds__(256) void beta_g_kernel(
    const bf16* __restrict__ hh, const float* __restrict__ Wb, const float* __restrict__ Wa,
    const float* __restrict__ A_log, const float* __restrict__ dt_bias,
    float* __restrict__ beta, float* __restrict__ eg)
{
  const int row = blockIdx.x;
  const us* hr = (const us*)hh + (size_t)row*Dz;
  float ab[8]={0,0,0,0,0,0,0,0}, aa[8]={0,0,0,0,0,0,0,0};
  for (int kk=threadIdx.x; kk<Dz; kk+=256){
    const float hv = us2f(hr[kk]);
    float4 b0 = *(const float4*)(Wb + kk*8);
    float4 b1 = *(const float4*)(Wb + kk*8 + 4);
    float4 a0 = *(const float4*)(Wa + kk*8);
    float4 a1 = *(const float4*)(Wa + kk*8 + 4);
    ab[0]=fmaf(hv,b0.x,ab[0]); ab[1]=fmaf(hv,b0.y,ab[1]);
    ab[2]=fmaf(hv,b0.z,ab[2]); ab[3]=fmaf(hv,b0.w,ab[3]);
    ab[4]=fmaf(hv,b1.x,ab[4]); ab[5]=fmaf(hv,b1.y,ab[5]);
    ab[6]=fmaf(hv,b1.z,ab[6]); ab[7]=fmaf(hv,b1.w,ab[7]);
    aa[0]=fmaf(hv,a0.x,aa[0]); aa[1]=fmaf(hv,a0.y,aa[1]);
    aa[2]=fmaf(hv,a0.z,aa[2]); aa[3]=fmaf(hv,a0.w,aa[3]);
    aa[4]=fmaf(hv,a1.x,aa[4]); aa[5]=fmaf(hv,a1.y,aa[5]);
    aa[6]=fmaf(hv,a1.z,aa[6]); aa[7]=fmaf(hv,a1.w,aa[7]);
  }
  #pragma unroll
  for (int off=32; off>=1; off>>=1){
    #pragma unroll
    for (int n=0;n<8;n++){ ab[n]+=__shfl_xor(ab[n],off); aa[n]+=__shfl_xor(aa[n],off); }
  }
  __shared__ float red[4][16];
  const int wv = threadIdx.x>>6, ln = threadIdx.x&63;
  if (ln==0){
    #pragma unroll
    for (int n=0;n<8;n++){ red[wv][n]=ab[n]; red[wv][8+n]=aa[n]; }
  }
  __syncthreads();
  if (threadIdx.x < 8){
    const int n = threadIdx.x;
    float sb = red[0][n]+red[1][n]+red[2][n]+red[3][n];
    float sa = red[0][8+n]+red[1][8+n]+red[2][8+n]+red[3][8+n];
    beta[(size_t)row*Hz+n] = 1.f/(1.f+expf(-sb));
    float xx = sa + dt_bias[n];
    float sp = (xx > 20.f) ? xx : log1pf(expf(xx));
    eg[(size_t)row*Hz+n] = expf(-expf(A_log[n])*sp);
  }
}

// ------------- conv(K=4)+SiLU+l2norm SCALES for q,k (parallel over B*T*H) -------------
__global__ __launch_bounds__(64) void conv_inv_kernel(
    const bf16* __restrict__ preq, const bf16* __restrict__ prek,
    const float* __restrict__ wqc, const float* __restrict__ wkc,
    float* __restrict__ invq, float* __restrict__ invk)
{
  const int idx = blockIdx.x; const int h = idx & 7; const int bt = idx >> 3;
  const int t = bt & (Tz-1);
  const int lane = threadIdx.x;
  const us* Q = (const us*)preq;
  const us* K = (const us*)prek;
  const int c0 = h*DKz + lane, c1 = c0 + 64;
  const bool hi = lane < 32;
  float yq0=0.f, yq1=0.f, yk0=0.f, yk1=0.f;
  #pragma unroll
  for (int i=0;i<4;i++){
    const int ti = t - 3 + i;
    if (ti >= 0){
      const size_t rowb = (size_t)(bt-3+i)*KDz;
      yq0 = fmaf(us2f(Q[rowb + c0]), wqc[c0*4+i], yq0);
      yk0 = fmaf(us2f(K[rowb + c0]), wkc[c0*4+i], yk0);
      if (hi){
        yq1 = fmaf(us2f(Q[rowb + c1]), wqc[c1*4+i], yq1);
        yk1 = fmaf(us2f(K[rowb + c1]), wkc[c1*4+i], yk1);
      }
    }
  }
  yq0 = siluf_(yq0); yk0 = siluf_(yk0);
  yq1 = hi ? siluf_(yq1) : 0.f;
  yk1 = hi ? siluf_(yk1) : 0.f;
  float ssq = yq0*yq0 + yq1*yq1;
  float ssk = yk0*yk0 + yk1*yk1;
  #pragma unroll
  for (int off=32; off>=1; off>>=1){ ssq += __shfl_xor(ssq,off); ssk += __shfl_xor(ssk,off); }
  if (lane == 0){
    invq[(size_t)bt*Hz + h] = rsqrtf(ssq + 1e-6f) * 0.10206207262f;  // * dk^-0.5
    invk[(size_t)bt*Hz + h] = rsqrtf(ssk + 1e-6f);
  }
}

// ---------------- gated delta-rule scan, split over v-columns ----------------
// Grid = Bz*Hz*8 blocks; block (bh, sp) owns v-cols [sp*24, sp*24+24).
// 192 threads: tid = j*8 + g; thread owns S[g*12 .. g*12+11][col sp*24+j] (12 f32 regs).
// Phase = 8 timesteps, ONE barrier per phase:
//   - producers (1:1 thread->channel) write conv+silu+l2scaled k,q for the NEXT
//     phase into the other LDS buffer (pure function of inputs, no S dependency);
//   - cv/eg/beta for the current phase precomputed into registers;
//   - 8 sequential S-update steps consume current buffer (broadcast ds_read,
//     3-level shfl_xor reductions over the 8-lane g-group).
__global__ __launch_bounds__(192) void scan_kernel(
    const bf16* __restrict__ preq, const bf16* __restrict__ prek, const bf16* __restrict__ prev,
    const float* __restrict__ wqc, const float* __restrict__ wkc, const float* __restrict__ wvc,
    const float* __restrict__ eg_, const float* __restrict__ beta,
    const float* __restrict__ invq_, const float* __restrict__ invk_,
    bf16* __restrict__ o)
{
  const int blk = blockIdx.x;
  const int bh = blk >> 3, sp = blk & 7;
  const int b = bh >> 3, h = bh & 7;
  const int tid = threadIdx.x;
  const int j = tid >> 3, g = tid & 7;
  const int jg = sp*24 + j;
  const int vc = h*DVz + jg;

  __shared__ float kq[2][8][192];   // [buf][step][96 k | 96 q]

  // ---- producer setup: thread ch = tid; ch<96 -> k channel, else q channel ----
  const bool prodK = (tid < 96);
  const int ch = prodK ? tid : (tid - 96);
  const int kcol = h*DKz + ch;
  float w0,w1,w2,w3;
  {
    const float* wc = prodK ? wkc : wqc;
    w0 = wc[kcol*4+0]; w1 = wc[kcol*4+1]; w2 = wc[kcol*4+2]; w3 = wc[kcol*4+3];
  }
  const us* PP = (const us*)(prodK ? prek : preq) + (size_t)b*Tz*KDz + kcol;
  const float* ivp = (prodK ? invk_ : invq_) + (size_t)b*Tz*Hz + h;

  // ---- consumer setup ----
  float wv0 = wvc[vc*4+0], wv1 = wvc[vc*4+1], wv2 = wvc[vc*4+2], wv3 = wvc[vc*4+3];
  const us* VP = (const us*)prev + (size_t)b*Tz*VDz + vc;
  us* op = (us*)o + (size_t)b*Tz*VDz + vc;
  const float* egp = eg_  + (size_t)b*Tz*Hz + h;
  const float* bp  = beta + (size_t)b*Tz*Hz + h;

  float S[12];
  #pragma unroll
  for (int m=0;m<12;m++) S[m]=0.f;

  float pra=0.f, prb=0.f, prc=0.f;  // producer conv ring (t-3,t-2,t-1)
  float va=0.f, vb=0.f, vcr=0.f;    // v conv ring

  // prologue: produce steps 0..7 into buf 0
  #pragma unroll
  for (int s=0;s<8;s++){
    const float raw = us2f(PP[(size_t)s*KDz]);
    const float y = fmaf(pra,w0, fmaf(prb,w1, fmaf(prc,w2, raw*w3)));
    pra=prb; prb=prc; prc=raw;
    kq[0][s][tid] = siluf_(y) * ivp[(size_t)s*Hz];
  }
  __syncthreads();

  for (int ph=0; ph<Tz/8; ph++){
    const int base = ph*8;
    const int p = ph & 1;
    // cv/ce/cb for this phase (independent of S)
    float cv[8], ce[8], cb[8];
    #pragma unroll
    for (int s=0;s<8;s++){
      const size_t r = (size_t)(base + s);
      const float rv = us2f(VP[r*VDz]);
      const float yv = fmaf(va,wv0, fmaf(vb,wv1, fmaf(vcr,wv2, rv*wv3)));
      va=vb; vb=vcr; vcr=rv;
      cv[s] = siluf_(yv);
      ce[s] = egp[r*Hz];
      cb[s] = bp[r*Hz];
    }
    // produce next phase's k,q into the other buffer
    if (base + 8 < Tz){
      #pragma unroll
      for (int s=0;s<8;s++){
        const size_t r = (size_t)(base + 8 + s);
        const float raw = us2f(PP[r*KDz]);
        const float y = fmaf(pra,w0, fmaf(prb,w1, fmaf(prc,w2, raw*w3)));
        pra=prb; prb=prc; prc=raw;
        kq[p^1][s][tid] = siluf_(y) * ivp[r*Hz];
      }
    }
    // consume 8 sequential steps
    #pragma unroll
    for (int s=0;s<8;s++){
      const float4 k0 = *(const float4*)&kq[p][s][g*12];
      const float4 k1 = *(const float4*)&kq[p][s][g*12+4];
      const float4 k2 = *(const float4*)&kq[p][s][g*12+8];
      const float4 q0 = *(const float4*)&kq[p][s][96+g*12];
      const float4 q1 = *(const float4*)&kq[p][s][96+g*12+4];
      const float4 q2 = *(const float4*)&kq[p][s][96+g*12+8];
      // pv = k . S (pre-decay), 4 parallel chains then tree
      float a0,a1,a2,a3;
      a0 = k0.x*S[0]; a1 = k0.y*S[1]; a2 = k0.z*S[2]; a3 = k0.w*S[3];
      a0 = fmaf(k1.x,S[4],a0); a1 = fmaf(k1.y,S[5],a1); a2 = fmaf(k1.z,S[6],a2); a3 = fmaf(k1.w,S[7],a3);
      a0 = fmaf(k2.x,S[8],a0); a1 = fmaf(k2.y,S[9],a1); a2 = fmaf(k2.z,S[10],a2); a3 = fmaf(k2.w,S[11],a3);
      float pv = (a0+a1)+(a2+a3);
      pv += __shfl_xor(pv, 1);
      pv += __shfl_xor(pv, 2);
      pv += __shfl_xor(pv, 4);
      const float eg = ce[s];
      const float delta = (cv[s] - eg*pv)*cb[s];
      // S update + o partials
      float o0,o1,o2,o3;
      float t0;
      t0 = fmaf(eg,S[0], k0.x*delta); S[0]=t0; o0 = q0.x*t0;
      t0 = fmaf(eg,S[1], k0.y*delta); S[1]=t0; o1 = q0.y*t0;
      t0 = fmaf(eg,S[2], k0.z*delta); S[2]=t0; o2 = q0.z*t0;
      t0 = fmaf(eg,S[3], k0.w*delta); S[3]=t0; o3 = q0.w*t0;
      t0 = fmaf(eg,S[4], k1.x*delta); S[4]=t0; o0 = fmaf(q1.x,t0,o0);
      t0 = fmaf(eg,S[5], k1.y*delta); S[5]=t0; o1 = fmaf(q1.y,t0,o1);
      t0 = fmaf(eg,S[6], k1.z*delta); S[6]=t0; o2 = fmaf(q1.z,t0,o2);
      t0 = fmaf(eg,S[7], k1.w*delta); S[7]=t0; o3 = fmaf(q1.w,t0,o3);
      t0 = fmaf(eg,S[8], k2.x*delta); S[8]=t0; o0 = fmaf(q2.x,t0,o0);
      t0 = fmaf(eg,S[9], k2.y*delta); S[9]=t0; o1 = fmaf(q2.y,t0,o1);
      t0 = fmaf(eg,S[10],k2.z*delta); S[10]=t0; o2 = fmaf(q2.z,t0,o2);
      t0 = fmaf(eg,S[11],k2.w*delta); S[11]=t0; o3 = fmaf(q2.w,t0,o3);
      float po = (o0+o1)+(o2+o3);
      po += __shfl_xor(po, 1);
      po += __shfl_xor(po, 2);
      po += __shfl_xor(po, 4);
      if (g == 0) op[(size_t)(base+s)*VDz] = f2bs(po);
    }
    __syncthreads();
  }
}

// ---------------- output gate: rmsnorm_dv(o) * silu(gout) ----------------
__global__ __launch_bounds__(64) void gate_out_kernel(
    const bf16* __restrict__ o, const bf16* __restrict__ gout,
    const float* __restrict__ onw, bf16* __restrict__ og)
{
  const size_t base = (size_t)blockIdx.x * DVz;
  const int lane = threadIdx.x;
  const us* O = (const us*)o;
  float x0 = us2f(O[base+lane]), x1 = us2f(O[base+64+lane]), x2 = us2f(O[base+128+lane]);
  float ss = x0*x0 + x1*x1 + x2*x2;
  #pragma unroll
  for (int off=32; off>=1; off>>=1) ss += __shfl_xor(ss, off);
  const float inv = rsqrtf(ss*(1.f/DVz) + 1e-6f);
  const us* G = (const us*)gout;
  us* OG = (us*)og;
  float xs[3] = {x0, x1, x2};
  #pragma unroll
  for (int i=0;i<3;i++){
    const int c = lane + 64*i;
    const float gv = us2f(G[base+c]);
    OG[base+c] = f2bs(xs[i]*inv*onw[c] * siluf_(gv));
  }
}

extern "C" void kernel_launch(void* const* d_in, const int* in_sizes, int n_in,
                              void* d_out, int out_size, void* d_ws, size_t ws_size,
                              hipStream_t stream) {
  const float* x        = (const float*)d_in[0];
  const float* Wq       = (const float*)d_in[1];
  const float* Wk       = (const float*)d_in[2];
  const float* Wv       = (const float*)d_in[3];
  const float* Wb       = (const float*)d_in[4];
  const float* Wa       = (const float*)d_in[5];
  const float* A_log    = (const float*)d_in[6];
  const float* dt_bias  = (const float*)d_in[7];
  const float* conv_q_w = (const float*)d_in[8];
  const float* conv_k_w = (const float*)d_in[9];
  const float* conv_v_w = (const float*)d_in[10];
  const float* Wg       = (const float*)d_in[11];
  const float* onorm_w  = (const float*)d_in[12];
  const float* Wo       = (const float*)d_in[13];
  const float* norm1_w  = (const float*)d_in[14];
  const float* norm2_w  = (const float*)d_in[15];
  const float* Wgate    = (const float*)d_in[16];
  const float* Wup      = (const float*)d_in[17];
  const float* Wdown    = (const float*)d_in[18];

  char* W = (char*)d_ws;
  // bf16-transposed weights (rewritten every launch; deterministic)
  us* WoT    = (us*)(W + 0);           // [1024,1536]  3.15 MB
  us* WgateT = (us*)(W + 3145728);     // [4096,1024]  8.39 MB
  us* WupT   = (us*)(W + 11534336);    // [4096,1024]  8.39 MB
  us* WdownT = (us*)(W + 19922944);    // [1024,4096]  8.39 MB
  us* WqT    = (us*)(W + 28311552);    // [768,1024]   1.57 MB (dead after proj)
  us* WkT    = (us*)(W + 29884416);    // [768,1024]
  us* WvT    = (us*)(W + 31457280);    // [1536,1024]  3.15 MB
  us* WgT    = (us*)(W + 34603008);    // [1536,1024]  -> ends 37,748,736
  // activations
  bf16*  h_    = (bf16*) (W + 37748736);   // [8192,1024]; dead after gout GEMM
  bf16*  preq  = (bf16*) (W + 54525952);   // [8192,768];  dead after scan
  bf16*  prek  = (bf16*) (W + 67108864);   // [8192,768];  dead after scan
  bf16*  prev  = (bf16*) (W + 79691776);   // [8192,1536]; dead after scan
  float* beta_ = (float*)(W + 104857600);  // [8192,8]
  float* eg_   = (float*)(W + 105119744);  // [8192,8]
  float* invq_ = (float*)(W + 105381888);  // [8192,8]
  float* invk_ = (float*)(W + 105644032);  // [8192,8]
  bf16*  gout  = (bf16*) (W + 105906176);  // [8192,1536]; -> ends 131,072,000 (PEAK)
  // aliases over dead regions
  bf16*  o_    = (bf16*) (W + 28311552);   // [8192,1536] over WqT..WgT+h_ (dead pre-scan)
  bf16*  og    = (bf16*) (W + 54525952);   // [8192,1536] over preq+prek (dead post-scan)
  float* x2    = (float*)(W + 79691776);   // [8192,1024] f32 over prev+scalars+gout-head
  bf16*  h2    = (bf16*) (W + 113246208);  // [8192,1024] over gout tail (dead)
  bf16*  gateC = (bf16*) (W + 28311552);   // [2048,4096] over o_ region (dead post-gating)

  // 0. weight prep (transpose + f32->bf16)
  wprep_kernel<<<dim3(48,32),  256, 0, stream>>>(Wo,    WoT,    1536, 1024);
  wprep_kernel<<<dim3(32,128), 256, 0, stream>>>(Wgate, WgateT, 1024, 4096);
  wprep_kernel<<<dim3(32,128), 256, 0, stream>>>(Wup,   WupT,   1024, 4096);
  wprep_kernel<<<dim3(128,32), 256, 0, stream>>>(Wdown, WdownT, 4096, 1024);
  wprep_kernel<<<dim3(32,24),  256, 0, stream>>>(Wq,    WqT,    1024, 768);
  wprep_kernel<<<dim3(32,24),  256, 0, stream>>>(Wk,    WkT,    1024, 768);
  wprep_kernel<<<dim3(32,48),  256, 0, stream>>>(Wv,    WvT,    1024, 1536);
  wprep_kernel<<<dim3(32,48),  256, 0, stream>>>(Wg,    WgT,    1024, 1536);
  // 1. pre-norm
  rmsnorm_kernel<<<BTz, 256, 0, stream>>>(x, norm1_w, h_);
  // 2. projections + beta/eg
  mgemm_kernel<0><<<dim3(6,64),  256, 0, stream>>>(h_, WqT, nullptr, preq, BTz, KDz, Dz);
  mgemm_kernel<0><<<dim3(6,64),  256, 0, stream>>>(h_, WkT, nullptr, prek, BTz, KDz, Dz);
  mgemm_kernel<0><<<dim3(12,64), 256, 0, stream>>>(h_, WvT, nullptr, prev, BTz, VDz, Dz);
  beta_g_kernel<<<BTz, 256, 0, stream>>>(h_, Wb, Wa, A_log, dt_bias, beta_, eg_);
  mgemm_kernel<0><<<dim3(12,64), 256, 0, stream>>>(h_, WgT, nullptr, gout, BTz, VDz, Dz);
  // 3. l2norm scales, then fused conv+scan (256 blocks x 192 threads, 8-step phases)
  conv_inv_kernel<<<BTz*Hz, 64, 0, stream>>>(preq, prek, conv_q_w, conv_k_w, invq_, invk_);
  scan_kernel<<<Bz*Hz*8, 192, 0, stream>>>(preq, prek, prev, conv_q_w, conv_k_w, conv_v_w,
                                           eg_, beta_, invq_, invk_, o_);
  // 4. output gating + Wo projection with residual
  gate_out_kernel<<<BTz*Hz, 64, 0, stream>>>(o_, gout, onorm_w, og);
  mgemm_kernel<1><<<dim3(8,64), 256, 0, stream>>>(og, WoT, x, x2, BTz, Dz, VDz);
  // 5. MLP, chunked over 4 x 2048 rows
  rmsnorm_kernel<<<BTz, 256, 0, stream>>>(x2, norm2_w, h2);
  for (int c = 0; c < 4; c++){
    const bf16*  h2c = h2 + (size_t)c*2048*Dz;
    const float* x2c = x2 + (size_t)c*2048*Dz;
    float*       out = (float*)d_out + (size_t)c*2048*Dz;
    mgemm_kernel<0><<<dim3(32,16), 256, 0, stream>>>(h2c, WgateT, nullptr, gateC, 2048, Iz, Dz);
    mgemm_kernel<3><<<dim3(32,16), 256, 0, stream>>>(h2c, WupT, gateC, gateC, 2048, Iz, Dz);
    mgemm_kernel<1><<<dim3(8,16),  256, 0, stream>>>(gateC, WdownT, x2c, out, 2048, Dz, Iz);
  }
}

// Round 8
// 2275.959 us; speedup vs baseline: 4.2020x; 1.1093x over previous
//
#include <hip/hip_runtime.h>
#include <hip/hip_bf16.h>

typedef __hip_bfloat16 bf16;
typedef unsigned short us;
typedef short short8v __attribute__((ext_vector_type(8)));
typedef float f32x4 __attribute__((ext_vector_type(4)));
typedef __attribute__((address_space(3))) unsigned int lds_u32;
typedef __attribute__((address_space(1))) const unsigned int glb_u32;

#define GLOAD16(gp, lp) __builtin_amdgcn_global_load_lds((glb_u32*)(gp), (lds_u32*)(lp), 16, 0, 0)

#define Bz 4
#define Tz 2048
#define Dz 1024
#define Hz 8
#define DKz 96
#define DVz 192
#define KDz 768
#define VDz 1536
#define Iz 4096
#define BTz (Bz*Tz)

static __device__ __forceinline__ float us2f(us s){
  return __uint_as_float(((unsigned)s) << 16);
}
static __device__ __forceinline__ us f2bs(float f){
  bf16 t = __float2bfloat16(f);
  return *(us*)&t;
}
static __device__ __forceinline__ float sigmoidf_(float x){ return 1.f/(1.f+expf(-x)); }
static __device__ __forceinline__ float siluf_(float x){ return x*sigmoidf_(x); }

// DPP-based 8-lane-group sum (groups = lanes [8m..8m+7]):
// xor1 (quad_perm 0xB1), xor2 (quad_perm 0x4E), then row_half_mirror (0x141):
// after the two quad steps each quad is uniform, mirror adds the other quad's total.
#define DPPADD(x, ctrl) \
  ((x) + __int_as_float(__builtin_amdgcn_update_dpp(0, __float_as_int(x), (ctrl), 0xF, 0xF, true)))
static __device__ __forceinline__ float gsum8(float x){
  x = DPPADD(x, 0xB1);   // quad_perm [1,0,3,2]  : + lane^1
  x = DPPADD(x, 0x4E);   // quad_perm [2,3,0,1]  : + lane^2
  x = DPPADD(x, 0x141);  // row_half_mirror      : + other quad's sum
  return x;
}

// ---------------- weight prep: W[K,N] f32 -> WT[N,K] bf16 ----------------
__global__ __launch_bounds__(256) void wprep_kernel(
    const float* __restrict__ Wsrc, us* __restrict__ WTdst, int K, int N)
{
  __shared__ float t[32][33];
  const int k0 = blockIdx.x*32, n0 = blockIdx.y*32;
  const int c = threadIdx.x & 31, r8 = threadIdx.x >> 5;
  #pragma unroll
  for (int i=0;i<4;i++){
    const int r = r8 + i*8;
    t[r][c] = Wsrc[(size_t)(k0+r)*N + n0 + c];
  }
  __syncthreads();
  #pragma unroll
  for (int i=0;i<4;i++){
    const int r = r8 + i*8;
    WTdst[(size_t)(n0+r)*K + k0 + c] = f2bs(t[c][r]);
  }
}

// ---------------- RMSNorm (f32 in -> bf16 out, f32 weights) ----------------
__global__ __launch_bounds__(256) void rmsnorm_kernel(
    const float* __restrict__ x, const float* __restrict__ w, bf16* __restrict__ out)
{
  const int row = blockIdx.x;
  const float* xr = x + (size_t)row*Dz;
  const int i0 = threadIdx.x*4;
  float4 xv = *(const float4*)(xr + i0);
  float ss = xv.x*xv.x+xv.y*xv.y+xv.z*xv.z+xv.w*xv.w;
  #pragma unroll
  for (int off=32; off>=1; off>>=1) ss += __shfl_xor(ss, off);
  __shared__ float red[4];
  if ((threadIdx.x&63)==0) red[threadIdx.x>>6] = ss;
  __syncthreads();
  ss = red[0]+red[1]+red[2]+red[3];
  const float inv = rsqrtf(ss*(1.f/Dz) + 1e-6f);
  float4 wv = *(const float4*)(w + i0);
  ushort4 ov;
  ov.x=f2bs(xv.x*inv*wv.x); ov.y=f2bs(xv.y*inv*wv.y);
  ov.z=f2bs(xv.z*inv*wv.z); ov.w=f2bs(xv.w*inv*wv.w);
  *(ushort4*)((us*)out + (size_t)row*Dz + i0) = ov;
}

// ------------- MFMA GEMM: C[M,N] = A[M,K](bf16) @ BT[N,K](bf16)^T (+res) -------------
// Tile 128x128, BK=64, 256 threads (4 waves, 2x2), mfma_f32_16x16x32_bf16.
// MODE 0: write bf16.  MODE 1: write f32 + f32 residual.  MODE 3: bf16 = silu(bf16 res)*acc.
template<int MODE>
__global__ __launch_bounds__(256, 2) void mgemm_kernel(
    const bf16* __restrict__ A, const us* __restrict__ BT,
    const void* __restrict__ res, void* __restrict__ Cout,
    int M, int N, int K)
{
  __shared__ us As[128*64];
  __shared__ us Bs[128*64];
  const int m0 = blockIdx.y*128, n0 = blockIdx.x*128;
  const int tid = threadIdx.x;
  const int wid = tid >> 6, lane = tid & 63;
  const int wr = wid >> 1, wc = wid & 1;
  const int fq = lane >> 4, fr = lane & 15;

  const us* Ab = (const us*)A + (size_t)(m0 + (tid>>3))*K + (tid&7)*8;
  const us* Bb = BT + (size_t)(n0 + (tid>>3))*K + (tid&7)*8;
  char* AsB = (char*)As;
  char* BsB = (char*)Bs;
  const int ldsoff = wid*1024;

  f32x4 acc[4][4] = {};
  const int nk = K >> 6;
  for (int kt = 0; kt < nk; ++kt){
    const int kb = kt*64;
    #pragma unroll
    for (int i=0;i<4;i++){
      GLOAD16(Ab + (size_t)(32*i)*K + kb, AsB + ldsoff + i*4096);
      GLOAD16(Bb + (size_t)(32*i)*K + kb, BsB + ldsoff + i*4096);
    }
    __syncthreads();
    #pragma unroll
    for (int ks=0; ks<2; ks++){
      short8v af[4], bf[4];
      #pragma unroll
      for (int r=0;r<4;r++)
        af[r] = *(const short8v*)&As[(wr*64 + r*16 + fr)*64 + ks*32 + fq*8];
      #pragma unroll
      for (int c=0;c<4;c++)
        bf[c] = *(const short8v*)&Bs[(wc*64 + c*16 + fr)*64 + ks*32 + fq*8];
      #pragma unroll
      for (int r=0;r<4;r++)
        #pragma unroll
        for (int c=0;c<4;c++)
          acc[r][c] = __builtin_amdgcn_mfma_f32_16x16x32_bf16(af[r], bf[c], acc[r][c], 0, 0, 0);
    }
    __syncthreads();
  }
  #pragma unroll
  for (int r=0;r<4;r++){
    #pragma unroll
    for (int c=0;c<4;c++){
      const int col = n0 + wc*64 + c*16 + fr;
      #pragma unroll
      for (int jj=0;jj<4;jj++){
        const int row = m0 + wr*64 + r*16 + fq*4 + jj;
        const size_t idx = (size_t)row*N + col;
        const float a = acc[r][c][jj];
        if (MODE==0){
          ((us*)Cout)[idx] = f2bs(a);
        } else if (MODE==1){
          ((float*)Cout)[idx] = a + ((const float*)res)[idx];
        } else {
          ((us*)Cout)[idx] = f2bs(siluf_(us2f(((const us*)res)[idx]))*a);
        }
      }
    }
  }
}

// ---------------- beta / exp(g) projections (N=8 each, f32 weights) ----------------
__global__ __launch_bounds__(256) void beta_g_kernel(
    const bf16* __restrict__ hh, const float* __restrict__ Wb, const float* __restrict__ Wa,
    const float* __restrict__ A_log, const float* __restrict__ dt_bias,
    float* __restrict__ beta, float* __restrict__ eg)
{
  const int row = blockIdx.x;
  const us* hr = (const us*)hh + (size_t)row*Dz;
  float ab[8]={0,0,0,0,0,0,0,0}, aa[8]={0,0,0,0,0,0,0,0};
  for (int kk=threadIdx.x; kk<Dz; kk+=256){
    const float hv = us2f(hr[kk]);
    float4 b0 = *(const float4*)(Wb + kk*8);
    float4 b1 = *(const float4*)(Wb + kk*8 + 4);
    float4 a0 = *(const float4*)(Wa + kk*8);
    float4 a1 = *(const float4*)(Wa + kk*8 + 4);
    ab[0]=fmaf(hv,b0.x,ab[0]); ab[1]=fmaf(hv,b0.y,ab[1]);
    ab[2]=fmaf(hv,b0.z,ab[2]); ab[3]=fmaf(hv,b0.w,ab[3]);
    ab[4]=fmaf(hv,b1.x,ab[4]); ab[5]=fmaf(hv,b1.y,ab[5]);
    ab[6]=fmaf(hv,b1.z,ab[6]); ab[7]=fmaf(hv,b1.w,ab[7]);
    aa[0]=fmaf(hv,a0.x,aa[0]); aa[1]=fmaf(hv,a0.y,aa[1]);
    aa[2]=fmaf(hv,a0.z,aa[2]); aa[3]=fmaf(hv,a0.w,aa[3]);
    aa[4]=fmaf(hv,a1.x,aa[4]); aa[5]=fmaf(hv,a1.y,aa[5]);
    aa[6]=fmaf(hv,a1.z,aa[6]); aa[7]=fmaf(hv,a1.w,aa[7]);
  }
  #pragma unroll
  for (int off=32; off>=1; off>>=1){
    #pragma unroll
    for (int n=0;n<8;n++){ ab[n]+=__shfl_xor(ab[n],off); aa[n]+=__shfl_xor(aa[n],off); }
  }
  __shared__ float red[4][16];
  const int wv = threadIdx.x>>6, ln = threadIdx.x&63;
  if (ln==0){
    #pragma unroll
    for (int n=0;n<8;n++){ red[wv][n]=ab[n]; red[wv][8+n]=aa[n]; }
  }
  __syncthreads();
  if (threadIdx.x < 8){
    const int n = threadIdx.x;
    float sb = red[0][n]+red[1][n]+red[2][n]+red[3][n];
    float sa = red[0][8+n]+red[1][8+n]+red[2][8+n]+red[3][8+n];
    beta[(size_t)row*Hz+n] = 1.f/(1.f+expf(-sb));
    float xx = sa + dt_bias[n];
    float sp = (xx > 20.f) ? xx : log1pf(expf(xx));
    eg[(size_t)row*Hz+n] = expf(-expf(A_log[n])*sp);
  }
}

// ------------- conv(K=4)+SiLU+l2norm SCALES for q,k (parallel over B*T*H) -------------
__global__ __launch_bounds__(64) void conv_inv_kernel(
    const bf16* __restrict__ preq, const bf16* __restrict__ prek,
    const float* __restrict__ wqc, const float* __restrict__ wkc,
    float* __restrict__ invq, float* __restrict__ invk)
{
  const int idx = blockIdx.x; const int h = idx & 7; const int bt = idx >> 3;
  const int t = bt & (Tz-1);
  const int lane = threadIdx.x;
  const us* Q = (const us*)preq;
  const us* K = (const us*)prek;
  const int c0 = h*DKz + lane, c1 = c0 + 64;
  const bool hi = lane < 32;
  float yq0=0.f, yq1=0.f, yk0=0.f, yk1=0.f;
  #pragma unroll
  for (int i=0;i<4;i++){
    const int ti = t - 3 + i;
    if (ti >= 0){
      const size_t rowb = (size_t)(bt-3+i)*KDz;
      yq0 = fmaf(us2f(Q[rowb + c0]), wqc[c0*4+i], yq0);
      yk0 = fmaf(us2f(K[rowb + c0]), wkc[c0*4+i], yk0);
      if (hi){
        yq1 = fmaf(us2f(Q[rowb + c1]), wqc[c1*4+i], yq1);
        yk1 = fmaf(us2f(K[rowb + c1]), wkc[c1*4+i], yk1);
      }
    }
  }
  yq0 = siluf_(yq0); yk0 = siluf_(yk0);
  yq1 = hi ? siluf_(yq1) : 0.f;
  yk1 = hi ? siluf_(yk1) : 0.f;
  float ssq = yq0*yq0 + yq1*yq1;
  float ssk = yk0*yk0 + yk1*yk1;
  #pragma unroll
  for (int off=32; off>=1; off>>=1){ ssq += __shfl_xor(ssq,off); ssk += __shfl_xor(ssk,off); }
  if (lane == 0){
    invq[(size_t)bt*Hz + h] = rsqrtf(ssq + 1e-6f) * 0.10206207262f;  // * dk^-0.5
    invk[(size_t)bt*Hz + h] = rsqrtf(ssk + 1e-6f);
  }
}

// ---------------- gated delta-rule scan, split over v-columns ----------------
// Grid = Bz*Hz*8 blocks; block (bh, sp) owns v-cols [sp*24, sp*24+24).
// 192 threads: tid = j*8 + g; thread owns S[g*12 .. g*12+11][col sp*24+j].
// Phase = 8 timesteps, one barrier per phase. Cross-lane reductions over the
// 8-lane g-group are pure DPP (VALU pipe) — no DS-pipe shfl on the chain.
// k/q LDS reads are register-prefetched one step ahead.
__global__ __launch_bounds__(192) void scan_kernel(
    const bf16* __restrict__ preq, const bf16* __restrict__ prek, const bf16* __restrict__ prev,
    const float* __restrict__ wqc, const float* __restrict__ wkc, const float* __restrict__ wvc,
    const float* __restrict__ eg_, const float* __restrict__ beta,
    const float* __restrict__ invq_, const float* __restrict__ invk_,
    bf16* __restrict__ o)
{
  const int blk = blockIdx.x;
  const int bh = blk >> 3, sp = blk & 7;
  const int b = bh >> 3, h = bh & 7;
  const int tid = threadIdx.x;
  const int j = tid >> 3, g = tid & 7;
  const int jg = sp*24 + j;
  const int vc = h*DVz + jg;

  __shared__ float kq[2][8][192];   // [buf][step][96 k | 96 q]

  // ---- producer setup: thread ch = tid; ch<96 -> k channel, else q channel ----
  const bool prodK = (tid < 96);
  const int ch = prodK ? tid : (tid - 96);
  const int kcol = h*DKz + ch;
  float w0,w1,w2,w3;
  {
    const float* wc = prodK ? wkc : wqc;
    w0 = wc[kcol*4+0]; w1 = wc[kcol*4+1]; w2 = wc[kcol*4+2]; w3 = wc[kcol*4+3];
  }
  const us* PP = (const us*)(prodK ? prek : preq) + (size_t)b*Tz*KDz + kcol;
  const float* ivp = (prodK ? invk_ : invq_) + (size_t)b*Tz*Hz + h;

  // ---- consumer setup ----
  float wv0 = wvc[vc*4+0], wv1 = wvc[vc*4+1], wv2 = wvc[vc*4+2], wv3 = wvc[vc*4+3];
  const us* VP = (const us*)prev + (size_t)b*Tz*VDz + vc;
  us* op = (us*)o + (size_t)b*Tz*VDz + vc;
  const float* egp = eg_  + (size_t)b*Tz*Hz + h;
  const float* bp  = beta + (size_t)b*Tz*Hz + h;

  float S[12];
  #pragma unroll
  for (int m=0;m<12;m++) S[m]=0.f;

  float pra=0.f, prb=0.f, prc=0.f;  // producer conv ring (t-3,t-2,t-1)
  float va=0.f, vb=0.f, vcr=0.f;    // v conv ring

  // prologue: produce steps 0..7 into buf 0
  #pragma unroll
  for (int s=0;s<8;s++){
    const float raw = us2f(PP[(size_t)s*KDz]);
    const float y = fmaf(pra,w0, fmaf(prb,w1, fmaf(prc,w2, raw*w3)));
    pra=prb; prb=prc; prc=raw;
    kq[0][s][tid] = siluf_(y) * ivp[(size_t)s*Hz];
  }
  __syncthreads();

  for (int ph=0; ph<Tz/8; ph++){
    const int base = ph*8;
    const int p = ph & 1;
    // cv/eg/beta for this phase (independent of S)
    float cv[8], ce[8], cb[8];
    #pragma unroll
    for (int s=0;s<8;s++){
      const size_t r = (size_t)(base + s);
      const float rv = us2f(VP[r*VDz]);
      const float yv = fmaf(va,wv0, fmaf(vb,wv1, fmaf(vcr,wv2, rv*wv3)));
      va=vb; vb=vcr; vcr=rv;
      cv[s] = siluf_(yv);
      ce[s] = egp[r*Hz];
      cb[s] = bp[r*Hz];
    }
    // produce next phase's k,q into the other buffer
    if (base + 8 < Tz){
      #pragma unroll
      for (int s=0;s<8;s++){
        const size_t r = (size_t)(base + 8 + s);
        const float raw = us2f(PP[r*KDz]);
        const float y = fmaf(pra,w0, fmaf(prb,w1, fmaf(prc,w2, raw*w3)));
        pra=prb; prb=prc; prc=raw;
        kq[p^1][s][tid] = siluf_(y) * ivp[r*Hz];
      }
    }
    // consume 8 sequential steps; k/q slices register-prefetched 1 step ahead
    float4 ck0 = *(const float4*)&kq[p][0][g*12];
    float4 ck1 = *(const float4*)&kq[p][0][g*12+4];
    float4 ck2 = *(const float4*)&kq[p][0][g*12+8];
    float4 cq0 = *(const float4*)&kq[p][0][96+g*12];
    float4 cq1 = *(const float4*)&kq[p][0][96+g*12+4];
    float4 cq2 = *(const float4*)&kq[p][0][96+g*12+8];
    #pragma unroll
    for (int s=0;s<8;s++){
      float4 nk0,nk1,nk2,nq0,nq1,nq2;
      if (s < 7){
        nk0 = *(const float4*)&kq[p][s+1][g*12];
        nk1 = *(const float4*)&kq[p][s+1][g*12+4];
        nk2 = *(const float4*)&kq[p][s+1][g*12+8];
        nq0 = *(const float4*)&kq[p][s+1][96+g*12];
        nq1 = *(const float4*)&kq[p][s+1][96+g*12+4];
        nq2 = *(const float4*)&kq[p][s+1][96+g*12+8];
      }
      // pv = k . S (pre-decay), 4 parallel chains then tree + DPP group-sum
      float a0,a1,a2,a3;
      a0 = ck0.x*S[0]; a1 = ck0.y*S[1]; a2 = ck0.z*S[2]; a3 = ck0.w*S[3];
      a0 = fmaf(ck1.x,S[4],a0); a1 = fmaf(ck1.y,S[5],a1); a2 = fmaf(ck1.z,S[6],a2); a3 = fmaf(ck1.w,S[7],a3);
      a0 = fmaf(ck2.x,S[8],a0); a1 = fmaf(ck2.y,S[9],a1); a2 = fmaf(ck2.z,S[10],a2); a3 = fmaf(ck2.w,S[11],a3);
      const float pv = gsum8((a0+a1)+(a2+a3));
      const float eg = ce[s];
      const float delta = (cv[s] - eg*pv)*cb[s];
      // S update + o partials
      float o0,o1,o2,o3;
      float t0;
      t0 = fmaf(eg,S[0], ck0.x*delta); S[0]=t0; o0 = cq0.x*t0;
      t0 = fmaf(eg,S[1], ck0.y*delta); S[1]=t0; o1 = cq0.y*t0;
      t0 = fmaf(eg,S[2], ck0.z*delta); S[2]=t0; o2 = cq0.z*t0;
      t0 = fmaf(eg,S[3], ck0.w*delta); S[3]=t0; o3 = cq0.w*t0;
      t0 = fmaf(eg,S[4], ck1.x*delta); S[4]=t0; o0 = fmaf(cq1.x,t0,o0);
      t0 = fmaf(eg,S[5], ck1.y*delta); S[5]=t0; o1 = fmaf(cq1.y,t0,o1);
      t0 = fmaf(eg,S[6], ck1.z*delta); S[6]=t0; o2 = fmaf(cq1.z,t0,o2);
      t0 = fmaf(eg,S[7], ck1.w*delta); S[7]=t0; o3 = fmaf(cq1.w,t0,o3);
      t0 = fmaf(eg,S[8], ck2.x*delta); S[8]=t0; o0 = fmaf(cq2.x,t0,o0);
      t0 = fmaf(eg,S[9], ck2.y*delta); S[9]=t0; o1 = fmaf(cq2.y,t0,o1);
      t0 = fmaf(eg,S[10],ck2.z*delta); S[10]=t0; o2 = fmaf(cq2.z,t0,o2);
      t0 = fmaf(eg,S[11],ck2.w*delta); S[11]=t0; o3 = fmaf(cq2.w,t0,o3);
      const float po = gsum8((o0+o1)+(o2+o3));
      if (g == 0) op[(size_t)(base+s)*VDz] = f2bs(po);
      if (s < 7){
        ck0=nk0; ck1=nk1; ck2=nk2; cq0=nq0; cq1=nq1; cq2=nq2;
      }
    }
    __syncthreads();
  }
}

// ---------------- output gate: rmsnorm_dv(o) * silu(gout) ----------------
__global__ __launch_bounds__(64) void gate_out_kernel(
    const bf16* __restrict__ o, const bf16* __restrict__ gout,
    const float* __restrict__ onw, bf16* __restrict__ og)
{
  const size_t base = (size_t)blockIdx.x * DVz;
  const int lane = threadIdx.x;
  const us* O = (const us*)o;
  float x0 = us2f(O[base+lane]), x1 = us2f(O[base+64+lane]), x2 = us2f(O[base+128+lane]);
  float ss = x0*x0 + x1*x1 + x2*x2;
  #pragma unroll
  for (int off=32; off>=1; off>>=1) ss += __shfl_xor(ss, off);
  const float inv = rsqrtf(ss*(1.f/DVz) + 1e-6f);
  const us* G = (const us*)gout;
  us* OG = (us*)og;
  float xs[3] = {x0, x1, x2};
  #pragma unroll
  for (int i=0;i<3;i++){
    const int c = lane + 64*i;
    const float gv = us2f(G[base+c]);
    OG[base+c] = f2bs(xs[i]*inv*onw[c] * siluf_(gv));
  }
}

extern "C" void kernel_launch(void* const* d_in, const int* in_sizes, int n_in,
                              void* d_out, int out_size, void* d_ws, size_t ws_size,
                              hipStream_t stream) {
  const float* x        = (const float*)d_in[0];
  const float* Wq       = (const float*)d_in[1];
  const float* Wk       = (const float*)d_in[2];
  const float* Wv       = (const float*)d_in[3];
  const float* Wb       = (const float*)d_in[4];
  const float* Wa       = (const float*)d_in[5];
  const float* A_log    = (const float*)d_in[6];
  const float* dt_bias  = (const float*)d_in[7];
  const float* conv_q_w = (const float*)d_in[8];
  const float* conv_k_w = (const float*)d_in[9];
  const float* conv_v_w = (const float*)d_in[10];
  const float* Wg       = (const float*)d_in[11];
  const float* onorm_w  = (const float*)d_in[12];
  const float* Wo       = (const float*)d_in[13];
  const float* norm1_w  = (const float*)d_in[14];
  const float* norm2_w  = (const float*)d_in[15];
  const float* Wgate    = (const float*)d_in[16];
  const float* Wup      = (const float*)d_in[17];
  const float* Wdown    = (const float*)d_in[18];

  char* W = (char*)d_ws;
  // bf16-transposed weights (rewritten every launch; deterministic)
  us* WoT    = (us*)(W + 0);           // [1024,1536]  3.15 MB
  us* WgateT = (us*)(W + 3145728);     // [4096,1024]  8.39 MB
  us* WupT   = (us*)(W + 11534336);    // [4096,1024]  8.39 MB
  us* WdownT = (us*)(W + 19922944);    // [1024,4096]  8.39 MB
  us* WqT    = (us*)(W + 28311552);    // [768,1024]   1.57 MB (dead after proj)
  us* WkT    = (us*)(W + 29884416);    // [768,1024]
  us* WvT    = (us*)(W + 31457280);    // [1536,1024]  3.15 MB
  us* WgT    = (us*)(W + 34603008);    // [1536,1024]  -> ends 37,748,736
  // activations
  bf16*  h_    = (bf16*) (W + 37748736);   // [8192,1024]; dead after gout GEMM
  bf16*  preq  = (bf16*) (W + 54525952);   // [8192,768];  dead after scan
  bf16*  prek  = (bf16*) (W + 67108864);   // [8192,768];  dead after scan
  bf16*  prev  = (bf16*) (W + 79691776);   // [8192,1536]; dead after scan
  float* beta_ = (float*)(W + 104857600);  // [8192,8]
  float* eg_   = (float*)(W + 105119744);  // [8192,8]
  float* invq_ = (float*)(W + 105381888);  // [8192,8]
  float* invk_ = (float*)(W + 105644032);  // [8192,8]
  bf16*  gout  = (bf16*) (W + 105906176);  // [8192,1536]; -> ends 131,072,000 (PEAK)
  // aliases over dead regions
  bf16*  o_    = (bf16*) (W + 28311552);   // [8192,1536] over WqT..WgT+h_ (dead pre-scan)
  bf16*  og    = (bf16*) (W + 54525952);   // [8192,1536] over preq+prek (dead post-scan)
  float* x2    = (float*)(W + 79691776);   // [8192,1024] f32 over prev+scalars+gout-head
  bf16*  h2    = (bf16*) (W + 113246208);  // [8192,1024] over gout tail (dead)
  bf16*  gateC = (bf16*) (W + 28311552);   // [2048,4096] over o_ region (dead post-gating)

  // 0. weight prep (transpose + f32->bf16)
  wprep_kernel<<<dim3(48,32),  256, 0, stream>>>(Wo,    WoT,    1536, 1024);
  wprep_kernel<<<dim3(32,128), 256, 0, stream>>>(Wgate, WgateT, 1024, 4096);
  wprep_kernel<<<dim3(32,128), 256, 0, stream>>>(Wup,   WupT,   1024, 4096);
  wprep_kernel<<<dim3(128,32), 256, 0, stream>>>(Wdown, WdownT, 4096, 1024);
  wprep_kernel<<<dim3(32,24),  256, 0, stream>>>(Wq,    WqT,    1024, 768);
  wprep_kernel<<<dim3(32,24),  256, 0, stream>>>(Wk,    WkT,    1024, 768);
  wprep_kernel<<<dim3(32,48),  256, 0, stream>>>(Wv,    WvT,    1024, 1536);
  wprep_kernel<<<dim3(32,48),  256, 0, stream>>>(Wg,    WgT,    1024, 1536);
  // 1. pre-norm
  rmsnorm_kernel<<<BTz, 256, 0, stream>>>(x, norm1_w, h_);
  // 2. projections + beta/eg
  mgemm_kernel<0><<<dim3(6,64),  256, 0, stream>>>(h_, WqT, nullptr, preq, BTz, KDz, Dz);
  mgemm_kernel<0><<<dim3(6,64),  256, 0, stream>>>(h_, WkT, nullptr, prek, BTz, KDz, Dz);
  mgemm_kernel<0><<<dim3(12,64), 256, 0, stream>>>(h_, WvT, nullptr, prev, BTz, VDz, Dz);
  beta_g_kernel<<<BTz, 256, 0, stream>>>(h_, Wb, Wa, A_log, dt_bias, beta_, eg_);
  mgemm_kernel<0><<<dim3(12,64), 256, 0, stream>>>(h_, WgT, nullptr, gout, BTz, VDz, Dz);
  // 3. l2norm scales, then fused conv+scan (256 blocks x 192 threads, 8-step phases)
  conv_inv_kernel<<<BTz*Hz, 64, 0, stream>>>(preq, prek, conv_q_w, conv_k_w, invq_, invk_);
  scan_kernel<<<Bz*Hz*8, 192, 0, stream>>>(preq, prek, prev, conv_q_w, conv_k_w, conv_v_w,
                                           eg_, beta_, invq_, invk_, o_);
  // 4. output gating + Wo projection with residual
  gate_out_kernel<<<BTz*Hz, 64, 0, stream>>>(o_, gout, onorm_w, og);
  mgemm_kernel<1><<<dim3(8,64), 256, 0, stream>>>(og, WoT, x, x2, BTz, Dz, VDz);
  // 5. MLP, chunked over 4 x 2048 rows
  rmsnorm_kernel<<<BTz, 256, 0, stream>>>(x2, norm2_w, h2);
  for (int c = 0; c < 4; c++){
    const bf16*  h2c = h2 + (size_t)c*2048*Dz;
    const float* x2c = x2 + (size_t)c*2048*Dz;
    float*       out = (float*)d_out + (size_t)c*2048*Dz;
    mgemm_kernel<0><<<dim3(32,16), 256, 0, stream>>>(h2c, WgateT, nullptr, gateC, 2048, Iz, Dz);
    mgemm_kernel<3><<<dim3(32,16), 256, 0, stream>>>(h2c, WupT, gateC, gateC, 2048, Iz, Dz);
    mgemm_kernel<1><<<dim3(8,16),  256, 0, stream>>>(gateC, WdownT, x2c, out, 2048, Dz, Iz);
  }
}

// Round 9
// 1713.405 us; speedup vs baseline: 5.5817x; 1.3283x over previous
//
#include <hip/hip_runtime.h>
#include <hip/hip_bf16.h>

typedef __hip_bfloat16 bf16;
typedef unsigned short us;
typedef short short8v __attribute__((ext_vector_type(8)));
typedef float f32x4 __attribute__((ext_vector_type(4)));
typedef __attribute__((address_space(3))) unsigned int lds_u32;
typedef __attribute__((address_space(1))) const unsigned int glb_u32;

#define GLOAD16(gp, lp) __builtin_amdgcn_global_load_lds((glb_u32*)(gp), (lds_u32*)(lp), 16, 0, 0)

#define Bz 4
#define Tz 2048
#define Dz 1024
#define Hz 8
#define DKz 96
#define DVz 192
#define KDz 768
#define VDz 1536
#define Iz 4096
#define BTz (Bz*Tz)

static __device__ __forceinline__ float us2f(us s){
  return __uint_as_float(((unsigned)s) << 16);
}
static __device__ __forceinline__ us f2bs(float f){
  bf16 t = __float2bfloat16(f);
  return *(us*)&t;
}
static __device__ __forceinline__ float sigmoidf_(float x){ return 1.f/(1.f+expf(-x)); }
static __device__ __forceinline__ float siluf_(float x){ return x*sigmoidf_(x); }

// DPP-based 8-lane-group sum (groups = lanes [8m..8m+7]):
#define DPPADD(x, ctrl) \
  ((x) + __int_as_float(__builtin_amdgcn_update_dpp(0, __float_as_int(x), (ctrl), 0xF, 0xF, true)))
static __device__ __forceinline__ float gsum8(float x){
  x = DPPADD(x, 0xB1);   // quad_perm [1,0,3,2]  : + lane^1
  x = DPPADD(x, 0x4E);   // quad_perm [2,3,0,1]  : + lane^2
  x = DPPADD(x, 0x141);  // row_half_mirror      : + other quad's sum
  return x;
}

// ---------------- weight prep: W[K,N] f32 -> WT[N,K] bf16 ----------------
__global__ __launch_bounds__(256) void wprep_kernel(
    const float* __restrict__ Wsrc, us* __restrict__ WTdst, int K, int N)
{
  __shared__ float t[32][33];
  const int k0 = blockIdx.x*32, n0 = blockIdx.y*32;
  const int c = threadIdx.x & 31, r8 = threadIdx.x >> 5;
  #pragma unroll
  for (int i=0;i<4;i++){
    const int r = r8 + i*8;
    t[r][c] = Wsrc[(size_t)(k0+r)*N + n0 + c];
  }
  __syncthreads();
  #pragma unroll
  for (int i=0;i<4;i++){
    const int r = r8 + i*8;
    WTdst[(size_t)(n0+r)*K + k0 + c] = f2bs(t[c][r]);
  }
}

// ---------------- RMSNorm (f32 in -> bf16 out, f32 weights) ----------------
__global__ __launch_bounds__(256) void rmsnorm_kernel(
    const float* __restrict__ x, const float* __restrict__ w, bf16* __restrict__ out)
{
  const int row = blockIdx.x;
  const float* xr = x + (size_t)row*Dz;
  const int i0 = threadIdx.x*4;
  float4 xv = *(const float4*)(xr + i0);
  float ss = xv.x*xv.x+xv.y*xv.y+xv.z*xv.z+xv.w*xv.w;
  #pragma unroll
  for (int off=32; off>=1; off>>=1) ss += __shfl_xor(ss, off);
  __shared__ float red[4];
  if ((threadIdx.x&63)==0) red[threadIdx.x>>6] = ss;
  __syncthreads();
  ss = red[0]+red[1]+red[2]+red[3];
  const float inv = rsqrtf(ss*(1.f/Dz) + 1e-6f);
  float4 wv = *(const float4*)(w + i0);
  ushort4 ov;
  ov.x=f2bs(xv.x*inv*wv.x); ov.y=f2bs(xv.y*inv*wv.y);
  ov.z=f2bs(xv.z*inv*wv.z); ov.w=f2bs(xv.w*inv*wv.w);
  *(ushort4*)((us*)out + (size_t)row*Dz + i0) = ov;
}

// ------------- MFMA GEMM: C[M,N] = A[M,K](bf16) @ BT[N,K](bf16)^T (+res) -------------
template<int MODE>
__global__ __launch_bounds__(256, 2) void mgemm_kernel(
    const bf16* __restrict__ A, const us* __restrict__ BT,
    const void* __restrict__ res, void* __restrict__ Cout,
    int M, int N, int K)
{
  __shared__ us As[128*64];
  __shared__ us Bs[128*64];
  const int m0 = blockIdx.y*128, n0 = blockIdx.x*128;
  const int tid = threadIdx.x;
  const int wid = tid >> 6, lane = tid & 63;
  const int wr = wid >> 1, wc = wid & 1;
  const int fq = lane >> 4, fr = lane & 15;

  const us* Ab = (const us*)A + (size_t)(m0 + (tid>>3))*K + (tid&7)*8;
  const us* Bb = BT + (size_t)(n0 + (tid>>3))*K + (tid&7)*8;
  char* AsB = (char*)As;
  char* BsB = (char*)Bs;
  const int ldsoff = wid*1024;

  f32x4 acc[4][4] = {};
  const int nk = K >> 6;
  for (int kt = 0; kt < nk; ++kt){
    const int kb = kt*64;
    #pragma unroll
    for (int i=0;i<4;i++){
      GLOAD16(Ab + (size_t)(32*i)*K + kb, AsB + ldsoff + i*4096);
      GLOAD16(Bb + (size_t)(32*i)*K + kb, BsB + ldsoff + i*4096);
    }
    __syncthreads();
    #pragma unroll
    for (int ks=0; ks<2; ks++){
      short8v af[4], bf[4];
      #pragma unroll
      for (int r=0;r<4;r++)
        af[r] = *(const short8v*)&As[(wr*64 + r*16 + fr)*64 + ks*32 + fq*8];
      #pragma unroll
      for (int c=0;c<4;c++)
        bf[c] = *(const short8v*)&Bs[(wc*64 + c*16 + fr)*64 + ks*32 + fq*8];
      #pragma unroll
      for (int r=0;r<4;r++)
        #pragma unroll
        for (int c=0;c<4;c++)
          acc[r][c] = __builtin_amdgcn_mfma_f32_16x16x32_bf16(af[r], bf[c], acc[r][c], 0, 0, 0);
    }
    __syncthreads();
  }
  #pragma unroll
  for (int r=0;r<4;r++){
    #pragma unroll
    for (int c=0;c<4;c++){
      const int col = n0 + wc*64 + c*16 + fr;
      #pragma unroll
      for (int jj=0;jj<4;jj++){
        const int row = m0 + wr*64 + r*16 + fq*4 + jj;
        const size_t idx = (size_t)row*N + col;
        const float a = acc[r][c][jj];
        if (MODE==0){
          ((us*)Cout)[idx] = f2bs(a);
        } else if (MODE==1){
          ((float*)Cout)[idx] = a + ((const float*)res)[idx];
        } else {
          ((us*)Cout)[idx] = f2bs(siluf_(us2f(((const us*)res)[idx]))*a);
        }
      }
    }
  }
}

// ------- beta / exp(g) projections -> meta.x = exp(g), meta.y = beta -------
__global__ __launch_bounds__(256) void beta_g_kernel(
    const bf16* __restrict__ hh, const float* __restrict__ Wb, const float* __restrict__ Wa,
    const float* __restrict__ A_log, const float* __restrict__ dt_bias,
    float4* __restrict__ meta)
{
  const int row = blockIdx.x;
  const us* hr = (const us*)hh + (size_t)row*Dz;
  float ab[8]={0,0,0,0,0,0,0,0}, aa[8]={0,0,0,0,0,0,0,0};
  for (int kk=threadIdx.x; kk<Dz; kk+=256){
    const float hv = us2f(hr[kk]);
    float4 b0 = *(const float4*)(Wb + kk*8);
    float4 b1 = *(const float4*)(Wb + kk*8 + 4);
    float4 a0 = *(const float4*)(Wa + kk*8);
    float4 a1 = *(const float4*)(Wa + kk*8 + 4);
    ab[0]=fmaf(hv,b0.x,ab[0]); ab[1]=fmaf(hv,b0.y,ab[1]);
    ab[2]=fmaf(hv,b0.z,ab[2]); ab[3]=fmaf(hv,b0.w,ab[3]);
    ab[4]=fmaf(hv,b1.x,ab[4]); ab[5]=fmaf(hv,b1.y,ab[5]);
    ab[6]=fmaf(hv,b1.z,ab[6]); ab[7]=fmaf(hv,b1.w,ab[7]);
    aa[0]=fmaf(hv,a0.x,aa[0]); aa[1]=fmaf(hv,a0.y,aa[1]);
    aa[2]=fmaf(hv,a0.z,aa[2]); aa[3]=fmaf(hv,a0.w,aa[3]);
    aa[4]=fmaf(hv,a1.x,aa[4]); aa[5]=fmaf(hv,a1.y,aa[5]);
    aa[6]=fmaf(hv,a1.z,aa[6]); aa[7]=fmaf(hv,a1.w,aa[7]);
  }
  #pragma unroll
  for (int off=32; off>=1; off>>=1){
    #pragma unroll
    for (int n=0;n<8;n++){ ab[n]+=__shfl_xor(ab[n],off); aa[n]+=__shfl_xor(aa[n],off); }
  }
  __shared__ float red[4][16];
  const int wv = threadIdx.x>>6, ln = threadIdx.x&63;
  if (ln==0){
    #pragma unroll
    for (int n=0;n<8;n++){ red[wv][n]=ab[n]; red[wv][8+n]=aa[n]; }
  }
  __syncthreads();
  if (threadIdx.x < 8){
    const int n = threadIdx.x;
    float sb = red[0][n]+red[1][n]+red[2][n]+red[3][n];
    float sa = red[0][8+n]+red[1][8+n]+red[2][8+n]+red[3][8+n];
    float* mp = (float*)&meta[(size_t)row*Hz + n];
    mp[1] = 1.f/(1.f+expf(-sb));
    float xx = sa + dt_bias[n];
    float sp = (xx > 20.f) ? xx : log1pf(expf(xx));
    mp[0] = expf(-expf(A_log[n])*sp);
  }
}

// ------- conv(K=4)+SiLU+l2norm scales -> meta.z = invq, meta.w = invk -------
__global__ __launch_bounds__(64) void conv_inv_kernel(
    const bf16* __restrict__ preq, const bf16* __restrict__ prek,
    const float* __restrict__ wqc, const float* __restrict__ wkc,
    float4* __restrict__ meta)
{
  const int idx = blockIdx.x; const int h = idx & 7; const int bt = idx >> 3;
  const int t = bt & (Tz-1);
  const int lane = threadIdx.x;
  const us* Q = (const us*)preq;
  const us* K = (const us*)prek;
  const int c0 = h*DKz + lane, c1 = c0 + 64;
  const bool hi = lane < 32;
  float yq0=0.f, yq1=0.f, yk0=0.f, yk1=0.f;
  #pragma unroll
  for (int i=0;i<4;i++){
    const int ti = t - 3 + i;
    if (ti >= 0){
      const size_t rowb = (size_t)(bt-3+i)*KDz;
      yq0 = fmaf(us2f(Q[rowb + c0]), wqc[c0*4+i], yq0);
      yk0 = fmaf(us2f(K[rowb + c0]), wkc[c0*4+i], yk0);
      if (hi){
        yq1 = fmaf(us2f(Q[rowb + c1]), wqc[c1*4+i], yq1);
        yk1 = fmaf(us2f(K[rowb + c1]), wkc[c1*4+i], yk1);
      }
    }
  }
  yq0 = siluf_(yq0); yk0 = siluf_(yk0);
  yq1 = hi ? siluf_(yq1) : 0.f;
  yk1 = hi ? siluf_(yk1) : 0.f;
  float ssq = yq0*yq0 + yq1*yq1;
  float ssk = yk0*yk0 + yk1*yk1;
  #pragma unroll
  for (int off=32; off>=1; off>>=1){ ssq += __shfl_xor(ssq,off); ssk += __shfl_xor(ssk,off); }
  if (lane == 0){
    float* mp = (float*)&meta[(size_t)bt*Hz + h];
    mp[2] = rsqrtf(ssq + 1e-6f) * 0.10206207262f;  // invq * dk^-0.5
    mp[3] = rsqrtf(ssk + 1e-6f);                   // invk
  }
}

// ---------------- gated delta-rule scan, v-split + phase-pipelined ----------------
// Grid = Bz*Hz*8 blocks; block (bh, sp) owns v-cols [sp*24, sp*24+24).
// 192 threads: tid = j*8 + g; thread owns S[g*12 .. g*12+11][col sp*24+j].
// Phase = 8 steps. Pipeline: (1) issue ALL next-phase global loads into named
// regs; (2) consume 8 steps from LDS (DPP reductions, 1-step LDS prefetch);
// (3) produce next phase's kq + cv/ce/cb from the prefetched regs; (4) barrier.
// launch_bounds(192,1): 1 block/CU anyway -> let compiler keep loads in flight.
__global__ __launch_bounds__(192, 1) void scan_kernel(
    const bf16* __restrict__ preq, const bf16* __restrict__ prek, const bf16* __restrict__ prev,
    const float* __restrict__ wqc, const float* __restrict__ wkc, const float* __restrict__ wvc,
    const float4* __restrict__ meta, bf16* __restrict__ o)
{
  const int blk = blockIdx.x;
  const int bh = blk >> 3, sp = blk & 7;
  const int b = bh >> 3, h = bh & 7;
  const int tid = threadIdx.x;
  const int g = tid & 7;
  const int j = tid >> 3;
  const int vc = h*DVz + sp*24 + j;

  __shared__ float kq[2][8][192];   // [buf][step][96 k | 96 q]

  const bool prodK = (tid < 96);
  const int ch = prodK ? tid : (tid - 96);
  const int kcol = h*DKz + ch;
  float w0,w1,w2,w3;
  {
    const float* wc = prodK ? wkc : wqc;
    w0 = wc[kcol*4+0]; w1 = wc[kcol*4+1]; w2 = wc[kcol*4+2]; w3 = wc[kcol*4+3];
  }
  const us* PP = (const us*)(prodK ? prek : preq) + (size_t)b*Tz*KDz + kcol;

  const float wv0 = wvc[vc*4+0], wv1 = wvc[vc*4+1], wv2 = wvc[vc*4+2], wv3 = wvc[vc*4+3];
  const us* VP = (const us*)prev + (size_t)b*Tz*VDz + vc;
  us* op = (us*)o + (size_t)b*Tz*VDz + vc;
  const float4* MP = meta + (size_t)b*Tz*Hz + h;

  float S[12];
  #pragma unroll
  for (int m=0;m<12;m++) S[m]=0.f;

  float pra=0.f, prb=0.f, prc=0.f;  // producer conv ring
  float va=0.f, vb=0.f, vcr=0.f;    // v conv ring
  float cv[8], ce[8], cb[8];

  // ---- prologue: load + produce phase 0 ----
  {
    float nraw[8], nv[8]; float4 nm[8];
    #pragma unroll
    for (int s=0;s<8;s++){
      nraw[s] = us2f(PP[(size_t)s*KDz]);
      nv[s]   = us2f(VP[(size_t)s*VDz]);
      nm[s]   = MP[(size_t)s*Hz];
    }
    #pragma unroll
    for (int s=0;s<8;s++){
      const float y = fmaf(pra,w0, fmaf(prb,w1, fmaf(prc,w2, nraw[s]*w3)));
      pra=prb; prb=prc; prc=nraw[s];
      kq[0][s][tid] = siluf_(y) * (prodK ? nm[s].w : nm[s].z);
      const float yv = fmaf(va,wv0, fmaf(vb,wv1, fmaf(vcr,wv2, nv[s]*wv3)));
      va=vb; vb=vcr; vcr=nv[s];
      cv[s] = siluf_(yv); ce[s] = nm[s].x; cb[s] = nm[s].y;
    }
  }
  __syncthreads();

  for (int ph=0; ph<Tz/8; ph++){
    const int base = ph*8;
    const int p = ph & 1;
    const bool more = (base + 8 < Tz);
    const int nb = more ? base + 8 : base;   // clamp; values unused when !more
    // (1) issue next-phase loads (independent -> compiler issues at top)
    float nraw[8], nv[8]; float4 nm[8];
    #pragma unroll
    for (int s=0;s<8;s++){
      nraw[s] = us2f(PP[(size_t)(nb+s)*KDz]);
      nv[s]   = us2f(VP[(size_t)(nb+s)*VDz]);
      nm[s]   = MP[(size_t)(nb+s)*Hz];
    }
    // (2) consume 8 steps; k/q slices register-prefetched 1 step ahead
    float4 ck0 = *(const float4*)&kq[p][0][g*12];
    float4 ck1 = *(const float4*)&kq[p][0][g*12+4];
    float4 ck2 = *(const float4*)&kq[p][0][g*12+8];
    float4 cq0 = *(const float4*)&kq[p][0][96+g*12];
    float4 cq1 = *(const float4*)&kq[p][0][96+g*12+4];
    float4 cq2 = *(const float4*)&kq[p][0][96+g*12+8];
    #pragma unroll
    for (int s=0;s<8;s++){
      float4 nk0,nk1,nk2,nq0,nq1,nq2;
      if (s < 7){
        nk0 = *(const float4*)&kq[p][s+1][g*12];
        nk1 = *(const float4*)&kq[p][s+1][g*12+4];
        nk2 = *(const float4*)&kq[p][s+1][g*12+8];
        nq0 = *(const float4*)&kq[p][s+1][96+g*12];
        nq1 = *(const float4*)&kq[p][s+1][96+g*12+4];
        nq2 = *(const float4*)&kq[p][s+1][96+g*12+8];
      }
      float a0,a1,a2,a3;
      a0 = ck0.x*S[0]; a1 = ck0.y*S[1]; a2 = ck0.z*S[2]; a3 = ck0.w*S[3];
      a0 = fmaf(ck1.x,S[4],a0); a1 = fmaf(ck1.y,S[5],a1); a2 = fmaf(ck1.z,S[6],a2); a3 = fmaf(ck1.w,S[7],a3);
      a0 = fmaf(ck2.x,S[8],a0); a1 = fmaf(ck2.y,S[9],a1); a2 = fmaf(ck2.z,S[10],a2); a3 = fmaf(ck2.w,S[11],a3);
      const float pv = gsum8((a0+a1)+(a2+a3));
      const float eg = ce[s];
      const float delta = (cv[s] - eg*pv)*cb[s];
      float o0,o1,o2,o3;
      float t0;
      t0 = fmaf(eg,S[0], ck0.x*delta); S[0]=t0; o0 = cq0.x*t0;
      t0 = fmaf(eg,S[1], ck0.y*delta); S[1]=t0; o1 = cq0.y*t0;
      t0 = fmaf(eg,S[2], ck0.z*delta); S[2]=t0; o2 = cq0.z*t0;
      t0 = fmaf(eg,S[3], ck0.w*delta); S[3]=t0; o3 = cq0.w*t0;
      t0 = fmaf(eg,S[4], ck1.x*delta); S[4]=t0; o0 = fmaf(cq1.x,t0,o0);
      t0 = fmaf(eg,S[5], ck1.y*delta); S[5]=t0; o1 = fmaf(cq1.y,t0,o1);
      t0 = fmaf(eg,S[6], ck1.z*delta); S[6]=t0; o2 = fmaf(cq1.z,t0,o2);
      t0 = fmaf(eg,S[7], ck1.w*delta); S[7]=t0; o3 = fmaf(cq1.w,t0,o3);
      t0 = fmaf(eg,S[8], ck2.x*delta); S[8]=t0; o0 = fmaf(cq2.x,t0,o0);
      t0 = fmaf(eg,S[9], ck2.y*delta); S[9]=t0; o1 = fmaf(cq2.y,t0,o1);
      t0 = fmaf(eg,S[10],ck2.z*delta); S[10]=t0; o2 = fmaf(cq2.z,t0,o2);
      t0 = fmaf(eg,S[11],ck2.w*delta); S[11]=t0; o3 = fmaf(cq2.w,t0,o3);
      const float po = gsum8((o0+o1)+(o2+o3));
      if (g == 0) op[(size_t)(base+s)*VDz] = f2bs(po);
      if (s < 7){
        ck0=nk0; ck1=nk1; ck2=nk2; cq0=nq0; cq1=nq1; cq2=nq2;
      }
    }
    // (3) produce next phase from prefetched registers
    if (more){
      #pragma unroll
      for (int s=0;s<8;s++){
        const float y = fmaf(pra,w0, fmaf(prb,w1, fmaf(prc,w2, nraw[s]*w3)));
        pra=prb; prb=prc; prc=nraw[s];
        kq[p^1][s][tid] = siluf_(y) * (prodK ? nm[s].w : nm[s].z);
        const float yv = fmaf(va,wv0, fmaf(vb,wv1, fmaf(vcr,wv2, nv[s]*wv3)));
        va=vb; vb=vcr; vcr=nv[s];
        cv[s] = siluf_(yv); ce[s] = nm[s].x; cb[s] = nm[s].y;
      }
    }
    __syncthreads();
  }
}

// ---------------- output gate: rmsnorm_dv(o) * silu(gout) ----------------
__global__ __launch_bounds__(64) void gate_out_kernel(
    const bf16* __restrict__ o, const bf16* __restrict__ gout,
    const float* __restrict__ onw, bf16* __restrict__ og)
{
  const size_t base = (size_t)blockIdx.x * DVz;
  const int lane = threadIdx.x;
  const us* O = (const us*)o;
  float x0 = us2f(O[base+lane]), x1 = us2f(O[base+64+lane]), x2 = us2f(O[base+128+lane]);
  float ss = x0*x0 + x1*x1 + x2*x2;
  #pragma unroll
  for (int off=32; off>=1; off>>=1) ss += __shfl_xor(ss, off);
  const float inv = rsqrtf(ss*(1.f/DVz) + 1e-6f);
  const us* G = (const us*)gout;
  us* OG = (us*)og;
  float xs[3] = {x0, x1, x2};
  #pragma unroll
  for (int i=0;i<3;i++){
    const int c = lane + 64*i;
    const float gv = us2f(G[base+c]);
    OG[base+c] = f2bs(xs[i]*inv*onw[c] * siluf_(gv));
  }
}

extern "C" void kernel_launch(void* const* d_in, const int* in_sizes, int n_in,
                              void* d_out, int out_size, void* d_ws, size_t ws_size,
                              hipStream_t stream) {
  const float* x        = (const float*)d_in[0];
  const float* Wq       = (const float*)d_in[1];
  const float* Wk       = (const float*)d_in[2];
  const float* Wv       = (const float*)d_in[3];
  const float* Wb       = (const float*)d_in[4];
  const float* Wa       = (const float*)d_in[5];
  const float* A_log    = (const float*)d_in[6];
  const float* dt_bias  = (const float*)d_in[7];
  const float* conv_q_w = (const float*)d_in[8];
  const float* conv_k_w = (const float*)d_in[9];
  const float* conv_v_w = (const float*)d_in[10];
  const float* Wg       = (const float*)d_in[11];
  const float* onorm_w  = (const float*)d_in[12];
  const float* Wo       = (const float*)d_in[13];
  const float* norm1_w  = (const float*)d_in[14];
  const float* norm2_w  = (const float*)d_in[15];
  const float* Wgate    = (const float*)d_in[16];
  const float* Wup      = (const float*)d_in[17];
  const float* Wdown    = (const float*)d_in[18];

  char* W = (char*)d_ws;
  // bf16-transposed weights (rewritten every launch; deterministic)
  us* WoT    = (us*)(W + 0);           // [1024,1536]  3.15 MB
  us* WgateT = (us*)(W + 3145728);     // [4096,1024]  8.39 MB
  us* WupT   = (us*)(W + 11534336);    // [4096,1024]  8.39 MB
  us* WdownT = (us*)(W + 19922944);    // [1024,4096]  8.39 MB
  us* WqT    = (us*)(W + 28311552);    // [768,1024]   1.57 MB (dead after proj)
  us* WkT    = (us*)(W + 29884416);    // [768,1024]
  us* WvT    = (us*)(W + 31457280);    // [1536,1024]  3.15 MB
  us* WgT    = (us*)(W + 34603008);    // [1536,1024]  -> ends 37,748,736
  // activations
  bf16*   h_   = (bf16*) (W + 37748736);   // [8192,1024]; dead after gout GEMM
  bf16*   preq = (bf16*) (W + 54525952);   // [8192,768];  dead after scan
  bf16*   prek = (bf16*) (W + 67108864);   // [8192,768];  dead after scan
  bf16*   prev = (bf16*) (W + 79691776);   // [8192,1536]; dead after scan
  float4* meta = (float4*)(W + 104857600); // [8192,8] float4 -> ends 105,906,176
  bf16*   gout = (bf16*) (W + 105906176);  // [8192,1536]; -> ends 131,072,000 (PEAK)
  // aliases over dead regions
  bf16*  o_    = (bf16*) (W + 28311552);   // [8192,1536] over WqT..WgT+h_ (dead pre-scan)
  bf16*  og    = (bf16*) (W + 54525952);   // [8192,1536] over preq+prek (dead post-scan)
  float* x2    = (float*)(W + 79691776);   // [8192,1024] f32 over prev+meta+gout-head
  bf16*  h2    = (bf16*) (W + 113246208);  // [8192,1024] over gout tail (dead)
  bf16*  gateC = (bf16*) (W + 28311552);   // [2048,4096] over o_ region (dead post-gating)

  // 0. weight prep (transpose + f32->bf16)
  wprep_kernel<<<dim3(48,32),  256, 0, stream>>>(Wo,    WoT,    1536, 1024);
  wprep_kernel<<<dim3(32,128), 256, 0, stream>>>(Wgate, WgateT, 1024, 4096);
  wprep_kernel<<<dim3(32,128), 256, 0, stream>>>(Wup,   WupT,   1024, 4096);
  wprep_kernel<<<dim3(128,32), 256, 0, stream>>>(Wdown, WdownT, 4096, 1024);
  wprep_kernel<<<dim3(32,24),  256, 0, stream>>>(Wq,    WqT,    1024, 768);
  wprep_kernel<<<dim3(32,24),  256, 0, stream>>>(Wk,    WkT,    1024, 768);
  wprep_kernel<<<dim3(32,48),  256, 0, stream>>>(Wv,    WvT,    1024, 1536);
  wprep_kernel<<<dim3(32,48),  256, 0, stream>>>(Wg,    WgT,    1024, 1536);
  // 1. pre-norm
  rmsnorm_kernel<<<BTz, 256, 0, stream>>>(x, norm1_w, h_);
  // 2. projections + meta (eg, beta)
  mgemm_kernel<0><<<dim3(6,64),  256, 0, stream>>>(h_, WqT, nullptr, preq, BTz, KDz, Dz);
  mgemm_kernel<0><<<dim3(6,64),  256, 0, stream>>>(h_, WkT, nullptr, prek, BTz, KDz, Dz);
  mgemm_kernel<0><<<dim3(12,64), 256, 0, stream>>>(h_, WvT, nullptr, prev, BTz, VDz, Dz);
  beta_g_kernel<<<BTz, 256, 0, stream>>>(h_, Wb, Wa, A_log, dt_bias, meta);
  mgemm_kernel<0><<<dim3(12,64), 256, 0, stream>>>(h_, WgT, nullptr, gout, BTz, VDz, Dz);
  // 3. l2norm scales into meta (invq, invk), then fused conv+scan
  conv_inv_kernel<<<BTz*Hz, 64, 0, stream>>>(preq, prek, conv_q_w, conv_k_w, meta);
  scan_kernel<<<Bz*Hz*8, 192, 0, stream>>>(preq, prek, prev, conv_q_w, conv_k_w, conv_v_w,
                                           meta, o_);
  // 4. output gating + Wo projection with residual
  gate_out_kernel<<<BTz*Hz, 64, 0, stream>>>(o_, gout, onorm_w, og);
  mgemm_kernel<1><<<dim3(8,64), 256, 0, stream>>>(og, WoT, x, x2, BTz, Dz, VDz);
  // 5. MLP, chunked over 4 x 2048 rows
  rmsnorm_kernel<<<BTz, 256, 0, stream>>>(x2, norm2_w, h2);
  for (int c = 0; c < 4; c++){
    const bf16*  h2c = h2 + (size_t)c*2048*Dz;
    const float* x2c = x2 + (size_t)c*2048*Dz;
    float*       out = (float*)d_out + (size_t)c*2048*Dz;
    mgemm_kernel<0><<<dim3(32,16), 256, 0, stream>>>(h2c, WgateT, nullptr, gateC, 2048, Iz, Dz);
    mgemm_kernel<3><<<dim3(32,16), 256, 0, stream>>>(h2c, WupT, gateC, gateC, 2048, Iz, Dz);
    mgemm_kernel<1><<<dim3(8,16),  256, 0, stream>>>(gateC, WdownT, x2c, out, 2048, Dz, Iz);
  }
}

// Round 10
// 1588.913 us; speedup vs baseline: 6.0190x; 1.0784x over previous
//
#include <hip/hip_runtime.h>
#include <hip/hip_bf16.h>

typedef __hip_bfloat16 bf16;
typedef unsigned short us;
typedef short short8v __attribute__((ext_vector_type(8)));
typedef float f32x4 __attribute__((ext_vector_type(4)));
typedef __attribute__((address_space(3))) unsigned int lds_u32;
typedef __attribute__((address_space(1))) const unsigned int glb_u32;

#define GLOAD16(gp, lp) __builtin_amdgcn_global_load_lds((glb_u32*)(gp), (lds_u32*)(lp), 16, 0, 0)

#define Bz 4
#define Tz 2048
#define Dz 1024
#define Hz 8
#define DKz 96
#define DVz 192
#define KDz 768
#define VDz 1536
#define Iz 4096
#define BTz (Bz*Tz)

static __device__ __forceinline__ float us2f(us s){
  return __uint_as_float(((unsigned)s) << 16);
}
static __device__ __forceinline__ us f2bs(float f){
  bf16 t = __float2bfloat16(f);
  return *(us*)&t;
}
static __device__ __forceinline__ float sigmoidf_(float x){ return 1.f/(1.f+expf(-x)); }
static __device__ __forceinline__ float siluf_(float x){ return x*sigmoidf_(x); }

// DPP-based 8-lane-group sum (groups = lanes [8m..8m+7]):
#define DPPADD(x, ctrl) \
  ((x) + __int_as_float(__builtin_amdgcn_update_dpp(0, __float_as_int(x), (ctrl), 0xF, 0xF, true)))
static __device__ __forceinline__ float gsum8(float x){
  x = DPPADD(x, 0xB1);   // quad_perm [1,0,3,2]  : + lane^1
  x = DPPADD(x, 0x4E);   // quad_perm [2,3,0,1]  : + lane^2
  x = DPPADD(x, 0x141);  // row_half_mirror      : + other quad's sum
  return x;
}

// ---------------- weight prep: W[K,N] f32 -> WT[N,K] bf16 ----------------
__global__ __launch_bounds__(256) void wprep_kernel(
    const float* __restrict__ Wsrc, us* __restrict__ WTdst, int K, int N)
{
  __shared__ float t[32][33];
  const int k0 = blockIdx.x*32, n0 = blockIdx.y*32;
  const int c = threadIdx.x & 31, r8 = threadIdx.x >> 5;
  #pragma unroll
  for (int i=0;i<4;i++){
    const int r = r8 + i*8;
    t[r][c] = Wsrc[(size_t)(k0+r)*N + n0 + c];
  }
  __syncthreads();
  #pragma unroll
  for (int i=0;i<4;i++){
    const int r = r8 + i*8;
    WTdst[(size_t)(n0+r)*K + k0 + c] = f2bs(t[c][r]);
  }
}

// ---------------- RMSNorm (f32 in -> bf16 out, f32 weights) ----------------
__global__ __launch_bounds__(256) void rmsnorm_kernel(
    const float* __restrict__ x, const float* __restrict__ w, bf16* __restrict__ out)
{
  const int row = blockIdx.x;
  const float* xr = x + (size_t)row*Dz;
  const int i0 = threadIdx.x*4;
  float4 xv = *(const float4*)(xr + i0);
  float ss = xv.x*xv.x+xv.y*xv.y+xv.z*xv.z+xv.w*xv.w;
  #pragma unroll
  for (int off=32; off>=1; off>>=1) ss += __shfl_xor(ss, off);
  __shared__ float red[4];
  if ((threadIdx.x&63)==0) red[threadIdx.x>>6] = ss;
  __syncthreads();
  ss = red[0]+red[1]+red[2]+red[3];
  const float inv = rsqrtf(ss*(1.f/Dz) + 1e-6f);
  float4 wv = *(const float4*)(w + i0);
  ushort4 ov;
  ov.x=f2bs(xv.x*inv*wv.x); ov.y=f2bs(xv.y*inv*wv.y);
  ov.z=f2bs(xv.z*inv*wv.z); ov.w=f2bs(xv.w*inv*wv.w);
  *(ushort4*)((us*)out + (size_t)row*Dz + i0) = ov;
}

// ------------- MFMA GEMM: C[M,N] = A[M,K](bf16) @ BT[N,K](bf16)^T (+res) -------------
template<int MODE>
__global__ __launch_bounds__(256, 2) void mgemm_kernel(
    const bf16* __restrict__ A, const us* __restrict__ BT,
    const void* __restrict__ res, void* __restrict__ Cout,
    int M, int N, int K)
{
  __shared__ us As[128*64];
  __shared__ us Bs[128*64];
  const int m0 = blockIdx.y*128, n0 = blockIdx.x*128;
  const int tid = threadIdx.x;
  const int wid = tid >> 6, lane = tid & 63;
  const int wr = wid >> 1, wc = wid & 1;
  const int fq = lane >> 4, fr = lane & 15;

  const us* Ab = (const us*)A + (size_t)(m0 + (tid>>3))*K + (tid&7)*8;
  const us* Bb = BT + (size_t)(n0 + (tid>>3))*K + (tid&7)*8;
  char* AsB = (char*)As;
  char* BsB = (char*)Bs;
  const int ldsoff = wid*1024;

  f32x4 acc[4][4] = {};
  const int nk = K >> 6;
  for (int kt = 0; kt < nk; ++kt){
    const int kb = kt*64;
    #pragma unroll
    for (int i=0;i<4;i++){
      GLOAD16(Ab + (size_t)(32*i)*K + kb, AsB + ldsoff + i*4096);
      GLOAD16(Bb + (size_t)(32*i)*K + kb, BsB + ldsoff + i*4096);
    }
    __syncthreads();
    #pragma unroll
    for (int ks=0; ks<2; ks++){
      short8v af[4], bf[4];
      #pragma unroll
      for (int r=0;r<4;r++)
        af[r] = *(const short8v*)&As[(wr*64 + r*16 + fr)*64 + ks*32 + fq*8];
      #pragma unroll
      for (int c=0;c<4;c++)
        bf[c] = *(const short8v*)&Bs[(wc*64 + c*16 + fr)*64 + ks*32 + fq*8];
      #pragma unroll
      for (int r=0;r<4;r++)
        #pragma unroll
        for (int c=0;c<4;c++)
          acc[r][c] = __builtin_amdgcn_mfma_f32_16x16x32_bf16(af[r], bf[c], acc[r][c], 0, 0, 0);
    }
    __syncthreads();
  }
  #pragma unroll
  for (int r=0;r<4;r++){
    #pragma unroll
    for (int c=0;c<4;c++){
      const int col = n0 + wc*64 + c*16 + fr;
      #pragma unroll
      for (int jj=0;jj<4;jj++){
        const int row = m0 + wr*64 + r*16 + fq*4 + jj;
        const size_t idx = (size_t)row*N + col;
        const float a = acc[r][c][jj];
        if (MODE==0){
          ((us*)Cout)[idx] = f2bs(a);
        } else if (MODE==1){
          ((float*)Cout)[idx] = a + ((const float*)res)[idx];
        } else {
          ((us*)Cout)[idx] = f2bs(siluf_(us2f(((const us*)res)[idx]))*a);
        }
      }
    }
  }
}

// ------- beta / exp(g) projections -> meta.x = exp(g), meta.y = beta -------
__global__ __launch_bounds__(256) void beta_g_kernel(
    const bf16* __restrict__ hh, const float* __restrict__ Wb, const float* __restrict__ Wa,
    const float* __restrict__ A_log, const float* __restrict__ dt_bias,
    float4* __restrict__ meta)
{
  const int row = blockIdx.x;
  const us* hr = (const us*)hh + (size_t)row*Dz;
  float ab[8]={0,0,0,0,0,0,0,0}, aa[8]={0,0,0,0,0,0,0,0};
  for (int kk=threadIdx.x; kk<Dz; kk+=256){
    const float hv = us2f(hr[kk]);
    float4 b0 = *(const float4*)(Wb + kk*8);
    float4 b1 = *(const float4*)(Wb + kk*8 + 4);
    float4 a0 = *(const float4*)(Wa + kk*8);
    float4 a1 = *(const float4*)(Wa + kk*8 + 4);
    ab[0]=fmaf(hv,b0.x,ab[0]); ab[1]=fmaf(hv,b0.y,ab[1]);
    ab[2]=fmaf(hv,b0.z,ab[2]); ab[3]=fmaf(hv,b0.w,ab[3]);
    ab[4]=fmaf(hv,b1.x,ab[4]); ab[5]=fmaf(hv,b1.y,ab[5]);
    ab[6]=fmaf(hv,b1.z,ab[6]); ab[7]=fmaf(hv,b1.w,ab[7]);
    aa[0]=fmaf(hv,a0.x,aa[0]); aa[1]=fmaf(hv,a0.y,aa[1]);
    aa[2]=fmaf(hv,a0.z,aa[2]); aa[3]=fmaf(hv,a0.w,aa[3]);
    aa[4]=fmaf(hv,a1.x,aa[4]); aa[5]=fmaf(hv,a1.y,aa[5]);
    aa[6]=fmaf(hv,a1.z,aa[6]); aa[7]=fmaf(hv,a1.w,aa[7]);
  }
  #pragma unroll
  for (int off=32; off>=1; off>>=1){
    #pragma unroll
    for (int n=0;n<8;n++){ ab[n]+=__shfl_xor(ab[n],off); aa[n]+=__shfl_xor(aa[n],off); }
  }
  __shared__ float red[4][16];
  const int wv = threadIdx.x>>6, ln = threadIdx.x&63;
  if (ln==0){
    #pragma unroll
    for (int n=0;n<8;n++){ red[wv][n]=ab[n]; red[wv][8+n]=aa[n]; }
  }
  __syncthreads();
  if (threadIdx.x < 8){
    const int n = threadIdx.x;
    float sb = red[0][n]+red[1][n]+red[2][n]+red[3][n];
    float sa = red[0][8+n]+red[1][8+n]+red[2][8+n]+red[3][8+n];
    float* mp = (float*)&meta[(size_t)row*Hz + n];
    mp[1] = 1.f/(1.f+expf(-sb));
    float xx = sa + dt_bias[n];
    float sp = (xx > 20.f) ? xx : log1pf(expf(xx));
    mp[0] = expf(-expf(A_log[n])*sp);
  }
}

// ------- conv(K=4)+SiLU+l2norm scales -> meta.z = invq, meta.w = invk -------
__global__ __launch_bounds__(64) void conv_inv_kernel(
    const bf16* __restrict__ preq, const bf16* __restrict__ prek,
    const float* __restrict__ wqc, const float* __restrict__ wkc,
    float4* __restrict__ meta)
{
  const int idx = blockIdx.x; const int h = idx & 7; const int bt = idx >> 3;
  const int t = bt & (Tz-1);
  const int lane = threadIdx.x;
  const us* Q = (const us*)preq;
  const us* K = (const us*)prek;
  const int c0 = h*DKz + lane, c1 = c0 + 64;
  const bool hi = lane < 32;
  float yq0=0.f, yq1=0.f, yk0=0.f, yk1=0.f;
  #pragma unroll
  for (int i=0;i<4;i++){
    const int ti = t - 3 + i;
    if (ti >= 0){
      const size_t rowb = (size_t)(bt-3+i)*KDz;
      yq0 = fmaf(us2f(Q[rowb + c0]), wqc[c0*4+i], yq0);
      yk0 = fmaf(us2f(K[rowb + c0]), wkc[c0*4+i], yk0);
      if (hi){
        yq1 = fmaf(us2f(Q[rowb + c1]), wqc[c1*4+i], yq1);
        yk1 = fmaf(us2f(K[rowb + c1]), wkc[c1*4+i], yk1);
      }
    }
  }
  yq0 = siluf_(yq0); yk0 = siluf_(yk0);
  yq1 = hi ? siluf_(yq1) : 0.f;
  yk1 = hi ? siluf_(yk1) : 0.f;
  float ssq = yq0*yq0 + yq1*yq1;
  float ssk = yk0*yk0 + yk1*yk1;
  #pragma unroll
  for (int off=32; off>=1; off>>=1){ ssq += __shfl_xor(ssq,off); ssk += __shfl_xor(ssk,off); }
  if (lane == 0){
    float* mp = (float*)&meta[(size_t)bt*Hz + h];
    mp[2] = rsqrtf(ssq + 1e-6f) * 0.10206207262f;  // invq * dk^-0.5
    mp[3] = rsqrtf(ssk + 1e-6f);                   // invk
  }
}

// ------- apply conv+SiLU+scale to k,q -> packed kqn[bt][h][96k|96q] bf16 -------
__global__ __launch_bounds__(768) void conv_apply_kq_kernel(
    const bf16* __restrict__ preq, const bf16* __restrict__ prek,
    const float* __restrict__ wqc, const float* __restrict__ wkc,
    const float4* __restrict__ meta, us* __restrict__ kqn)
{
  const int bt = blockIdx.x; const int t = bt & (Tz-1);
  const int tid = threadIdx.x;          // channel = h*96+c
  const int h = tid / 96, c = tid - h*96;
  const us* Q = (const us*)preq;
  const us* K = (const us*)prek;
  float yq=0.f, yk=0.f;
  #pragma unroll
  for (int i=0;i<4;i++){
    const int ti = t - 3 + i;
    if (ti >= 0){
      const size_t rowb = (size_t)(bt-3+i)*KDz + tid;
      yq = fmaf(us2f(Q[rowb]), wqc[tid*4+i], yq);
      yk = fmaf(us2f(K[rowb]), wkc[tid*4+i], yk);
    }
  }
  const float4 m = meta[(size_t)bt*Hz + h];
  const size_t ob = (size_t)bt*1536 + h*192 + c;
  kqn[ob]      = f2bs(siluf_(yk) * m.w);   // k, l2-scaled
  kqn[ob + 96] = f2bs(siluf_(yq) * m.z);   // q, l2-scaled * dk^-0.5
}

// ------- apply conv+SiLU to v -> vn bf16 -------
__global__ __launch_bounds__(256) void conv_apply_v_kernel(
    const bf16* __restrict__ prev, const float* __restrict__ wvc, bf16* __restrict__ vn)
{
  const int bt = blockIdx.y; const int ccol = blockIdx.x*256 + threadIdx.x;
  const int t = bt & (Tz-1);
  const us* X = (const us*)prev;
  float acc = 0.f;
  #pragma unroll
  for (int i=0;i<4;i++){
    const int ti = t - 3 + i;
    if (ti >= 0) acc = fmaf(us2f(X[(size_t)(bt-3+i)*VDz + ccol]), wvc[ccol*4+i], acc);
  }
  ((us*)vn)[(size_t)bt*VDz + ccol] = f2bs(siluf_(acc));
}

// ---------------- gated delta-rule scan, consume-only ----------------
// Grid = Bz*Hz*8 blocks; block (bh, sp) owns v-cols [sp*24, sp*24+24).
// 192 threads: tid = j*8 + g; thread owns S[g*12 .. g*12+11][col sp*24+j].
// All conv/silu/l2norm precomputed (kqn, vn). Phase = 8 steps:
// (1) prefetch next phase (kqn row value, vn, meta) into regs;
// (2) consume 8 steps from LDS (DPP reductions, 1-step LDS prefetch);
// (3) stage next phase: kq[p^1][s][tid] = prefetched value (1:1, no branches);
// (4) barrier.
__global__ __launch_bounds__(192, 1) void scan_kernel(
    const us* __restrict__ kqn, const bf16* __restrict__ vn,
    const float4* __restrict__ meta, bf16* __restrict__ o)
{
  const int blk = blockIdx.x;
  const int bh = blk >> 3, sp = blk & 7;
  const int b = bh >> 3, h = bh & 7;
  const int tid = threadIdx.x;
  const int g = tid & 7;
  const int j = tid >> 3;
  const int vc = h*DVz + sp*24 + j;

  __shared__ float kq[2][8][192];   // [buf][step][96 k | 96 q]

  const us* KQ = kqn + (size_t)b*Tz*1536 + h*192 + tid;
  const us* VP = (const us*)vn + (size_t)b*Tz*VDz + vc;
  us* op = (us*)o + (size_t)b*Tz*VDz + vc;
  const float4* MP = meta + (size_t)b*Tz*Hz + h;

  float S[12];
  #pragma unroll
  for (int m=0;m<12;m++) S[m]=0.f;

  float cv[8], ce[8], cb[8];

  // ---- prologue: stage phase 0 ----
  #pragma unroll
  for (int s=0;s<8;s++){
    kq[0][s][tid] = us2f(KQ[(size_t)s*1536]);
    cv[s] = us2f(VP[(size_t)s*VDz]);
    const float4 m = MP[(size_t)s*Hz];
    ce[s] = m.x; cb[s] = m.y;
  }
  __syncthreads();

  for (int ph=0; ph<Tz/8; ph++){
    const int base = ph*8;
    const int p = ph & 1;
    const bool more = (base + 8 < Tz);
    const int nb = more ? base + 8 : base;   // clamp; values unused when !more
    // (1) prefetch next-phase inputs (independent -> issue at top)
    float nkq[8], nv[8]; float4 nm[8];
    #pragma unroll
    for (int s=0;s<8;s++){
      nkq[s] = us2f(KQ[(size_t)(nb+s)*1536]);
      nv[s]  = us2f(VP[(size_t)(nb+s)*VDz]);
      nm[s]  = MP[(size_t)(nb+s)*Hz];
    }
    // (2) consume 8 steps; k/q slices register-prefetched 1 step ahead
    float4 ck0 = *(const float4*)&kq[p][0][g*12];
    float4 ck1 = *(const float4*)&kq[p][0][g*12+4];
    float4 ck2 = *(const float4*)&kq[p][0][g*12+8];
    float4 cq0 = *(const float4*)&kq[p][0][96+g*12];
    float4 cq1 = *(const float4*)&kq[p][0][96+g*12+4];
    float4 cq2 = *(const float4*)&kq[p][0][96+g*12+8];
    #pragma unroll
    for (int s=0;s<8;s++){
      float4 nk0,nk1,nk2,nq0,nq1,nq2;
      if (s < 7){
        nk0 = *(const float4*)&kq[p][s+1][g*12];
        nk1 = *(const float4*)&kq[p][s+1][g*12+4];
        nk2 = *(const float4*)&kq[p][s+1][g*12+8];
        nq0 = *(const float4*)&kq[p][s+1][96+g*12];
        nq1 = *(const float4*)&kq[p][s+1][96+g*12+4];
        nq2 = *(const float4*)&kq[p][s+1][96+g*12+8];
      }
      float a0,a1,a2,a3;
      a0 = ck0.x*S[0]; a1 = ck0.y*S[1]; a2 = ck0.z*S[2]; a3 = ck0.w*S[3];
      a0 = fmaf(ck1.x,S[4],a0); a1 = fmaf(ck1.y,S[5],a1); a2 = fmaf(ck1.z,S[6],a2); a3 = fmaf(ck1.w,S[7],a3);
      a0 = fmaf(ck2.x,S[8],a0); a1 = fmaf(ck2.y,S[9],a1); a2 = fmaf(ck2.z,S[10],a2); a3 = fmaf(ck2.w,S[11],a3);
      const float pv = gsum8((a0+a1)+(a2+a3));
      const float eg = ce[s];
      const float delta = (cv[s] - eg*pv)*cb[s];
      float o0,o1,o2,o3;
      float t0;
      t0 = fmaf(eg,S[0], ck0.x*delta); S[0]=t0; o0 = cq0.x*t0;
      t0 = fmaf(eg,S[1], ck0.y*delta); S[1]=t0; o1 = cq0.y*t0;
      t0 = fmaf(eg,S[2], ck0.z*delta); S[2]=t0; o2 = cq0.z*t0;
      t0 = fmaf(eg,S[3], ck0.w*delta); S[3]=t0; o3 = cq0.w*t0;
      t0 = fmaf(eg,S[4], ck1.x*delta); S[4]=t0; o0 = fmaf(cq1.x,t0,o0);
      t0 = fmaf(eg,S[5], ck1.y*delta); S[5]=t0; o1 = fmaf(cq1.y,t0,o1);
      t0 = fmaf(eg,S[6], ck1.z*delta); S[6]=t0; o2 = fmaf(cq1.z,t0,o2);
      t0 = fmaf(eg,S[7], ck1.w*delta); S[7]=t0; o3 = fmaf(cq1.w,t0,o3);
      t0 = fmaf(eg,S[8], ck2.x*delta); S[8]=t0; o0 = fmaf(cq2.x,t0,o0);
      t0 = fmaf(eg,S[9], ck2.y*delta); S[9]=t0; o1 = fmaf(cq2.y,t0,o1);
      t0 = fmaf(eg,S[10],ck2.z*delta); S[10]=t0; o2 = fmaf(cq2.z,t0,o2);
      t0 = fmaf(eg,S[11],ck2.w*delta); S[11]=t0; o3 = fmaf(cq2.w,t0,o3);
      const float po = gsum8((o0+o1)+(o2+o3));
      if (g == 0) op[(size_t)(base+s)*VDz] = f2bs(po);
      if (s < 7){
        ck0=nk0; ck1=nk1; ck2=nk2; cq0=nq0; cq1=nq1; cq2=nq2;
      }
    }
    // (3) stage next phase from prefetched registers (1:1, branch-free)
    if (more){
      #pragma unroll
      for (int s=0;s<8;s++){
        kq[p^1][s][tid] = nkq[s];
        cv[s] = nv[s]; ce[s] = nm[s].x; cb[s] = nm[s].y;
      }
    }
    __syncthreads();
  }
}

// ---------------- output gate: rmsnorm_dv(o) * silu(gout) ----------------
__global__ __launch_bounds__(64) void gate_out_kernel(
    const bf16* __restrict__ o, const bf16* __restrict__ gout,
    const float* __restrict__ onw, bf16* __restrict__ og)
{
  const size_t base = (size_t)blockIdx.x * DVz;
  const int lane = threadIdx.x;
  const us* O = (const us*)o;
  float x0 = us2f(O[base+lane]), x1 = us2f(O[base+64+lane]), x2 = us2f(O[base+128+lane]);
  float ss = x0*x0 + x1*x1 + x2*x2;
  #pragma unroll
  for (int off=32; off>=1; off>>=1) ss += __shfl_xor(ss, off);
  const float inv = rsqrtf(ss*(1.f/DVz) + 1e-6f);
  const us* G = (const us*)gout;
  us* OG = (us*)og;
  float xs[3] = {x0, x1, x2};
  #pragma unroll
  for (int i=0;i<3;i++){
    const int c = lane + 64*i;
    const float gv = us2f(G[base+c]);
    OG[base+c] = f2bs(xs[i]*inv*onw[c] * siluf_(gv));
  }
}

extern "C" void kernel_launch(void* const* d_in, const int* in_sizes, int n_in,
                              void* d_out, int out_size, void* d_ws, size_t ws_size,
                              hipStream_t stream) {
  const float* x        = (const float*)d_in[0];
  const float* Wq       = (const float*)d_in[1];
  const float* Wk       = (const float*)d_in[2];
  const float* Wv       = (const float*)d_in[3];
  const float* Wb       = (const float*)d_in[4];
  const float* Wa       = (const float*)d_in[5];
  const float* A_log    = (const float*)d_in[6];
  const float* dt_bias  = (const float*)d_in[7];
  const float* conv_q_w = (const float*)d_in[8];
  const float* conv_k_w = (const float*)d_in[9];
  const float* conv_v_w = (const float*)d_in[10];
  const float* Wg       = (const float*)d_in[11];
  const float* onorm_w  = (const float*)d_in[12];
  const float* Wo       = (const float*)d_in[13];
  const float* norm1_w  = (const float*)d_in[14];
  const float* norm2_w  = (const float*)d_in[15];
  const float* Wgate    = (const float*)d_in[16];
  const float* Wup      = (const float*)d_in[17];
  const float* Wdown    = (const float*)d_in[18];

  char* W = (char*)d_ws;
  // bf16-transposed weights (rewritten every launch; deterministic)
  us* WoT    = (us*)(W + 0);           // [1024,1536]  3.15 MB  (live thru Wo GEMM)
  us* WgateT = (us*)(W + 3145728);     // [4096,1024]  (live thru MLP)
  us* WupT   = (us*)(W + 11534336);    // [4096,1024]
  us* WdownT = (us*)(W + 19922944);    // [1024,4096]  ends 28,311,552
  us* WqT    = (us*)(W + 28311552);    // [768,1024]   dead after proj
  us* WkT    = (us*)(W + 29884416);
  us* WvT    = (us*)(W + 31457280);
  us* WgT    = (us*)(W + 34603008);    // ends 37,748,736; dead after gout GEMM
  // activations
  bf16*   h_   = (bf16*) (W + 37748736);   // [8192,1024]; dead after gout GEMM
  bf16*   preq = (bf16*) (W + 54525952);   // [8192,768];  dead after conv_apply_kq
  bf16*   prek = (bf16*) (W + 67108864);   // [8192,768];  dead after conv_apply_kq
  bf16*   prev = (bf16*) (W + 79691776);   // [8192,1536]; dead after conv_apply_v
  float4* meta = (float4*)(W + 104857600); // [8192,8] float4
  bf16*   gout = (bf16*) (W + 105906176);  // [8192,1536]; ends 131,072,000 (PEAK)
  // aliases over dead regions
  us*    kqn   = (us*)   (W + 28311552);   // [8192,1536] bf16 over WqT..WgT+h_-head (dead after scan)
  bf16*  vn    = (bf16*) (W + 54525952);   // [8192,1536] over preq+prek (dead after scan)
  bf16*  o_    = (bf16*) (W + 79691776);   // [8192,1536] over prev (dead after gate_out)
  bf16*  og    = (bf16*) (W + 28311552);   // [8192,1536] over kqn (dead after Wo GEMM)
  float* x2    = (float*)(W + 54525952);   // [8192,1024] f32 over vn+o_-head
  bf16*  h2    = (bf16*) (W + 105906176);  // [8192,1024] over gout (dead after gate_out)
  bf16*  gateC = (bf16*) (W + 28311552);   // [2048,4096] over og (dead after Wo GEMM)

  // 0. weight prep (transpose + f32->bf16)
  wprep_kernel<<<dim3(48,32),  256, 0, stream>>>(Wo,    WoT,    1536, 1024);
  wprep_kernel<<<dim3(32,128), 256, 0, stream>>>(Wgate, WgateT, 1024, 4096);
  wprep_kernel<<<dim3(32,128), 256, 0, stream>>>(Wup,   WupT,   1024, 4096);
  wprep_kernel<<<dim3(128,32), 256, 0, stream>>>(Wdown, WdownT, 4096, 1024);
  wprep_kernel<<<dim3(32,24),  256, 0, stream>>>(Wq,    WqT,    1024, 768);
  wprep_kernel<<<dim3(32,24),  256, 0, stream>>>(Wk,    WkT,    1024, 768);
  wprep_kernel<<<dim3(32,48),  256, 0, stream>>>(Wv,    WvT,    1024, 1536);
  wprep_kernel<<<dim3(32,48),  256, 0, stream>>>(Wg,    WgT,    1024, 1536);
  // 1. pre-norm
  rmsnorm_kernel<<<BTz, 256, 0, stream>>>(x, norm1_w, h_);
  // 2. projections + meta (eg, beta); gout GEMM before h_/WgT regions are reused
  mgemm_kernel<0><<<dim3(6,64),  256, 0, stream>>>(h_, WqT, nullptr, preq, BTz, KDz, Dz);
  mgemm_kernel<0><<<dim3(6,64),  256, 0, stream>>>(h_, WkT, nullptr, prek, BTz, KDz, Dz);
  mgemm_kernel<0><<<dim3(12,64), 256, 0, stream>>>(h_, WvT, nullptr, prev, BTz, VDz, Dz);
  beta_g_kernel<<<BTz, 256, 0, stream>>>(h_, Wb, Wa, A_log, dt_bias, meta);
  mgemm_kernel<0><<<dim3(12,64), 256, 0, stream>>>(h_, WgT, nullptr, gout, BTz, VDz, Dz);
  // 3. conv precompute: scales -> apply k/q -> apply v; then consume-only scan
  conv_inv_kernel<<<BTz*Hz, 64, 0, stream>>>(preq, prek, conv_q_w, conv_k_w, meta);
  conv_apply_kq_kernel<<<BTz, 768, 0, stream>>>(preq, prek, conv_q_w, conv_k_w, meta, kqn);
  conv_apply_v_kernel<<<dim3(6, BTz), 256, 0, stream>>>(prev, conv_v_w, vn);
  scan_kernel<<<Bz*Hz*8, 192, 0, stream>>>(kqn, vn, meta, o_);
  // 4. output gating + Wo projection with residual
  gate_out_kernel<<<BTz*Hz, 64, 0, stream>>>(o_, gout, onorm_w, og);
  mgemm_kernel<1><<<dim3(8,64), 256, 0, stream>>>(og, WoT, x, x2, BTz, Dz, VDz);
  // 5. MLP, chunked over 4 x 2048 rows
  rmsnorm_kernel<<<BTz, 256, 0, stream>>>(x2, norm2_w, h2);
  for (int c = 0; c < 4; c++){
    const bf16*  h2c = h2 + (size_t)c*2048*Dz;
    const float* x2c = x2 + (size_t)c*2048*Dz;
    float*       out = (float*)d_out + (size_t)c*2048*Dz;
    mgemm_kernel<0><<<dim3(32,16), 256, 0, stream>>>(h2c, WgateT, nullptr, gateC, 2048, Iz, Dz);
    mgemm_kernel<3><<<dim3(32,16), 256, 0, stream>>>(h2c, WupT, gateC, gateC, 2048, Iz, Dz);
    mgemm_kernel<1><<<dim3(8,16),  256, 0, stream>>>(gateC, WdownT, x2c, out, 2048, Dz, Iz);
  }
}

// Round 11
// 1343.873 us; speedup vs baseline: 7.1165x; 1.1823x over previous
//
#include <hip/hip_runtime.h>
#include <hip/hip_bf16.h>

typedef __hip_bfloat16 bf16;
typedef unsigned short us;
typedef short short8v __attribute__((ext_vector_type(8)));
typedef float f32x4 __attribute__((ext_vector_type(4)));
typedef __attribute__((address_space(3))) unsigned int lds_u32;
typedef __attribute__((address_space(1))) const unsigned int glb_u32;

#define GLOAD16(gp, lp) __builtin_amdgcn_global_load_lds((glb_u32*)(gp), (lds_u32*)(lp), 16, 0, 0)

#define Bz 4
#define Tz 2048
#define Dz 1024
#define Hz 8
#define DKz 96
#define DVz 192
#define KDz 768
#define VDz 1536
#define Iz 4096
#define BTz (Bz*Tz)

static __device__ __forceinline__ float us2f(us s){
  return __uint_as_float(((unsigned)s) << 16);
}
static __device__ __forceinline__ us f2bs(float f){
  bf16 t = __float2bfloat16(f);
  return *(us*)&t;
}
static __device__ __forceinline__ float sigmoidf_(float x){ return 1.f/(1.f+expf(-x)); }
static __device__ __forceinline__ float siluf_(float x){ return x*sigmoidf_(x); }

// DPP-based 8-lane-group sum (groups = lanes [8m..8m+7]):
#define DPPADD(x, ctrl) \
  ((x) + __int_as_float(__builtin_amdgcn_update_dpp(0, __float_as_int(x), (ctrl), 0xF, 0xF, true)))
static __device__ __forceinline__ float gsum8(float x){
  x = DPPADD(x, 0xB1);   // quad_perm [1,0,3,2]  : + lane^1
  x = DPPADD(x, 0x4E);   // quad_perm [2,3,0,1]  : + lane^2
  x = DPPADD(x, 0x141);  // row_half_mirror      : + other quad's sum
  return x;
}

// ---------------- weight prep: W[K,N] f32 -> WT[N,K] bf16 ----------------
__global__ __launch_bounds__(256) void wprep_kernel(
    const float* __restrict__ Wsrc, us* __restrict__ WTdst, int K, int N)
{
  __shared__ float t[32][33];
  const int k0 = blockIdx.x*32, n0 = blockIdx.y*32;
  const int c = threadIdx.x & 31, r8 = threadIdx.x >> 5;
  #pragma unroll
  for (int i=0;i<4;i++){
    const int r = r8 + i*8;
    t[r][c] = Wsrc[(size_t)(k0+r)*N + n0 + c];
  }
  __syncthreads();
  #pragma unroll
  for (int i=0;i<4;i++){
    const int r = r8 + i*8;
    WTdst[(size_t)(n0+r)*K + k0 + c] = f2bs(t[c][r]);
  }
}

// ---------------- RMSNorm (f32 in -> bf16 out, f32 weights) ----------------
__global__ __launch_bounds__(256) void rmsnorm_kernel(
    const float* __restrict__ x, const float* __restrict__ w, bf16* __restrict__ out)
{
  const int row = blockIdx.x;
  const float* xr = x + (size_t)row*Dz;
  const int i0 = threadIdx.x*4;
  float4 xv = *(const float4*)(xr + i0);
  float ss = xv.x*xv.x+xv.y*xv.y+xv.z*xv.z+xv.w*xv.w;
  #pragma unroll
  for (int off=32; off>=1; off>>=1) ss += __shfl_xor(ss, off);
  __shared__ float red[4];
  if ((threadIdx.x&63)==0) red[threadIdx.x>>6] = ss;
  __syncthreads();
  ss = red[0]+red[1]+red[2]+red[3];
  const float inv = rsqrtf(ss*(1.f/Dz) + 1e-6f);
  float4 wv = *(const float4*)(w + i0);
  ushort4 ov;
  ov.x=f2bs(xv.x*inv*wv.x); ov.y=f2bs(xv.y*inv*wv.y);
  ov.z=f2bs(xv.z*inv*wv.z); ov.w=f2bs(xv.w*inv*wv.w);
  *(ushort4*)((us*)out + (size_t)row*Dz + i0) = ov;
}

// ------------- MFMA GEMM: C[M,N] = A[M,K](bf16) @ BT[N,K](bf16)^T (+res) -------------
// XCD-aware swizzle: grids must have (gridX*gridY)%8==0 (all call sites satisfy).
template<int MODE>
__global__ __launch_bounds__(256, 2) void mgemm_kernel(
    const bf16* __restrict__ A, const us* __restrict__ BT,
    const void* __restrict__ res, void* __restrict__ Cout,
    int M, int N, int K)
{
  __shared__ us As[128*64];
  __shared__ us Bs[128*64];
  const int nwgx = gridDim.x;
  const int lid = blockIdx.y*nwgx + blockIdx.x;
  const int cpx = (nwgx*gridDim.y) >> 3;
  const int swz = (lid & 7)*cpx + (lid >> 3);
  const int m0 = (swz / nwgx)*128, n0 = (swz % nwgx)*128;
  const int tid = threadIdx.x;
  const int wid = tid >> 6, lane = tid & 63;
  const int wr = wid >> 1, wc = wid & 1;
  const int fq = lane >> 4, fr = lane & 15;

  const us* Ab = (const us*)A + (size_t)(m0 + (tid>>3))*K + (tid&7)*8;
  const us* Bb = BT + (size_t)(n0 + (tid>>3))*K + (tid&7)*8;
  char* AsB = (char*)As;
  char* BsB = (char*)Bs;
  const int ldsoff = wid*1024;

  f32x4 acc[4][4] = {};
  const int nk = K >> 6;
  for (int kt = 0; kt < nk; ++kt){
    const int kb = kt*64;
    #pragma unroll
    for (int i=0;i<4;i++){
      GLOAD16(Ab + (size_t)(32*i)*K + kb, AsB + ldsoff + i*4096);
      GLOAD16(Bb + (size_t)(32*i)*K + kb, BsB + ldsoff + i*4096);
    }
    __syncthreads();
    #pragma unroll
    for (int ks=0; ks<2; ks++){
      short8v af[4], bf[4];
      #pragma unroll
      for (int r=0;r<4;r++)
        af[r] = *(const short8v*)&As[(wr*64 + r*16 + fr)*64 + ks*32 + fq*8];
      #pragma unroll
      for (int c=0;c<4;c++)
        bf[c] = *(const short8v*)&Bs[(wc*64 + c*16 + fr)*64 + ks*32 + fq*8];
      #pragma unroll
      for (int r=0;r<4;r++)
        #pragma unroll
        for (int c=0;c<4;c++)
          acc[r][c] = __builtin_amdgcn_mfma_f32_16x16x32_bf16(af[r], bf[c], acc[r][c], 0, 0, 0);
    }
    __syncthreads();
  }
  #pragma unroll
  for (int r=0;r<4;r++){
    #pragma unroll
    for (int c=0;c<4;c++){
      const int col = n0 + wc*64 + c*16 + fr;
      #pragma unroll
      for (int jj=0;jj<4;jj++){
        const int row = m0 + wr*64 + r*16 + fq*4 + jj;
        const size_t idx = (size_t)row*N + col;
        const float a = acc[r][c][jj];
        if (MODE==0){
          ((us*)Cout)[idx] = f2bs(a);
        } else if (MODE==1){
          ((float*)Cout)[idx] = a + ((const float*)res)[idx];
        } else {
          ((us*)Cout)[idx] = f2bs(siluf_(us2f(((const us*)res)[idx]))*a);
        }
      }
    }
  }
}

// ------- beta / exp(g) projections -> meta = (exp(g), beta) float2 -------
__global__ __launch_bounds__(256) void beta_g_kernel(
    const bf16* __restrict__ hh, const float* __restrict__ Wb, const float* __restrict__ Wa,
    const float* __restrict__ A_log, const float* __restrict__ dt_bias,
    float2* __restrict__ meta)
{
  const int row = blockIdx.x;
  const us* hr = (const us*)hh + (size_t)row*Dz;
  float ab[8]={0,0,0,0,0,0,0,0}, aa[8]={0,0,0,0,0,0,0,0};
  for (int kk=threadIdx.x; kk<Dz; kk+=256){
    const float hv = us2f(hr[kk]);
    float4 b0 = *(const float4*)(Wb + kk*8);
    float4 b1 = *(const float4*)(Wb + kk*8 + 4);
    float4 a0 = *(const float4*)(Wa + kk*8);
    float4 a1 = *(const float4*)(Wa + kk*8 + 4);
    ab[0]=fmaf(hv,b0.x,ab[0]); ab[1]=fmaf(hv,b0.y,ab[1]);
    ab[2]=fmaf(hv,b0.z,ab[2]); ab[3]=fmaf(hv,b0.w,ab[3]);
    ab[4]=fmaf(hv,b1.x,ab[4]); ab[5]=fmaf(hv,b1.y,ab[5]);
    ab[6]=fmaf(hv,b1.z,ab[6]); ab[7]=fmaf(hv,b1.w,ab[7]);
    aa[0]=fmaf(hv,a0.x,aa[0]); aa[1]=fmaf(hv,a0.y,aa[1]);
    aa[2]=fmaf(hv,a0.z,aa[2]); aa[3]=fmaf(hv,a0.w,aa[3]);
    aa[4]=fmaf(hv,a1.x,aa[4]); aa[5]=fmaf(hv,a1.y,aa[5]);
    aa[6]=fmaf(hv,a1.z,aa[6]); aa[7]=fmaf(hv,a1.w,aa[7]);
  }
  #pragma unroll
  for (int off=32; off>=1; off>>=1){
    #pragma unroll
    for (int n=0;n<8;n++){ ab[n]+=__shfl_xor(ab[n],off); aa[n]+=__shfl_xor(aa[n],off); }
  }
  __shared__ float red[4][16];
  const int wv = threadIdx.x>>6, ln = threadIdx.x&63;
  if (ln==0){
    #pragma unroll
    for (int n=0;n<8;n++){ red[wv][n]=ab[n]; red[wv][8+n]=aa[n]; }
  }
  __syncthreads();
  if (threadIdx.x < 8){
    const int n = threadIdx.x;
    float sb = red[0][n]+red[1][n]+red[2][n]+red[3][n];
    float sa = red[0][8+n]+red[1][8+n]+red[2][8+n]+red[3][8+n];
    float xx = sa + dt_bias[n];
    float sp = (xx > 20.f) ? xx : log1pf(expf(xx));
    float eg = expf(-expf(A_log[n])*sp);
    float bt = 1.f/(1.f+expf(-sb));
    meta[(size_t)row*Hz + n] = make_float2(eg, bt);
  }
}

// ------- fused conv(K=4)+SiLU+l2norm+scale for k,q -> kqn[bt][h][96k|96q] bf16 -------
__global__ __launch_bounds__(64) void conv_kq_kernel(
    const bf16* __restrict__ preq, const bf16* __restrict__ prek,
    const float* __restrict__ wqc, const float* __restrict__ wkc,
    us* __restrict__ kqn)
{
  const int idx = blockIdx.x; const int h = idx & 7; const int bt = idx >> 3;
  const int t = bt & (Tz-1);
  const int lane = threadIdx.x;
  const us* Q = (const us*)preq;
  const us* K = (const us*)prek;
  const int c0 = h*DKz + lane, c1 = c0 + 64;
  const bool hi = lane < 32;
  float yq0=0.f, yq1=0.f, yk0=0.f, yk1=0.f;
  #pragma unroll
  for (int i=0;i<4;i++){
    const int ti = t - 3 + i;
    if (ti >= 0){
      const size_t rowb = (size_t)(bt-3+i)*KDz;
      yq0 = fmaf(us2f(Q[rowb + c0]), wqc[c0*4+i], yq0);
      yk0 = fmaf(us2f(K[rowb + c0]), wkc[c0*4+i], yk0);
      if (hi){
        yq1 = fmaf(us2f(Q[rowb + c1]), wqc[c1*4+i], yq1);
        yk1 = fmaf(us2f(K[rowb + c1]), wkc[c1*4+i], yk1);
      }
    }
  }
  yq0 = siluf_(yq0); yk0 = siluf_(yk0);
  yq1 = hi ? siluf_(yq1) : 0.f;
  yk1 = hi ? siluf_(yk1) : 0.f;
  float ssq = yq0*yq0 + yq1*yq1;
  float ssk = yk0*yk0 + yk1*yk1;
  #pragma unroll
  for (int off=32; off>=1; off>>=1){ ssq += __shfl_xor(ssq,off); ssk += __shfl_xor(ssk,off); }
  const float iq = rsqrtf(ssq + 1e-6f) * 0.10206207262f;  // invq * dk^-0.5
  const float ik = rsqrtf(ssk + 1e-6f);
  const size_t base = (size_t)bt*1536 + (size_t)h*192;
  kqn[base + lane]      = f2bs(yk0*ik);
  kqn[base + 96 + lane] = f2bs(yq0*iq);
  if (hi){
    kqn[base + 64 + lane]      = f2bs(yk1*ik);
    kqn[base + 96 + 64 + lane] = f2bs(yq1*iq);
  }
}

// ------- apply conv+SiLU to v -> vn bf16 -------
__global__ __launch_bounds__(256) void conv_apply_v_kernel(
    const bf16* __restrict__ prev, const float* __restrict__ wvc, bf16* __restrict__ vn)
{
  const int bt = blockIdx.y; const int ccol = blockIdx.x*256 + threadIdx.x;
  const int t = bt & (Tz-1);
  const us* X = (const us*)prev;
  float acc = 0.f;
  #pragma unroll
  for (int i=0;i<4;i++){
    const int ti = t - 3 + i;
    if (ti >= 0) acc = fmaf(us2f(X[(size_t)(bt-3+i)*VDz + ccol]), wvc[ccol*4+i], acc);
  }
  ((us*)vn)[(size_t)bt*VDz + ccol] = f2bs(siluf_(acc));
}

// ---------------- gated delta-rule scan, consume-only ----------------
// Grid = Bz*Hz*8; block (bh, sp) owns v-cols [sp*24, sp*24+24).
// 192 threads: tid = j*8 + g; thread owns S[g*12 .. g*12+11][col sp*24+j].
// Phase = 8 steps: (1) global prefetch next phase; (2) consume 8 steps (parity
// register sets for LDS prefetch, no rotation movs; 1-FMA delta via precomputed
// eg*beta and v*beta); (3) stage next phase; (4) barrier.
__global__ __launch_bounds__(192, 1) void scan_kernel(
    const us* __restrict__ kqn, const bf16* __restrict__ vn,
    const float2* __restrict__ meta, bf16* __restrict__ o)
{
  const int blk = blockIdx.x;
  const int bh = blk >> 3, sp = blk & 7;
  const int b = bh >> 3, h = bh & 7;
  const int tid = threadIdx.x;
  const int g = tid & 7;
  const int j = tid >> 3;
  const int vc = h*DVz + sp*24 + j;

  __shared__ float kq[2][8][192];   // [buf][step][96 k | 96 q]

  const us* KQ = kqn + (size_t)b*Tz*1536 + h*192 + tid;
  const us* VP = (const us*)vn + (size_t)b*Tz*VDz + vc;
  us* op = (us*)o + (size_t)b*Tz*VDz + vc;
  const float2* MP = meta + (size_t)b*Tz*Hz + h;

  float S[12];
  #pragma unroll
  for (int m=0;m<12;m++) S[m]=0.f;

  float ced[8], egb[8], cvb[8];   // eg, eg*beta, v*beta

  // ---- prologue: stage phase 0 ----
  #pragma unroll
  for (int s=0;s<8;s++){
    kq[0][s][tid] = us2f(KQ[(size_t)s*1536]);
    const float cv = us2f(VP[(size_t)s*VDz]);
    const float2 m = MP[(size_t)s*Hz];
    ced[s] = m.x; egb[s] = m.x*m.y; cvb[s] = cv*m.y;
  }
  __syncthreads();

  for (int ph=0; ph<Tz/8; ph++){
    const int base = ph*8;
    const int p = ph & 1;
    const bool more = (base + 8 < Tz);
    const int nb = more ? base + 8 : base;   // clamp; values unused when !more
    // (1) prefetch next-phase inputs (independent -> issue at top)
    float nkq[8], nv[8]; float2 nm[8];
    #pragma unroll
    for (int s=0;s<8;s++){
      nkq[s] = us2f(KQ[(size_t)(nb+s)*1536]);
      nv[s]  = us2f(VP[(size_t)(nb+s)*VDz]);
      nm[s]  = MP[(size_t)(nb+s)*Hz];
    }
    // (2) consume 8 steps; parity register sets (no rotation copies)
    float4 kf[2][3], qf[2][3];
    #pragma unroll
    for (int m=0;m<3;m++){
      kf[0][m] = *(const float4*)&kq[p][0][g*12 + m*4];
      qf[0][m] = *(const float4*)&kq[p][0][96 + g*12 + m*4];
    }
    #pragma unroll
    for (int s=0;s<8;s++){
      const int cu = s & 1, nx = cu ^ 1;
      if (s < 7){
        #pragma unroll
        for (int m=0;m<3;m++){
          kf[nx][m] = *(const float4*)&kq[p][s+1][g*12 + m*4];
          qf[nx][m] = *(const float4*)&kq[p][s+1][96 + g*12 + m*4];
        }
      }
      float a0,a1,a2,a3;
      a0 = kf[cu][0].x*S[0]; a1 = kf[cu][0].y*S[1]; a2 = kf[cu][0].z*S[2]; a3 = kf[cu][0].w*S[3];
      a0 = fmaf(kf[cu][1].x,S[4],a0); a1 = fmaf(kf[cu][1].y,S[5],a1);
      a2 = fmaf(kf[cu][1].z,S[6],a2); a3 = fmaf(kf[cu][1].w,S[7],a3);
      a0 = fmaf(kf[cu][2].x,S[8],a0); a1 = fmaf(kf[cu][2].y,S[9],a1);
      a2 = fmaf(kf[cu][2].z,S[10],a2); a3 = fmaf(kf[cu][2].w,S[11],a3);
      const float pv = gsum8((a0+a1)+(a2+a3));
      const float eg = ced[s];
      const float delta = fmaf(-egb[s], pv, cvb[s]);   // (cv - eg*pv)*beta
      float o0,o1,o2,o3;
      float t0;
      t0 = fmaf(eg,S[0], kf[cu][0].x*delta); S[0]=t0; o0 = qf[cu][0].x*t0;
      t0 = fmaf(eg,S[1], kf[cu][0].y*delta); S[1]=t0; o1 = qf[cu][0].y*t0;
      t0 = fmaf(eg,S[2], kf[cu][0].z*delta); S[2]=t0; o2 = qf[cu][0].z*t0;
      t0 = fmaf(eg,S[3], kf[cu][0].w*delta); S[3]=t0; o3 = qf[cu][0].w*t0;
      t0 = fmaf(eg,S[4], kf[cu][1].x*delta); S[4]=t0; o0 = fmaf(qf[cu][1].x,t0,o0);
      t0 = fmaf(eg,S[5], kf[cu][1].y*delta); S[5]=t0; o1 = fmaf(qf[cu][1].y,t0,o1);
      t0 = fmaf(eg,S[6], kf[cu][1].z*delta); S[6]=t0; o2 = fmaf(qf[cu][1].z,t0,o2);
      t0 = fmaf(eg,S[7], kf[cu][1].w*delta); S[7]=t0; o3 = fmaf(qf[cu][1].w,t0,o3);
      t0 = fmaf(eg,S[8], kf[cu][2].x*delta); S[8]=t0; o0 = fmaf(qf[cu][2].x,t0,o0);
      t0 = fmaf(eg,S[9], kf[cu][2].y*delta); S[9]=t0; o1 = fmaf(qf[cu][2].y,t0,o1);
      t0 = fmaf(eg,S[10],kf[cu][2].z*delta); S[10]=t0; o2 = fmaf(qf[cu][2].z,t0,o2);
      t0 = fmaf(eg,S[11],kf[cu][2].w*delta); S[11]=t0; o3 = fmaf(qf[cu][2].w,t0,o3);
      const float po = gsum8((o0+o1)+(o2+o3));
      if (g == 0) op[(size_t)(base+s)*VDz] = f2bs(po);
    }
    // (3) stage next phase from prefetched registers (1:1, branch-free)
    if (more){
      #pragma unroll
      for (int s=0;s<8;s++){
        kq[p^1][s][tid] = nkq[s];
        ced[s] = nm[s].x; egb[s] = nm[s].x*nm[s].y; cvb[s] = nv[s]*nm[s].y;
      }
    }
    __syncthreads();
  }
}

// ---------------- output gate: rmsnorm_dv(o) * silu(gout) ----------------
__global__ __launch_bounds__(64) void gate_out_kernel(
    const bf16* __restrict__ o, const bf16* __restrict__ gout,
    const float* __restrict__ onw, bf16* __restrict__ og)
{
  const size_t base = (size_t)blockIdx.x * DVz;
  const int lane = threadIdx.x;
  const us* O = (const us*)o;
  float x0 = us2f(O[base+lane]), x1 = us2f(O[base+64+lane]), x2 = us2f(O[base+128+lane]);
  float ss = x0*x0 + x1*x1 + x2*x2;
  #pragma unroll
  for (int off=32; off>=1; off>>=1) ss += __shfl_xor(ss, off);
  const float inv = rsqrtf(ss*(1.f/DVz) + 1e-6f);
  const us* G = (const us*)gout;
  us* OG = (us*)og;
  float xs[3] = {x0, x1, x2};
  #pragma unroll
  for (int i=0;i<3;i++){
    const int c = lane + 64*i;
    const float gv = us2f(G[base+c]);
    OG[base+c] = f2bs(xs[i]*inv*onw[c] * siluf_(gv));
  }
}

extern "C" void kernel_launch(void* const* d_in, const int* in_sizes, int n_in,
                              void* d_out, int out_size, void* d_ws, size_t ws_size,
                              hipStream_t stream) {
  const float* x        = (const float*)d_in[0];
  const float* Wq       = (const float*)d_in[1];
  const float* Wk       = (const float*)d_in[2];
  const float* Wv       = (const float*)d_in[3];
  const float* Wb       = (const float*)d_in[4];
  const float* Wa       = (const float*)d_in[5];
  const float* A_log    = (const float*)d_in[6];
  const float* dt_bias  = (const float*)d_in[7];
  const float* conv_q_w = (const float*)d_in[8];
  const float* conv_k_w = (const float*)d_in[9];
  const float* conv_v_w = (const float*)d_in[10];
  const float* Wg       = (const float*)d_in[11];
  const float* onorm_w  = (const float*)d_in[12];
  const float* Wo       = (const float*)d_in[13];
  const float* norm1_w  = (const float*)d_in[14];
  const float* norm2_w  = (const float*)d_in[15];
  const float* Wgate    = (const float*)d_in[16];
  const float* Wup      = (const float*)d_in[17];
  const float* Wdown    = (const float*)d_in[18];

  char* W = (char*)d_ws;
  // bf16-transposed weights (rewritten every launch; deterministic)
  us* WoT    = (us*)(W + 0);           // live thru Wo GEMM
  us* WgateT = (us*)(W + 3145728);     // live thru MLP
  us* WupT   = (us*)(W + 11534336);
  us* WdownT = (us*)(W + 19922944);    // ends 28,311,552
  us* WqT    = (us*)(W + 28311552);    // dead after proj
  us* WkT    = (us*)(W + 29884416);
  us* WvT    = (us*)(W + 31457280);
  us* WgT    = (us*)(W + 34603008);    // ends 37,748,736; dead after gout GEMM
  // activations
  bf16*   h_   = (bf16*)  (W + 37748736);   // [8192,1024]; dead after gout GEMM
  bf16*   preq = (bf16*)  (W + 54525952);   // [8192,768];  dead after conv_kq
  bf16*   prek = (bf16*)  (W + 67108864);   // [8192,768];  dead after conv_kq
  bf16*   prev = (bf16*)  (W + 79691776);   // [8192,1536]; dead after conv_apply_v
  float2* meta = (float2*)(W + 104857600);  // [8192,8] float2; dead after scan
  bf16*   gout = (bf16*)  (W + 105906176);  // [8192,1536]; ends 131,072,000 (PEAK)
  // aliases over dead regions
  us*    kqn   = (us*)   (W + 28311552);   // [8192,1536] bf16 over WqT..h_-head (dead after scan)
  bf16*  vn    = (bf16*) (W + 54525952);   // [8192,1536] over preq+prek (dead after scan)
  bf16*  o_    = (bf16*) (W + 79691776);   // [8192,1536] over prev (dead after gate_out)
  bf16*  og    = (bf16*) (W + 28311552);   // [8192,1536] over kqn (dead after Wo GEMM)
  float* x2    = (float*)(W + 79691776);   // [8192,1024] f32 over o_+meta+gout-head (post gate_out)
  bf16*  h2    = (bf16*) (W + 113246208);  // [8192,1024] over gout tail (dead after gate_out)
  bf16*  gateC = (bf16*) (W + 28311552);   // [4096,4096] over og+vn region (dead after Wo GEMM)

  // 0. weight prep (transpose + f32->bf16)
  wprep_kernel<<<dim3(48,32),  256, 0, stream>>>(Wo,    WoT,    1536, 1024);
  wprep_kernel<<<dim3(32,128), 256, 0, stream>>>(Wgate, WgateT, 1024, 4096);
  wprep_kernel<<<dim3(32,128), 256, 0, stream>>>(Wup,   WupT,   1024, 4096);
  wprep_kernel<<<dim3(128,32), 256, 0, stream>>>(Wdown, WdownT, 4096, 1024);
  wprep_kernel<<<dim3(32,24),  256, 0, stream>>>(Wq,    WqT,    1024, 768);
  wprep_kernel<<<dim3(32,24),  256, 0, stream>>>(Wk,    WkT,    1024, 768);
  wprep_kernel<<<dim3(32,48),  256, 0, stream>>>(Wv,    WvT,    1024, 1536);
  wprep_kernel<<<dim3(32,48),  256, 0, stream>>>(Wg,    WgT,    1024, 1536);
  // 1. pre-norm
  rmsnorm_kernel<<<BTz, 256, 0, stream>>>(x, norm1_w, h_);
  // 2. projections + meta (eg, beta); gout GEMM before h_/WgT regions are reused
  mgemm_kernel<0><<<dim3(6,64),  256, 0, stream>>>(h_, WqT, nullptr, preq, BTz, KDz, Dz);
  mgemm_kernel<0><<<dim3(6,64),  256, 0, stream>>>(h_, WkT, nullptr, prek, BTz, KDz, Dz);
  mgemm_kernel<0><<<dim3(12,64), 256, 0, stream>>>(h_, WvT, nullptr, prev, BTz, VDz, Dz);
  beta_g_kernel<<<BTz, 256, 0, stream>>>(h_, Wb, Wa, A_log, dt_bias, meta);
  mgemm_kernel<0><<<dim3(12,64), 256, 0, stream>>>(h_, WgT, nullptr, gout, BTz, VDz, Dz);
  // 3. fused conv+silu+l2+scale -> kqn; conv+silu -> vn; consume-only scan
  conv_kq_kernel<<<BTz*Hz, 64, 0, stream>>>(preq, prek, conv_q_w, conv_k_w, kqn);
  conv_apply_v_kernel<<<dim3(6, BTz), 256, 0, stream>>>(prev, conv_v_w, vn);
  scan_kernel<<<Bz*Hz*8, 192, 0, stream>>>(kqn, vn, meta, o_);
  // 4. output gating + Wo projection with residual
  gate_out_kernel<<<BTz*Hz, 64, 0, stream>>>(o_, gout, onorm_w, og);
  mgemm_kernel<1><<<dim3(8,64), 256, 0, stream>>>(og, WoT, x, x2, BTz, Dz, VDz);
  // 5. MLP, chunked over 2 x 4096 rows
  rmsnorm_kernel<<<BTz, 256, 0, stream>>>(x2, norm2_w, h2);
  for (int c = 0; c < 2; c++){
    const bf16*  h2c = h2 + (size_t)c*4096*Dz;
    const float* x2c = x2 + (size_t)c*4096*Dz;
    float*       out = (float*)d_out + (size_t)c*4096*Dz;
    mgemm_kernel<0><<<dim3(32,32), 256, 0, stream>>>(h2c, WgateT, nullptr, gateC, 4096, Iz, Dz);
    mgemm_kernel<3><<<dim3(32,32), 256, 0, stream>>>(h2c, WupT, gateC, gateC, 4096, Iz, Dz);
    mgemm_kernel<1><<<dim3(8,32),  256, 0, stream>>>(gateC, WdownT, x2c, out, 4096, Dz, Iz);
  }
}

// Round 13
// 1227.550 us; speedup vs baseline: 7.7909x; 1.0948x over previous
//
#include <hip/hip_runtime.h>
#include <hip/hip_bf16.h>

typedef __hip_bfloat16 bf16;
typedef unsigned short us;
typedef short short8v __attribute__((ext_vector_type(8)));
typedef float f32x4 __attribute__((ext_vector_type(4)));
typedef __attribute__((address_space(3))) unsigned int lds_u32;
typedef __attribute__((address_space(1))) const unsigned int glb_u32;

#define GLOAD16(gp, lp) __builtin_amdgcn_global_load_lds((glb_u32*)(gp), (lds_u32*)(lp), 16, 0, 0)

#define Bz 4
#define Tz 2048
#define Dz 1024
#define Hz 8
#define DKz 96
#define DVz 192
#define KDz 768
#define VDz 1536
#define Iz 4096
#define BTz (Bz*Tz)

static __device__ __forceinline__ float us2f(us s){
  return __uint_as_float(((unsigned)s) << 16);
}
static __device__ __forceinline__ us f2bs(float f){
  bf16 t = __float2bfloat16(f);
  return *(us*)&t;
}
static __device__ __forceinline__ float sigmoidf_(float x){ return 1.f/(1.f+expf(-x)); }
static __device__ __forceinline__ float siluf_(float x){ return x*sigmoidf_(x); }

// DPP lane-group sums (VALU pipe, no DS):
#define DPPADD(x, ctrl) \
  ((x) + __int_as_float(__builtin_amdgcn_update_dpp(0, __float_as_int(x), (ctrl), 0xF, 0xF, true)))
static __device__ __forceinline__ float gsum16(float x){
  x = DPPADD(x, 0xB1);   // quad_perm [1,0,3,2] : + lane^1
  x = DPPADD(x, 0x4E);   // quad_perm [2,3,0,1] : + lane^2
  x = DPPADD(x, 0x141);  // row_half_mirror     : + other quad (8-group sum)
  x = DPPADD(x, 0x140);  // row_mirror          : + other 8-half (16-group sum)
  return x;
}

// ---------------- weight prep: W[K,N] f32 -> WT[N,K] bf16 ----------------
__global__ __launch_bounds__(256) void wprep_kernel(
    const float* __restrict__ Wsrc, us* __restrict__ WTdst, int K, int N)
{
  __shared__ float t[32][33];
  const int k0 = blockIdx.x*32, n0 = blockIdx.y*32;
  const int c = threadIdx.x & 31, r8 = threadIdx.x >> 5;
  #pragma unroll
  for (int i=0;i<4;i++){
    const int r = r8 + i*8;
    t[r][c] = Wsrc[(size_t)(k0+r)*N + n0 + c];
  }
  __syncthreads();
  #pragma unroll
  for (int i=0;i<4;i++){
    const int r = r8 + i*8;
    WTdst[(size_t)(n0+r)*K + k0 + c] = f2bs(t[c][r]);
  }
}

// ---------------- RMSNorm (f32 in -> bf16 out, f32 weights) ----------------
__global__ __launch_bounds__(256) void rmsnorm_kernel(
    const float* __restrict__ x, const float* __restrict__ w, bf16* __restrict__ out)
{
  const int row = blockIdx.x;
  const float* xr = x + (size_t)row*Dz;
  const int i0 = threadIdx.x*4;
  float4 xv = *(const float4*)(xr + i0);
  float ss = xv.x*xv.x+xv.y*xv.y+xv.z*xv.z+xv.w*xv.w;
  #pragma unroll
  for (int off=32; off>=1; off>>=1) ss += __shfl_xor(ss, off);
  __shared__ float red[4];
  if ((threadIdx.x&63)==0) red[threadIdx.x>>6] = ss;
  __syncthreads();
  ss = red[0]+red[1]+red[2]+red[3];
  const float inv = rsqrtf(ss*(1.f/Dz) + 1e-6f);
  float4 wv = *(const float4*)(w + i0);
  ushort4 ov;
  ov.x=f2bs(xv.x*inv*wv.x); ov.y=f2bs(xv.y*inv*wv.y);
  ov.z=f2bs(xv.z*inv*wv.z); ov.w=f2bs(xv.w*inv*wv.w);
  *(ushort4*)((us*)out + (size_t)row*Dz + i0) = ov;
}

// ------------- MFMA GEMM: C[M,N] = A[M,K](bf16) @ BT[N,K](bf16)^T (+res) -------------
// XCD-aware swizzle: grids must have (gridX*gridY)%8==0 (all call sites satisfy).
template<int MODE>
__global__ __launch_bounds__(256, 2) void mgemm_kernel(
    const bf16* __restrict__ A, const us* __restrict__ BT,
    const void* __restrict__ res, void* __restrict__ Cout,
    int M, int N, int K)
{
  __shared__ us As[128*64];
  __shared__ us Bs[128*64];
  const int nwgx = gridDim.x;
  const int lid = blockIdx.y*nwgx + blockIdx.x;
  const int cpx = (nwgx*gridDim.y) >> 3;
  const int swz = (lid & 7)*cpx + (lid >> 3);
  const int m0 = (swz / nwgx)*128, n0 = (swz % nwgx)*128;
  const int tid = threadIdx.x;
  const int wid = tid >> 6, lane = tid & 63;
  const int wr = wid >> 1, wc = wid & 1;
  const int fq = lane >> 4, fr = lane & 15;

  const us* Ab = (const us*)A + (size_t)(m0 + (tid>>3))*K + (tid&7)*8;
  const us* Bb = BT + (size_t)(n0 + (tid>>3))*K + (tid&7)*8;
  char* AsB = (char*)As;
  char* BsB = (char*)Bs;
  const int ldsoff = wid*1024;

  f32x4 acc[4][4] = {};
  const int nk = K >> 6;
  for (int kt = 0; kt < nk; ++kt){
    const int kb = kt*64;
    #pragma unroll
    for (int i=0;i<4;i++){
      GLOAD16(Ab + (size_t)(32*i)*K + kb, AsB + ldsoff + i*4096);
      GLOAD16(Bb + (size_t)(32*i)*K + kb, BsB + ldsoff + i*4096);
    }
    __syncthreads();
    #pragma unroll
    for (int ks=0; ks<2; ks++){
      short8v af[4], bf[4];
      #pragma unroll
      for (int r=0;r<4;r++)
        af[r] = *(const short8v*)&As[(wr*64 + r*16 + fr)*64 + ks*32 + fq*8];
      #pragma unroll
      for (int c=0;c<4;c++)
        bf[c] = *(const short8v*)&Bs[(wc*64 + c*16 + fr)*64 + ks*32 + fq*8];
      #pragma unroll
      for (int r=0;r<4;r++)
        #pragma unroll
        for (int c=0;c<4;c++)
          acc[r][c] = __builtin_amdgcn_mfma_f32_16x16x32_bf16(af[r], bf[c], acc[r][c], 0, 0, 0);
    }
    __syncthreads();
  }
  #pragma unroll
  for (int r=0;r<4;r++){
    #pragma unroll
    for (int c=0;c<4;c++){
      const int col = n0 + wc*64 + c*16 + fr;
      #pragma unroll
      for (int jj=0;jj<4;jj++){
        const int row = m0 + wr*64 + r*16 + fq*4 + jj;
        const size_t idx = (size_t)row*N + col;
        const float a = acc[r][c][jj];
        if (MODE==0){
          ((us*)Cout)[idx] = f2bs(a);
        } else if (MODE==1){
          ((float*)Cout)[idx] = a + ((const float*)res)[idx];
        } else {
          ((us*)Cout)[idx] = f2bs(siluf_(us2f(((const us*)res)[idx]))*a);
        }
      }
    }
  }
}

// ------- beta / exp(g) projections -> meta = (exp(g), beta) float2 -------
__global__ __launch_bounds__(256) void beta_g_kernel(
    const bf16* __restrict__ hh, const float* __restrict__ Wb, const float* __restrict__ Wa,
    const float* __restrict__ A_log, const float* __restrict__ dt_bias,
    float2* __restrict__ meta)
{
  const int row = blockIdx.x;
  const us* hr = (const us*)hh + (size_t)row*Dz;
  float ab[8]={0,0,0,0,0,0,0,0}, aa[8]={0,0,0,0,0,0,0,0};
  for (int kk=threadIdx.x; kk<Dz; kk+=256){
    const float hv = us2f(hr[kk]);
    float4 b0 = *(const float4*)(Wb + kk*8);
    float4 b1 = *(const float4*)(Wb + kk*8 + 4);
    float4 a0 = *(const float4*)(Wa + kk*8);
    float4 a1 = *(const float4*)(Wa + kk*8 + 4);
    ab[0]=fmaf(hv,b0.x,ab[0]); ab[1]=fmaf(hv,b0.y,ab[1]);
    ab[2]=fmaf(hv,b0.z,ab[2]); ab[3]=fmaf(hv,b0.w,ab[3]);
    ab[4]=fmaf(hv,b1.x,ab[4]); ab[5]=fmaf(hv,b1.y,ab[5]);
    ab[6]=fmaf(hv,b1.z,ab[6]); ab[7]=fmaf(hv,b1.w,ab[7]);
    aa[0]=fmaf(hv,a0.x,aa[0]); aa[1]=fmaf(hv,a0.y,aa[1]);
    aa[2]=fmaf(hv,a0.z,aa[2]); aa[3]=fmaf(hv,a0.w,aa[3]);
    aa[4]=fmaf(hv,a1.x,aa[4]); aa[5]=fmaf(hv,a1.y,aa[5]);
    aa[6]=fmaf(hv,a1.z,aa[6]); aa[7]=fmaf(hv,a1.w,aa[7]);
  }
  #pragma unroll
  for (int off=32; off>=1; off>>=1){
    #pragma unroll
    for (int n=0;n<8;n++){ ab[n]+=__shfl_xor(ab[n],off); aa[n]+=__shfl_xor(aa[n],off); }
  }
  __shared__ float red[4][16];
  const int wv = threadIdx.x>>6, ln = threadIdx.x&63;
  if (ln==0){
    #pragma unroll
    for (int n=0;n<8;n++){ red[wv][n]=ab[n]; red[wv][8+n]=aa[n]; }
  }
  __syncthreads();
  if (threadIdx.x < 8){
    const int n = threadIdx.x;
    float sb = red[0][n]+red[1][n]+red[2][n]+red[3][n];
    float sa = red[0][8+n]+red[1][8+n]+red[2][8+n]+red[3][8+n];
    float xx = sa + dt_bias[n];
    float sp = (xx > 20.f) ? xx : log1pf(expf(xx));
    float eg = expf(-expf(A_log[n])*sp);
    float bt = 1.f/(1.f+expf(-sb));
    meta[(size_t)row*Hz + n] = make_float2(eg, bt);
  }
}

// ------- fused conv(K=4)+SiLU+l2norm+scale for k,q -> kqn[bt][h][96k|96q] bf16 -------
__global__ __launch_bounds__(64) void conv_kq_kernel(
    const bf16* __restrict__ preq, const bf16* __restrict__ prek,
    const float* __restrict__ wqc, const float* __restrict__ wkc,
    us* __restrict__ kqn)
{
  const int idx = blockIdx.x; const int h = idx & 7; const int bt = idx >> 3;
  const int t = bt & (Tz-1);
  const int lane = threadIdx.x;
  const us* Q = (const us*)preq;
  const us* K = (const us*)prek;
  const int c0 = h*DKz + lane, c1 = c0 + 64;
  const bool hi = lane < 32;
  float yq0=0.f, yq1=0.f, yk0=0.f, yk1=0.f;
  #pragma unroll
  for (int i=0;i<4;i++){
    const int ti = t - 3 + i;
    if (ti >= 0){
      const size_t rowb = (size_t)(bt-3+i)*KDz;
      yq0 = fmaf(us2f(Q[rowb + c0]), wqc[c0*4+i], yq0);
      yk0 = fmaf(us2f(K[rowb + c0]), wkc[c0*4+i], yk0);
      if (hi){
        yq1 = fmaf(us2f(Q[rowb + c1]), wqc[c1*4+i], yq1);
        yk1 = fmaf(us2f(K[rowb + c1]), wkc[c1*4+i], yk1);
      }
    }
  }
  yq0 = siluf_(yq0); yk0 = siluf_(yk0);
  yq1 = hi ? siluf_(yq1) : 0.f;
  yk1 = hi ? siluf_(yk1) : 0.f;
  float ssq = yq0*yq0 + yq1*yq1;
  float ssk = yk0*yk0 + yk1*yk1;
  #pragma unroll
  for (int off=32; off>=1; off>>=1){ ssq += __shfl_xor(ssq,off); ssk += __shfl_xor(ssk,off); }
  const float iq = rsqrtf(ssq + 1e-6f) * 0.10206207262f;  // invq * dk^-0.5
  const float ik = rsqrtf(ssk + 1e-6f);
  const size_t base = (size_t)bt*1536 + (size_t)h*192;
  kqn[base + lane]      = f2bs(yk0*ik);
  kqn[base + 96 + lane] = f2bs(yq0*iq);
  if (hi){
    kqn[base + 64 + lane]      = f2bs(yk1*ik);
    kqn[base + 96 + 64 + lane] = f2bs(yq1*iq);
  }
}

// ------- apply conv+SiLU to v -> vn bf16 -------
__global__ __launch_bounds__(256) void conv_apply_v_kernel(
    const bf16* __restrict__ prev, const float* __restrict__ wvc, bf16* __restrict__ vn)
{
  const int bt = blockIdx.y; const int ccol = blockIdx.x*256 + threadIdx.x;
  const int t = bt & (Tz-1);
  const us* X = (const us*)prev;
  float acc = 0.f;
  #pragma unroll
  for (int i=0;i<4;i++){
    const int ti = t - 3 + i;
    if (ti >= 0) acc = fmaf(us2f(X[(size_t)(bt-3+i)*VDz + ccol]), wvc[ccol*4+i], acc);
  }
  ((us*)vn)[(size_t)bt*VDz + ccol] = f2bs(siluf_(acc));
}

// ---------------- gated delta-rule scan, consume-only, 16-way split ----------------
// Grid = Bz*Hz*16; block (bh, sp) owns v-cols [sp*12, sp*12+12).
// 192 threads: tid = j*16 + g; thread owns S[g*6 .. g*6+5][col sp*12+j].
// 2 blocks/CU (512 blocks on 256 CUs) -> 1.5 waves/SIMD for stall overlap.
// Phase = 8 steps: (1) global prefetch next phase; (2) consume 8 steps (parity
// register sets, ds_read_b64, gsum16 DPP reductions); (3) stage next; barrier.
__global__ __launch_bounds__(192, 1) void scan_kernel(
    const us* __restrict__ kqn, const bf16* __restrict__ vn,
    const float2* __restrict__ meta, bf16* __restrict__ o)
{
  const int blk = blockIdx.x;
  const int bh = blk >> 4, sp = blk & 15;
  const int b = bh >> 3, h = bh & 7;
  const int tid = threadIdx.x;
  const int g = tid & 15;
  const int j = tid >> 4;               // 0..11
  const int vc = h*DVz + sp*12 + j;

  __shared__ float kq[2][8][192];       // [buf][step][96 k | 96 q]

  const us* KQ = kqn + (size_t)b*Tz*1536 + h*192 + tid;
  const us* VP = (const us*)vn + (size_t)b*Tz*VDz + vc;
  us* op = (us*)o + (size_t)b*Tz*VDz + vc;
  const float2* MP = meta + (size_t)b*Tz*Hz + h;

  float S[6];
  #pragma unroll
  for (int m=0;m<6;m++) S[m]=0.f;

  float ced[8], egb[8], cvb[8];   // eg, eg*beta, v*beta

  // ---- prologue: stage phase 0 ----
  #pragma unroll
  for (int s=0;s<8;s++){
    kq[0][s][tid] = us2f(KQ[(size_t)s*1536]);
    const float cv = us2f(VP[(size_t)s*VDz]);
    const float2 m = MP[(size_t)s*Hz];
    ced[s] = m.x; egb[s] = m.x*m.y; cvb[s] = cv*m.y;
  }
  __syncthreads();

  for (int ph=0; ph<Tz/8; ph++){
    const int base = ph*8;
    const int p = ph & 1;
    const bool more = (base + 8 < Tz);
    const int nb = more ? base + 8 : base;   // clamp; values unused when !more
    // (1) prefetch next-phase inputs (independent -> issue at top)
    float nkq[8], nv[8]; float2 nm[8];
    #pragma unroll
    for (int s=0;s<8;s++){
      nkq[s] = us2f(KQ[(size_t)(nb+s)*1536]);
      nv[s]  = us2f(VP[(size_t)(nb+s)*VDz]);
      nm[s]  = MP[(size_t)(nb+s)*Hz];
    }
    // (2) consume 8 steps; parity register sets, b64 reads (g*24B: all-banks-once)
    float2 kf[2][3], qf[2][3];
    #pragma unroll
    for (int m=0;m<3;m++){
      kf[0][m] = *(const float2*)&kq[p][0][g*6 + m*2];
      qf[0][m] = *(const float2*)&kq[p][0][96 + g*6 + m*2];
    }
    #pragma unroll
    for (int s=0;s<8;s++){
      const int cu = s & 1, nx = cu ^ 1;
      if (s < 7){
        #pragma unroll
        for (int m=0;m<3;m++){
          kf[nx][m] = *(const float2*)&kq[p][s+1][g*6 + m*2];
          qf[nx][m] = *(const float2*)&kq[p][s+1][96 + g*6 + m*2];
        }
      }
      float a0, a1;
      a0 = kf[cu][0].x*S[0];          a1 = kf[cu][0].y*S[1];
      a0 = fmaf(kf[cu][1].x,S[2],a0); a1 = fmaf(kf[cu][1].y,S[3],a1);
      a0 = fmaf(kf[cu][2].x,S[4],a0); a1 = fmaf(kf[cu][2].y,S[5],a1);
      const float pv = gsum16(a0+a1);
      const float eg = ced[s];
      const float delta = fmaf(-egb[s], pv, cvb[s]);   // (cv - eg*pv)*beta
      float o0, o1, t0;
      t0 = fmaf(eg,S[0], kf[cu][0].x*delta); S[0]=t0; o0 = qf[cu][0].x*t0;
      t0 = fmaf(eg,S[1], kf[cu][0].y*delta); S[1]=t0; o1 = qf[cu][0].y*t0;
      t0 = fmaf(eg,S[2], kf[cu][1].x*delta); S[2]=t0; o0 = fmaf(qf[cu][1].x,t0,o0);
      t0 = fmaf(eg,S[3], kf[cu][1].y*delta); S[3]=t0; o1 = fmaf(qf[cu][1].y,t0,o1);
      t0 = fmaf(eg,S[4], kf[cu][2].x*delta); S[4]=t0; o0 = fmaf(qf[cu][2].x,t0,o0);
      t0 = fmaf(eg,S[5], kf[cu][2].y*delta); S[5]=t0; o1 = fmaf(qf[cu][2].y,t0,o1);
      const float po = gsum16(o0+o1);
      if (g == 0) op[(size_t)(base+s)*VDz] = f2bs(po);
    }
    // (3) stage next phase from prefetched registers (1:1, branch-free)
    if (more){
      #pragma unroll
      for (int s=0;s<8;s++){
        kq[p^1][s][tid] = nkq[s];
        ced[s] = nm[s].x; egb[s] = nm[s].x*nm[s].y; cvb[s] = nv[s]*nm[s].y;
      }
    }
    __syncthreads();
  }
}

// ---------------- output gate: rmsnorm_dv(o) * silu(gout) ----------------
__global__ __launch_bounds__(64) void gate_out_kernel(
    const bf16* __restrict__ o, const bf16* __restrict__ gout,
    const float* __restrict__ onw, bf16* __restrict__ og)
{
  const size_t base = (size_t)blockIdx.x * DVz;
  const int lane = threadIdx.x;
  const us* O = (const us*)o;
  float x0 = us2f(O[base+lane]), x1 = us2f(O[base+64+lane]), x2 = us2f(O[base+128+lane]);
  float ss = x0*x0 + x1*x1 + x2*x2;
  #pragma unroll
  for (int off=32; off>=1; off>>=1) ss += __shfl_xor(ss, off);
  const float inv = rsqrtf(ss*(1.f/DVz) + 1e-6f);
  const us* G = (const us*)gout;
  us* OG = (us*)og;
  float xs[3] = {x0, x1, x2};
  #pragma unroll
  for (int i=0;i<3;i++){
    const int c = lane + 64*i;
    const float gv = us2f(G[base+c]);
    OG[base+c] = f2bs(xs[i]*inv*onw[c] * siluf_(gv));
  }
}

extern "C" void kernel_launch(void* const* d_in, const int* in_sizes, int n_in,
                              void* d_out, int out_size, void* d_ws, size_t ws_size,
                              hipStream_t stream) {
  const float* x        = (const float*)d_in[0];
  const float* Wq       = (const float*)d_in[1];
  const float* Wk       = (const float*)d_in[2];
  const float* Wv       = (const float*)d_in[3];
  const float* Wb       = (const float*)d_in[4];
  const float* Wa       = (const float*)d_in[5];
  const float* A_log    = (const float*)d_in[6];
  const float* dt_bias  = (const float*)d_in[7];
  const float* conv_q_w = (const float*)d_in[8];
  const float* conv_k_w = (const float*)d_in[9];
  const float* conv_v_w = (const float*)d_in[10];
  const float* Wg       = (const float*)d_in[11];
  const float* onorm_w  = (const float*)d_in[12];
  const float* Wo       = (const float*)d_in[13];
  const float* norm1_w  = (const float*)d_in[14];
  const float* norm2_w  = (const float*)d_in[15];
  const float* Wgate    = (const float*)d_in[16];
  const float* Wup      = (const float*)d_in[17];
  const float* Wdown    = (const float*)d_in[18];

  char* W = (char*)d_ws;
  // bf16-transposed weights (rewritten every launch; deterministic)
  us* WoT    = (us*)(W + 0);           // live thru Wo GEMM
  us* WgateT = (us*)(W + 3145728);     // live thru MLP
  us* WupT   = (us*)(W + 11534336);
  us* WdownT = (us*)(W + 19922944);    // ends 28,311,552
  us* WqT    = (us*)(W + 28311552);    // dead after proj
  us* WkT    = (us*)(W + 29884416);
  us* WvT    = (us*)(W + 31457280);
  us* WgT    = (us*)(W + 34603008);    // ends 37,748,736; dead after gout GEMM
  // activations
  bf16*   h_   = (bf16*)  (W + 37748736);   // [8192,1024]; dead after gout GEMM
  bf16*   preq = (bf16*)  (W + 54525952);   // [8192,768];  dead after conv_kq
  bf16*   prek = (bf16*)  (W + 67108864);   // [8192,768];  dead after conv_kq
  bf16*   prev = (bf16*)  (W + 79691776);   // [8192,1536]; dead after conv_apply_v
  float2* meta = (float2*)(W + 104857600);  // [8192,8] float2; dead after scan
  bf16*   gout = (bf16*)  (W + 105906176);  // [8192,1536]; ends 131,072,000 (PEAK)
  // aliases over dead regions
  us*    kqn   = (us*)   (W + 28311552);   // [8192,1536] bf16 over WqT..h_-head (dead after scan)
  bf16*  vn    = (bf16*) (W + 54525952);   // [8192,1536] over preq+prek (dead after scan)
  bf16*  o_    = (bf16*) (W + 79691776);   // [8192,1536] over prev (dead after gate_out)
  bf16*  og    = (bf16*) (W + 28311552);   // [8192,1536] over kqn (dead after Wo GEMM)
  float* x2    = (float*)(W + 79691776);   // [8192,1024] f32 over o_+meta+gout-head (post gate_out)
  bf16*  h2    = (bf16*) (W + 113246208);  // [8192,1024] over gout tail (dead after gate_out)
  bf16*  gateC = (bf16*) (W + 28311552);   // [4096,4096] over og+vn region (dead after Wo GEMM)

  // 0. weight prep (transpose + f32->bf16)
  wprep_kernel<<<dim3(48,32),  256, 0, stream>>>(Wo,    WoT,    1536, 1024);
  wprep_kernel<<<dim3(32,128), 256, 0, stream>>>(Wgate, WgateT, 1024, 4096);
  wprep_kernel<<<dim3(32,128), 256, 0, stream>>>(Wup,   WupT,   1024, 4096);
  wprep_kernel<<<dim3(128,32), 256, 0, stream>>>(Wdown, WdownT, 4096, 1024);
  wprep_kernel<<<dim3(32,24),  256, 0, stream>>>(Wq,    WqT,    1024, 768);
  wprep_kernel<<<dim3(32,24),  256, 0, stream>>>(Wk,    WkT,    1024, 768);
  wprep_kernel<<<dim3(32,48),  256, 0, stream>>>(Wv,    WvT,    1024, 1536);
  wprep_kernel<<<dim3(32,48),  256, 0, stream>>>(Wg,    WgT,    1024, 1536);
  // 1. pre-norm
  rmsnorm_kernel<<<BTz, 256, 0, stream>>>(x, norm1_w, h_);
  // 2. projections + meta (eg, beta); gout GEMM before h_/WgT regions are reused
  mgemm_kernel<0><<<dim3(6,64),  256, 0, stream>>>(h_, WqT, nullptr, preq, BTz, KDz, Dz);
  mgemm_kernel<0><<<dim3(6,64),  256, 0, stream>>>(h_, WkT, nullptr, prek, BTz, KDz, Dz);
  mgemm_kernel<0><<<dim3(12,64), 256, 0, stream>>>(h_, WvT, nullptr, prev, BTz, VDz, Dz);
  beta_g_kernel<<<BTz, 256, 0, stream>>>(h_, Wb, Wa, A_log, dt_bias, meta);
  mgemm_kernel<0><<<dim3(12,64), 256, 0, stream>>>(h_, WgT, nullptr, gout, BTz, VDz, Dz);
  // 3. fused conv+silu+l2+scale -> kqn; conv+silu -> vn; consume-only scan
  conv_kq_kernel<<<BTz*Hz, 64, 0, stream>>>(preq, prek, conv_q_w, conv_k_w, kqn);
  conv_apply_v_kernel<<<dim3(6, BTz), 256, 0, stream>>>(prev, conv_v_w, vn);
  scan_kernel<<<Bz*Hz*16, 192, 0, stream>>>(kqn, vn, meta, o_);
  // 4. output gating + Wo projection with residual
  gate_out_kernel<<<BTz*Hz, 64, 0, stream>>>(o_, gout, onorm_w, og);
  mgemm_kernel<1><<<dim3(8,64), 256, 0, stream>>>(og, WoT, x, x2, BTz, Dz, VDz);
  // 5. MLP, chunked over 2 x 4096 rows
  rmsnorm_kernel<<<BTz, 256, 0, stream>>>(x2, norm2_w, h2);
  for (int c = 0; c < 2; c++){
    const bf16*  h2c = h2 + (size_t)c*4096*Dz;
    const float* x2c = x2 + (size_t)c*4096*Dz;
    float*       out = (float*)d_out + (size_t)c*4096*Dz;
    mgemm_kernel<0><<<dim3(32,32), 256, 0, stream>>>(h2c, WgateT, nullptr, gateC, 4096, Iz, Dz);
    mgemm_kernel<3><<<dim3(32,32), 256, 0, stream>>>(h2c, WupT, gateC, gateC, 4096, Iz, Dz);
    mgemm_kernel<1><<<dim3(8,32),  256, 0, stream>>>(gateC, WdownT, x2c, out, 4096, Dz, Iz);
  }
}